// Round 1
// baseline (3910.069 us; speedup 1.0000x reference)
//
#include <hip/hip_runtime.h>
#include <hip/hip_bf16.h>
#include <math.h>

#define NN 50000
#define HIDD 96
#define NH 8
#define HD 12
#define FFND 384
#define NE 800000

// 1/sqrt(12)
#define INV_SCALE 0.28867513459481287f

// ---------------- zero kernel ----------------
__global__ void zero_kernel(float* __restrict__ p, int n) {
    int i = blockIdx.x * blockDim.x + threadIdx.x;
    if (i < n) p[i] = 0.0f;
}

// ---------------- LayerNorm: one wave (64 lanes) per row of 96 ----------------
__global__ void ln_kernel(const float* __restrict__ x, const float* __restrict__ g,
                          const float* __restrict__ b, float* __restrict__ y, int nrows) {
    int wave = (blockIdx.x * blockDim.x + threadIdx.x) >> 6;
    int lane = threadIdx.x & 63;
    if (wave >= nrows) return;
    const float* xr = x + (size_t)wave * HIDD;
    float v0 = xr[lane];
    float v1 = (lane < 32) ? xr[64 + lane] : 0.0f;
    float s = v0 + v1;
    float q = v0 * v0 + v1 * v1;
    for (int o = 32; o > 0; o >>= 1) {
        s += __shfl_xor(s, o);
        q += __shfl_xor(q, o);
    }
    float mean = s * (1.0f / 96.0f);
    float var = q * (1.0f / 96.0f) - mean * mean;
    float rs = rsqrtf(var + 1e-5f);
    float* yr = y + (size_t)wave * HIDD;
    yr[lane] = (v0 - mean) * rs * g[lane] + b[lane];
    if (lane < 32) yr[64 + lane] = (v1 - mean) * rs * g[64 + lane] + b[64 + lane];
}

// ---------------- QKV projection: 32 rows x 96 cols per block, 192 threads ----------------
// blockIdx.y selects q/k/v. Each thread owns one col for 16 rows (stride 2).
__global__ __launch_bounds__(192) void qkv_kernel(
    const float* __restrict__ y,
    const float* __restrict__ Wq, const float* __restrict__ bq,
    const float* __restrict__ Wk, const float* __restrict__ bk,
    const float* __restrict__ Wv, const float* __restrict__ bv,
    float* __restrict__ q, float* __restrict__ k, float* __restrict__ v) {
    __shared__ float ylds[32 * 96];
    int which = blockIdx.y;
    const float* W   = (which == 0) ? Wq : (which == 1) ? Wk : Wv;
    const float* bia = (which == 0) ? bq : (which == 1) ? bk : bv;
    float* out       = (which == 0) ? q  : (which == 1) ? k  : v;
    int t = threadIdx.x;
    int row0 = blockIdx.x * 32;
    for (int i = t; i < 32 * 96; i += 192) {
        int r = i / 96, c = i % 96;
        int row = row0 + r;
        ylds[i] = (row < NN) ? y[(size_t)row * HIDD + c] : 0.0f;
    }
    __syncthreads();
    int c = t % 96, half = t / 96;
    float acc[16];
#pragma unroll
    for (int i = 0; i < 16; i++) acc[i] = 0.0f;
    for (int kk = 0; kk < 96; kk++) {
        float w = W[kk * 96 + c];
#pragma unroll
        for (int i = 0; i < 16; i++) acc[i] += ylds[(half + 2 * i) * 96 + kk] * w;
    }
    float bb = bia[c];
#pragma unroll
    for (int i = 0; i < 16; i++) {
        int row = row0 + half + 2 * i;
        if (row < NN) out[(size_t)row * HIDD + c] = acc[i] + bb;
    }
}

// ---------------- Sparse attention: one thread per (edge, head) ----------------
__global__ void attn_kernel(const float* __restrict__ q, const float* __restrict__ k,
                            const float* __restrict__ v, const int* __restrict__ ei,
                            float* __restrict__ wV, float* __restrict__ Z) {
    int tid = blockIdx.x * blockDim.x + threadIdx.x;
    if (tid >= NE * NH) return;
    int e = tid >> 3;
    int h = tid & 7;
    int src = ei[e];
    int dst = ei[NE + e];
    const float4* kp = (const float4*)(k + (size_t)src * HIDD + h * HD);
    const float4* qp = (const float4*)(q + (size_t)dst * HIDD + h * HD);
    float4 k0 = kp[0], k1 = kp[1], k2 = kp[2];
    float4 q0 = qp[0], q1 = qp[1], q2 = qp[2];
    float dot = k0.x * q0.x + k0.y * q0.y + k0.z * q0.z + k0.w * q0.w
              + k1.x * q1.x + k1.y * q1.y + k1.z * q1.z + k1.w * q1.w
              + k2.x * q2.x + k2.y * q2.y + k2.z * q2.z + k2.w * q2.w;
    float s = dot * INV_SCALE;
    s = fminf(fmaxf(s, -5.0f), 5.0f);
    float sc = expf(s);
    const float4* vp = (const float4*)(v + (size_t)src * HIDD + h * HD);
    float4 v0 = vp[0], v1 = vp[1], v2 = vp[2];
    float* wp = wV + (size_t)dst * HIDD + h * HD;
    atomicAdd(wp + 0,  v0.x * sc);
    atomicAdd(wp + 1,  v0.y * sc);
    atomicAdd(wp + 2,  v0.z * sc);
    atomicAdd(wp + 3,  v0.w * sc);
    atomicAdd(wp + 4,  v1.x * sc);
    atomicAdd(wp + 5,  v1.y * sc);
    atomicAdd(wp + 6,  v1.z * sc);
    atomicAdd(wp + 7,  v1.w * sc);
    atomicAdd(wp + 8,  v2.x * sc);
    atomicAdd(wp + 9,  v2.y * sc);
    atomicAdd(wp + 10, v2.z * sc);
    atomicAdd(wp + 11, v2.w * sc);
    atomicAdd(Z + (size_t)dst * NH + h, sc);
}

// ---------------- Output projection + residual: x2 = x + (wV/Z) @ Wo + bo ----------------
__global__ __launch_bounds__(192) void proj_kernel(
    const float* __restrict__ wV, const float* __restrict__ Z,
    const float* __restrict__ x,
    const float* __restrict__ Wo, const float* __restrict__ bo,
    float* __restrict__ x2) {
    __shared__ float alds[32 * 96];
    int t = threadIdx.x;
    int row0 = blockIdx.x * 32;
    for (int i = t; i < 32 * 96; i += 192) {
        int r = i / 96, c = i % 96;
        int row = row0 + r;
        float val = 0.0f;
        if (row < NN) {
            float z = Z[(size_t)row * NH + c / HD];
            val = wV[(size_t)row * HIDD + c] / (z + 1e-6f);
        }
        alds[i] = val;
    }
    __syncthreads();
    int c = t % 96, half = t / 96;
    float acc[16];
#pragma unroll
    for (int i = 0; i < 16; i++) acc[i] = 0.0f;
    for (int kk = 0; kk < 96; kk++) {
        float w = Wo[kk * 96 + c];
#pragma unroll
        for (int i = 0; i < 16; i++) acc[i] += alds[(half + 2 * i) * 96 + kk] * w;
    }
    float bb = bo[c];
#pragma unroll
    for (int i = 0; i < 16; i++) {
        int row = row0 + half + 2 * i;
        if (row < NN) x2[(size_t)row * HIDD + c] = x[(size_t)row * HIDD + c] + acc[i] + bb;
    }
}

// ---------------- FFN1: h = gelu(t @ W1 + b1), cols split over blockIdx.y ----------------
__global__ __launch_bounds__(192) void ffn1_kernel(
    const float* __restrict__ tin, const float* __restrict__ W1,
    const float* __restrict__ b1, float* __restrict__ h) {
    __shared__ float tlds[32 * 96];
    int t = threadIdx.x;
    int row0 = blockIdx.x * 32;
    int col0 = blockIdx.y * 96;
    for (int i = t; i < 32 * 96; i += 192) {
        int r = i / 96, c = i % 96;
        int row = row0 + r;
        tlds[i] = (row < NN) ? tin[(size_t)row * HIDD + c] : 0.0f;
    }
    __syncthreads();
    int c = col0 + t % 96, half = t / 96;
    float acc[16];
#pragma unroll
    for (int i = 0; i < 16; i++) acc[i] = 0.0f;
    for (int kk = 0; kk < 96; kk++) {
        float w = W1[kk * FFND + c];
#pragma unroll
        for (int i = 0; i < 16; i++) acc[i] += tlds[(half + 2 * i) * 96 + kk] * w;
    }
    float bb = b1[c];
#pragma unroll
    for (int i = 0; i < 16; i++) {
        int row = row0 + half + 2 * i;
        if (row < NN) {
            float z = acc[i] + bb;
            float gel = 0.5f * z * (1.0f + erff(z * 0.70710678118654752f));
            h[(size_t)row * FFND + c] = gel;
        }
    }
}

// ---------------- FFN2 + residual: out = x2 + h @ W2 + b2 ----------------
__global__ __launch_bounds__(192) void ffn2_kernel(
    const float* __restrict__ h, const float* __restrict__ W2,
    const float* __restrict__ b2, const float* __restrict__ x2,
    float* __restrict__ out) {
    __shared__ float hlds[32 * 384];  // 48 KB
    int t = threadIdx.x;
    int row0 = blockIdx.x * 32;
    for (int i = t; i < 32 * 384; i += 192) {
        int r = i / 384, c = i % 384;
        int row = row0 + r;
        hlds[i] = (row < NN) ? h[(size_t)row * FFND + c] : 0.0f;
    }
    __syncthreads();
    int c = t % 96, half = t / 96;
    float acc[16];
#pragma unroll
    for (int i = 0; i < 16; i++) acc[i] = 0.0f;
    for (int kk = 0; kk < 384; kk++) {
        float w = W2[kk * 96 + c];
#pragma unroll
        for (int i = 0; i < 16; i++) acc[i] += hlds[(half + 2 * i) * 384 + kk] * w;
    }
    float bb = b2[c];
#pragma unroll
    for (int i = 0; i < 16; i++) {
        int row = row0 + half + 2 * i;
        if (row < NN) out[(size_t)row * HIDD + c] = x2[(size_t)row * HIDD + c] + acc[i] + bb;
    }
}

extern "C" void kernel_launch(void* const* d_in, const int* in_sizes, int n_in,
                              void* d_out, int out_size, void* d_ws, size_t ws_size,
                              hipStream_t stream) {
    const float* x     = (const float*)d_in[0];
    const int*   ei    = (const int*)d_in[1];
    const float* ln1_g = (const float*)d_in[2];
    const float* ln1_b = (const float*)d_in[3];
    const float* Wq    = (const float*)d_in[4];
    const float* bq    = (const float*)d_in[5];
    const float* Wk    = (const float*)d_in[6];
    const float* bk    = (const float*)d_in[7];
    const float* Wv    = (const float*)d_in[8];
    const float* bv    = (const float*)d_in[9];
    const float* Wo    = (const float*)d_in[10];
    const float* bo    = (const float*)d_in[11];
    const float* ln2_g = (const float*)d_in[12];
    const float* ln2_b = (const float*)d_in[13];
    const float* W1    = (const float*)d_in[14];
    const float* b1    = (const float*)d_in[15];
    const float* W2    = (const float*)d_in[16];
    const float* b2    = (const float*)d_in[17];
    float* out = (float*)d_out;

    // Workspace layout (floats). h aliases q/k/v/wV (dead by the time h is written).
    float* ws = (float*)d_ws;
    const size_t NF = (size_t)NN * HIDD;   // 4.8M
    float* q   = ws;                        // [0, 4.8M)
    float* k   = ws + NF;                   // [4.8M, 9.6M)
    float* v   = ws + 2 * NF;               // [9.6M, 14.4M)
    float* wV  = ws + 3 * NF;               // [14.4M, 19.2M)
    float* h   = ws;                        // aliases q..wV: [0, 19.2M)
    float* Z   = ws + 4 * NF;               // [19.2M, 19.6M)
    float* x2  = ws + 4 * NF + (size_t)NN * NH;            // [19.6M, 24.4M)
    float* ybuf = ws + 5 * NF + (size_t)NN * NH;           // [24.4M, 29.2M)

    const int ROWTILES = (NN + 31) / 32;  // 1563

    // 1. zero wV and Z (contiguous: 4.8M + 0.4M floats)
    {
        int n = (int)(NF + (size_t)NN * NH);
        zero_kernel<<<(n + 255) / 256, 256, 0, stream>>>(wV, n);
    }
    // 2. LN1: x -> ybuf
    ln_kernel<<<(NN + 3) / 4, 256, 0, stream>>>(x, ln1_g, ln1_b, ybuf, NN);
    // 3. QKV
    {
        dim3 g(ROWTILES, 3);
        qkv_kernel<<<g, 192, 0, stream>>>(ybuf, Wq, bq, Wk, bk, Wv, bv, q, k, v);
    }
    // 4. Sparse attention accumulate
    {
        long long nt = (long long)NE * NH;
        attn_kernel<<<(int)((nt + 255) / 256), 256, 0, stream>>>(q, k, v, ei, wV, Z);
    }
    // 5. Output projection + residual -> x2
    proj_kernel<<<ROWTILES, 192, 0, stream>>>(wV, Z, x, Wo, bo, x2);
    // 6. LN2: x2 -> ybuf
    ln_kernel<<<(NN + 3) / 4, 256, 0, stream>>>(x2, ln2_g, ln2_b, ybuf, NN);
    // 7. FFN1: ybuf -> h
    {
        dim3 g(ROWTILES, 4);
        ffn1_kernel<<<g, 192, 0, stream>>>(ybuf, W1, b1, h);
    }
    // 8. FFN2 + residual -> out
    ffn2_kernel<<<ROWTILES, 192, 0, stream>>>(h, W2, b2, x2, out);
}

// Round 2
// 776.344 us; speedup vs baseline: 5.0365x; 5.0365x over previous
//
#include <hip/hip_runtime.h>
#include <hip/hip_bf16.h>
#include <math.h>

#define NN 50000
#define HIDD 96
#define NH 8
#define HD 12
#define FFND 384
#define NE 800000

// 1/sqrt(12)
#define INV_SCALE 0.28867513459481287f

// ---------------- zero kernel (ints/floats, 0 bit pattern) ----------------
__global__ void zero_kernel(int* __restrict__ p, int n) {
    int i = blockIdx.x * blockDim.x + threadIdx.x;
    if (i < n) p[i] = 0;
}

// ---------------- degree histogram ----------------
__global__ void deg_hist(const int* __restrict__ ei, int* __restrict__ deg) {
    int e = blockIdx.x * blockDim.x + threadIdx.x;
    if (e < NE) atomicAdd(&deg[ei[NE + e]], 1);
}

// ---------------- scan step 1: per-block (1024 elems) inclusive scan ----------------
__global__ __launch_bounds__(256) void scan1(const int* __restrict__ deg,
                                             int* __restrict__ rowptr,
                                             int* __restrict__ bsum) {
    __shared__ int lds[256];
    int t = threadIdx.x;
    int base = blockIdx.x * 1024 + t * 4;
    int v0 = (base + 0 < NN) ? deg[base + 0] : 0;
    int v1 = (base + 1 < NN) ? deg[base + 1] : 0;
    int v2 = (base + 2 < NN) ? deg[base + 2] : 0;
    int v3 = (base + 3 < NN) ? deg[base + 3] : 0;
    int p0 = v0, p1 = p0 + v1, p2 = p1 + v2, p3 = p2 + v3;
    lds[t] = p3;
    __syncthreads();
    for (int off = 1; off < 256; off <<= 1) {
        int val = (t >= off) ? lds[t - off] : 0;
        __syncthreads();
        lds[t] += val;
        __syncthreads();
    }
    int prefix = (t > 0) ? lds[t - 1] : 0;
    if (base + 0 < NN) rowptr[base + 1] = prefix + p0;
    if (base + 1 < NN) rowptr[base + 2] = prefix + p1;
    if (base + 2 < NN) rowptr[base + 3] = prefix + p2;
    if (base + 3 < NN) rowptr[base + 4] = prefix + p3;
    if (t == 255) bsum[blockIdx.x] = lds[255];
}

// ---------------- scan step 2: serial exclusive scan of block sums ----------------
__global__ void scan2(int* __restrict__ bsum, int nblk) {
    if (threadIdx.x == 0 && blockIdx.x == 0) {
        int run = 0;
        for (int i = 0; i < nblk; i++) { int s = bsum[i]; bsum[i] = run; run += s; }
    }
}

// ---------------- scan step 3: add block offsets, init cursor ----------------
__global__ __launch_bounds__(256) void scan3(int* __restrict__ rowptr,
                                             const int* __restrict__ bsum,
                                             int* __restrict__ cursor) {
    int i = blockIdx.x * blockDim.x + threadIdx.x;
    if (i < NN) {
        int val = rowptr[i + 1] + bsum[i / 1024];
        rowptr[i + 1] = val;
        if (i + 1 < NN) cursor[i + 1] = val;
    }
    if (i == 0) { rowptr[0] = 0; cursor[0] = 0; }
}

// ---------------- scatter: group src indices by dst ----------------
__global__ void scatter_kernel(const int* __restrict__ ei, int* __restrict__ cursor,
                               int* __restrict__ srcs) {
    int e = blockIdx.x * blockDim.x + threadIdx.x;
    if (e >= NE) return;
    int dst = ei[NE + e];
    int pos = atomicAdd(&cursor[dst], 1);
    srcs[pos] = ei[e];
}

// ---------------- LayerNorm: one wave (64 lanes) per row of 96 ----------------
__global__ void ln_kernel(const float* __restrict__ x, const float* __restrict__ g,
                          const float* __restrict__ b, float* __restrict__ y, int nrows) {
    int wave = (blockIdx.x * blockDim.x + threadIdx.x) >> 6;
    int lane = threadIdx.x & 63;
    if (wave >= nrows) return;
    const float* xr = x + (size_t)wave * HIDD;
    float v0 = xr[lane];
    float v1 = (lane < 32) ? xr[64 + lane] : 0.0f;
    float s = v0 + v1;
    float q = v0 * v0 + v1 * v1;
    for (int o = 32; o > 0; o >>= 1) {
        s += __shfl_xor(s, o);
        q += __shfl_xor(q, o);
    }
    float mean = s * (1.0f / 96.0f);
    float var = q * (1.0f / 96.0f) - mean * mean;
    float rs = rsqrtf(var + 1e-5f);
    float* yr = y + (size_t)wave * HIDD;
    yr[lane] = (v0 - mean) * rs * g[lane] + b[lane];
    if (lane < 32) yr[64 + lane] = (v1 - mean) * rs * g[64 + lane] + b[64 + lane];
}

// ---------------- QKV projection: 32 rows x 96 cols per block, 192 threads ----------------
__global__ __launch_bounds__(192) void qkv_kernel(
    const float* __restrict__ y,
    const float* __restrict__ Wq, const float* __restrict__ bq,
    const float* __restrict__ Wk, const float* __restrict__ bk,
    const float* __restrict__ Wv, const float* __restrict__ bv,
    float* __restrict__ q, float* __restrict__ k, float* __restrict__ v) {
    __shared__ float ylds[32 * 96];
    int which = blockIdx.y;
    const float* W   = (which == 0) ? Wq : (which == 1) ? Wk : Wv;
    const float* bia = (which == 0) ? bq : (which == 1) ? bk : bv;
    float* out       = (which == 0) ? q  : (which == 1) ? k  : v;
    int t = threadIdx.x;
    int row0 = blockIdx.x * 32;
    for (int i = t; i < 32 * 96; i += 192) {
        int r = i / 96, c = i % 96;
        int row = row0 + r;
        ylds[i] = (row < NN) ? y[(size_t)row * HIDD + c] : 0.0f;
    }
    __syncthreads();
    int c = t % 96, half = t / 96;
    float acc[16];
#pragma unroll
    for (int i = 0; i < 16; i++) acc[i] = 0.0f;
    for (int kk = 0; kk < 96; kk++) {
        float w = W[kk * 96 + c];
#pragma unroll
        for (int i = 0; i < 16; i++) acc[i] += ylds[(half + 2 * i) * 96 + kk] * w;
    }
    float bb = bia[c];
#pragma unroll
    for (int i = 0; i < 16; i++) {
        int row = row0 + half + 2 * i;
        if (row < NN) out[(size_t)row * HIDD + c] = acc[i] + bb;
    }
}

// ---------------- Sparse attention gather: one wave per dst node ----------------
// lane = eslot*8 + h. Each lane accumulates head h over edge slots eslot, eslot+8, ...
__global__ __launch_bounds__(256) void attn_gather(
    const float* __restrict__ q, const float* __restrict__ k,
    const float* __restrict__ v, const int* __restrict__ rowptr,
    const int* __restrict__ srcs, float* __restrict__ a) {
    int wave = (blockIdx.x * blockDim.x + threadIdx.x) >> 6;
    int lane = threadIdx.x & 63;
    if (wave >= NN) return;
    int dst = wave;
    int h = lane & 7;
    int eslot = lane >> 3;
    const float4* qp = (const float4*)(q + (size_t)dst * HIDD + h * HD);
    float4 q0 = qp[0], q1 = qp[1], q2 = qp[2];
    int beg = rowptr[dst], end = rowptr[dst + 1];
    float4 a0 = {0, 0, 0, 0}, a1 = {0, 0, 0, 0}, a2 = {0, 0, 0, 0};
    float zz = 0.0f;
    for (int e = beg + eslot; e < end; e += 8) {
        int src = srcs[e];
        const float4* kp = (const float4*)(k + (size_t)src * HIDD + h * HD);
        float4 k0 = kp[0], k1 = kp[1], k2 = kp[2];
        float dot = k0.x * q0.x + k0.y * q0.y + k0.z * q0.z + k0.w * q0.w
                  + k1.x * q1.x + k1.y * q1.y + k1.z * q1.z + k1.w * q1.w
                  + k2.x * q2.x + k2.y * q2.y + k2.z * q2.z + k2.w * q2.w;
        float s = fminf(fmaxf(dot * INV_SCALE, -5.0f), 5.0f);
        float sc = expf(s);
        const float4* vp = (const float4*)(v + (size_t)src * HIDD + h * HD);
        float4 v0 = vp[0], v1 = vp[1], v2 = vp[2];
        a0.x += v0.x * sc; a0.y += v0.y * sc; a0.z += v0.z * sc; a0.w += v0.w * sc;
        a1.x += v1.x * sc; a1.y += v1.y * sc; a1.z += v1.z * sc; a1.w += v1.w * sc;
        a2.x += v2.x * sc; a2.y += v2.y * sc; a2.z += v2.z * sc; a2.w += v2.w * sc;
        zz += sc;
    }
    // butterfly reduce over eslot (lane bits 3,4,5)
#pragma unroll
    for (int m = 8; m < 64; m <<= 1) {
        a0.x += __shfl_xor(a0.x, m); a0.y += __shfl_xor(a0.y, m);
        a0.z += __shfl_xor(a0.z, m); a0.w += __shfl_xor(a0.w, m);
        a1.x += __shfl_xor(a1.x, m); a1.y += __shfl_xor(a1.y, m);
        a1.z += __shfl_xor(a1.z, m); a1.w += __shfl_xor(a1.w, m);
        a2.x += __shfl_xor(a2.x, m); a2.y += __shfl_xor(a2.y, m);
        a2.z += __shfl_xor(a2.z, m); a2.w += __shfl_xor(a2.w, m);
        zz += __shfl_xor(zz, m);
    }
    if (eslot == 0) {
        float inv = 1.0f / (zz + 1e-6f);
        a0.x *= inv; a0.y *= inv; a0.z *= inv; a0.w *= inv;
        a1.x *= inv; a1.y *= inv; a1.z *= inv; a1.w *= inv;
        a2.x *= inv; a2.y *= inv; a2.z *= inv; a2.w *= inv;
        float4* ar = (float4*)(a + (size_t)dst * HIDD + h * HD);
        ar[0] = a0; ar[1] = a1; ar[2] = a2;
    }
}

// ---------------- Output projection + residual: x2 = x + a @ Wo + bo ----------------
__global__ __launch_bounds__(192) void proj_kernel(
    const float* __restrict__ a, const float* __restrict__ x,
    const float* __restrict__ Wo, const float* __restrict__ bo,
    float* __restrict__ x2) {
    __shared__ float alds[32 * 96];
    int t = threadIdx.x;
    int row0 = blockIdx.x * 32;
    for (int i = t; i < 32 * 96; i += 192) {
        int r = i / 96, c = i % 96;
        int row = row0 + r;
        alds[i] = (row < NN) ? a[(size_t)row * HIDD + c] : 0.0f;
    }
    __syncthreads();
    int c = t % 96, half = t / 96;
    float acc[16];
#pragma unroll
    for (int i = 0; i < 16; i++) acc[i] = 0.0f;
    for (int kk = 0; kk < 96; kk++) {
        float w = Wo[kk * 96 + c];
#pragma unroll
        for (int i = 0; i < 16; i++) acc[i] += alds[(half + 2 * i) * 96 + kk] * w;
    }
    float bb = bo[c];
#pragma unroll
    for (int i = 0; i < 16; i++) {
        int row = row0 + half + 2 * i;
        if (row < NN) x2[(size_t)row * HIDD + c] = x[(size_t)row * HIDD + c] + acc[i] + bb;
    }
}

// ---------------- FFN1: h = gelu(t @ W1 + b1), cols split over blockIdx.y ----------------
__global__ __launch_bounds__(192) void ffn1_kernel(
    const float* __restrict__ tin, const float* __restrict__ W1,
    const float* __restrict__ b1, float* __restrict__ h) {
    __shared__ float tlds[32 * 96];
    int t = threadIdx.x;
    int row0 = blockIdx.x * 32;
    int col0 = blockIdx.y * 96;
    for (int i = t; i < 32 * 96; i += 192) {
        int r = i / 96, c = i % 96;
        int row = row0 + r;
        tlds[i] = (row < NN) ? tin[(size_t)row * HIDD + c] : 0.0f;
    }
    __syncthreads();
    int c = col0 + t % 96, half = t / 96;
    float acc[16];
#pragma unroll
    for (int i = 0; i < 16; i++) acc[i] = 0.0f;
    for (int kk = 0; kk < 96; kk++) {
        float w = W1[kk * FFND + c];
#pragma unroll
        for (int i = 0; i < 16; i++) acc[i] += tlds[(half + 2 * i) * 96 + kk] * w;
    }
    float bb = b1[c];
#pragma unroll
    for (int i = 0; i < 16; i++) {
        int row = row0 + half + 2 * i;
        if (row < NN) {
            float z = acc[i] + bb;
            float gel = 0.5f * z * (1.0f + erff(z * 0.70710678118654752f));
            h[(size_t)row * FFND + c] = gel;
        }
    }
}

// ---------------- FFN2 + residual: out = x2 + h @ W2 + b2 ----------------
__global__ __launch_bounds__(192) void ffn2_kernel(
    const float* __restrict__ h, const float* __restrict__ W2,
    const float* __restrict__ b2, const float* __restrict__ x2,
    float* __restrict__ out) {
    __shared__ float hlds[32 * 384];  // 48 KB
    int t = threadIdx.x;
    int row0 = blockIdx.x * 32;
    for (int i = t; i < 32 * 384; i += 192) {
        int r = i / 384, c = i % 384;
        int row = row0 + r;
        hlds[i] = (row < NN) ? h[(size_t)row * FFND + c] : 0.0f;
    }
    __syncthreads();
    int c = t % 96, half = t / 96;
    float acc[16];
#pragma unroll
    for (int i = 0; i < 16; i++) acc[i] = 0.0f;
    for (int kk = 0; kk < 384; kk++) {
        float w = W2[kk * 96 + c];
#pragma unroll
        for (int i = 0; i < 16; i++) acc[i] += hlds[(half + 2 * i) * 384 + kk] * w;
    }
    float bb = b2[c];
#pragma unroll
    for (int i = 0; i < 16; i++) {
        int row = row0 + half + 2 * i;
        if (row < NN) out[(size_t)row * HIDD + c] = x2[(size_t)row * HIDD + c] + acc[i] + bb;
    }
}

extern "C" void kernel_launch(void* const* d_in, const int* in_sizes, int n_in,
                              void* d_out, int out_size, void* d_ws, size_t ws_size,
                              hipStream_t stream) {
    const float* x     = (const float*)d_in[0];
    const int*   ei    = (const int*)d_in[1];
    const float* ln1_g = (const float*)d_in[2];
    const float* ln1_b = (const float*)d_in[3];
    const float* Wq    = (const float*)d_in[4];
    const float* bq    = (const float*)d_in[5];
    const float* Wk    = (const float*)d_in[6];
    const float* bk    = (const float*)d_in[7];
    const float* Wv    = (const float*)d_in[8];
    const float* bv    = (const float*)d_in[9];
    const float* Wo    = (const float*)d_in[10];
    const float* bo    = (const float*)d_in[11];
    const float* ln2_g = (const float*)d_in[12];
    const float* ln2_b = (const float*)d_in[13];
    const float* W1    = (const float*)d_in[14];
    const float* b1    = (const float*)d_in[15];
    const float* W2    = (const float*)d_in[16];
    const float* b2    = (const float*)d_in[17];
    float* out = (float*)d_out;

    // Workspace layout (floats):
    //   q [0,4.8M)  k [4.8M,9.6M)  v [9.6M,14.4M)  a [14.4M,19.2M)
    //   h aliases [0,19.2M) (q..a dead once ffn1 runs)
    //   x2 [19.2M,24M)   ybuf [24M,28.8M)
    // CSR ints alias x2's region (dead before proj writes x2):
    //   deg[NN] rowptr[NN+1] cursor[NN] srcs[NE] bsum[64]
    float* ws = (float*)d_ws;
    const size_t NF = (size_t)NN * HIDD;   // 4.8M
    float* q    = ws;
    float* k    = ws + NF;
    float* v    = ws + 2 * NF;
    float* a    = ws + 3 * NF;
    float* h    = ws;                       // aliases q..a
    float* x2   = ws + 4 * NF;
    float* ybuf = ws + 5 * NF;

    int* ibase  = (int*)(ws + 4 * NF);      // aliases x2
    int* deg    = ibase;                    // NN
    int* rowptr = ibase + NN;               // NN+1
    int* cursor = ibase + 2 * NN + 1;       // NN
    int* srcs   = ibase + 3 * NN + 1;       // NE
    int* bsum   = ibase + 3 * NN + 1 + NE;  // 64

    const int ROWTILES = (NN + 31) / 32;    // 1563
    const int SCAN_BLOCKS = (NN + 1023) / 1024;  // 49

    // --- CSR build ---
    zero_kernel<<<(NN + 255) / 256, 256, 0, stream>>>(deg, NN);
    deg_hist<<<(NE + 255) / 256, 256, 0, stream>>>(ei, deg);
    scan1<<<SCAN_BLOCKS, 256, 0, stream>>>(deg, rowptr, bsum);
    scan2<<<1, 64, 0, stream>>>(bsum, SCAN_BLOCKS);
    scan3<<<(NN + 255) / 256, 256, 0, stream>>>(rowptr, bsum, cursor);
    scatter_kernel<<<(NE + 255) / 256, 256, 0, stream>>>(ei, cursor, srcs);

    // --- transformer block ---
    ln_kernel<<<(NN + 3) / 4, 256, 0, stream>>>(x, ln1_g, ln1_b, ybuf, NN);
    {
        dim3 g(ROWTILES, 3);
        qkv_kernel<<<g, 192, 0, stream>>>(ybuf, Wq, bq, Wk, bk, Wv, bv, q, k, v);
    }
    attn_gather<<<(NN + 3) / 4, 256, 0, stream>>>(q, k, v, rowptr, srcs, a);
    proj_kernel<<<ROWTILES, 192, 0, stream>>>(a, x, Wo, bo, x2);
    ln_kernel<<<(NN + 3) / 4, 256, 0, stream>>>(x2, ln2_g, ln2_b, ybuf, NN);
    {
        dim3 g(ROWTILES, 4);
        ffn1_kernel<<<g, 192, 0, stream>>>(ybuf, W1, b1, h);
    }
    ffn2_kernel<<<ROWTILES, 192, 0, stream>>>(h, W2, b2, x2, out);
}

// Round 3
// 457.935 us; speedup vs baseline: 8.5385x; 1.6953x over previous
//
#include <hip/hip_runtime.h>
#include <hip/hip_bf16.h>
#include <math.h>

#define NN 50000
#define HIDD 96
#define NH 8
#define HD 12
#define FFND 384
#define NE 800000

// 1/sqrt(12)
#define INV_SCALE 0.28867513459481287f

// ---------------- zero kernel ----------------
__global__ void zero_kernel(int* __restrict__ p, int n) {
    int i = blockIdx.x * blockDim.x + threadIdx.x;
    if (i < n) p[i] = 0;
}

// ---------------- degree histogram ----------------
__global__ void deg_hist(const int* __restrict__ ei, int* __restrict__ deg) {
    int e = blockIdx.x * blockDim.x + threadIdx.x;
    if (e < NE) atomicAdd(&deg[ei[NE + e]], 1);
}

// ---------------- scan step 1 ----------------
__global__ __launch_bounds__(256) void scan1(const int* __restrict__ deg,
                                             int* __restrict__ rowptr,
                                             int* __restrict__ bsum) {
    __shared__ int lds[256];
    int t = threadIdx.x;
    int base = blockIdx.x * 1024 + t * 4;
    int v0 = (base + 0 < NN) ? deg[base + 0] : 0;
    int v1 = (base + 1 < NN) ? deg[base + 1] : 0;
    int v2 = (base + 2 < NN) ? deg[base + 2] : 0;
    int v3 = (base + 3 < NN) ? deg[base + 3] : 0;
    int p0 = v0, p1 = p0 + v1, p2 = p1 + v2, p3 = p2 + v3;
    lds[t] = p3;
    __syncthreads();
    for (int off = 1; off < 256; off <<= 1) {
        int val = (t >= off) ? lds[t - off] : 0;
        __syncthreads();
        lds[t] += val;
        __syncthreads();
    }
    int prefix = (t > 0) ? lds[t - 1] : 0;
    if (base + 0 < NN) rowptr[base + 1] = prefix + p0;
    if (base + 1 < NN) rowptr[base + 2] = prefix + p1;
    if (base + 2 < NN) rowptr[base + 3] = prefix + p2;
    if (base + 3 < NN) rowptr[base + 4] = prefix + p3;
    if (t == 255) bsum[blockIdx.x] = lds[255];
}

// ---------------- scan step 2 ----------------
__global__ void scan2(int* __restrict__ bsum, int nblk) {
    if (threadIdx.x == 0 && blockIdx.x == 0) {
        int run = 0;
        for (int i = 0; i < nblk; i++) { int s = bsum[i]; bsum[i] = run; run += s; }
    }
}

// ---------------- scan step 3 ----------------
__global__ __launch_bounds__(256) void scan3(int* __restrict__ rowptr,
                                             const int* __restrict__ bsum,
                                             int* __restrict__ cursor) {
    int i = blockIdx.x * blockDim.x + threadIdx.x;
    if (i < NN) {
        int val = rowptr[i + 1] + bsum[i / 1024];
        rowptr[i + 1] = val;
        if (i + 1 < NN) cursor[i + 1] = val;
    }
    if (i == 0) { rowptr[0] = 0; cursor[0] = 0; }
}

// ---------------- scatter: group src indices by dst ----------------
__global__ void scatter_kernel(const int* __restrict__ ei, int* __restrict__ cursor,
                               int* __restrict__ srcs) {
    int e = blockIdx.x * blockDim.x + threadIdx.x;
    if (e >= NE) return;
    int dst = ei[NE + e];
    int pos = atomicAdd(&cursor[dst], 1);
    srcs[pos] = ei[e];
}

// ---------------- LayerNorm: one wave per row ----------------
__global__ void ln_kernel(const float* __restrict__ x, const float* __restrict__ g,
                          const float* __restrict__ b, float* __restrict__ y, int nrows) {
    int wave = (blockIdx.x * blockDim.x + threadIdx.x) >> 6;
    int lane = threadIdx.x & 63;
    if (wave >= nrows) return;
    const float* xr = x + (size_t)wave * HIDD;
    float v0 = xr[lane];
    float v1 = (lane < 32) ? xr[64 + lane] : 0.0f;
    float s = v0 + v1;
    float q = v0 * v0 + v1 * v1;
    for (int o = 32; o > 0; o >>= 1) {
        s += __shfl_xor(s, o);
        q += __shfl_xor(q, o);
    }
    float mean = s * (1.0f / 96.0f);
    float var = q * (1.0f / 96.0f) - mean * mean;
    float rs = rsqrtf(var + 1e-5f);
    float* yr = y + (size_t)wave * HIDD;
    yr[lane] = (v0 - mean) * rs * g[lane] + b[lane];
    if (lane < 32) yr[64 + lane] = (v1 - mean) * rs * g[64 + lane] + b[64 + lane];
}

// ---------------- Register-tiled fp32 GEMM ----------------
// C[row][col] = A[row][:] dot B[:][col] + bias[col] (+ epilogue)
// Tile: 64 rows x 96 cols, BK=32. 192 threads, 8x4 outputs each.
// EPI: 0 = bias only, 1 = bias+gelu, 2 = bias+residual (R, stride 96)
template<int K, int EPI>
__global__ __launch_bounds__(192) void gemm_tile(
    const float* __restrict__ A, const float* __restrict__ B,
    const float* __restrict__ bias, const float* __restrict__ R,
    float* __restrict__ C, int ldb, int ldc) {
    __shared__ float At[32][64];
    __shared__ float Bs[32][96];
    int t = threadIdx.x;
    int row0 = blockIdx.x * 64;
    int col0 = blockIdx.y * 96;
    int rowg = t / 24;   // 0..7
    int colg = t % 24;   // 0..23

    float acc[8][4];
#pragma unroll
    for (int i = 0; i < 8; i++)
#pragma unroll
        for (int j = 0; j < 4; j++) acc[i][j] = 0.0f;

    for (int kc = 0; kc < K; kc += 32) {
        // stage A chunk transposed: At[k][r]
        for (int i = t; i < 512; i += 192) {
            int r = i >> 3, k4 = i & 7;
            int row = row0 + r;
            float4 av = (row < NN) ? *(const float4*)&A[(size_t)row * K + kc + k4 * 4]
                                   : make_float4(0.f, 0.f, 0.f, 0.f);
            At[k4 * 4 + 0][r] = av.x;
            At[k4 * 4 + 1][r] = av.y;
            At[k4 * 4 + 2][r] = av.z;
            At[k4 * 4 + 3][r] = av.w;
        }
        // stage B chunk: Bs[k][c]
        for (int i = t; i < 768; i += 192) {
            int kk = i / 24, c4 = i % 24;
            float4 bv = *(const float4*)&B[(size_t)(kc + kk) * ldb + col0 + c4 * 4];
            *(float4*)&Bs[kk][c4 * 4] = bv;
        }
        __syncthreads();
#pragma unroll
        for (int kk = 0; kk < 32; kk++) {
            float4 a0 = *(const float4*)&At[kk][rowg * 8];
            float4 a1 = *(const float4*)&At[kk][rowg * 8 + 4];
            float4 b4 = *(const float4*)&Bs[kk][colg * 4];
            float av[8] = {a0.x, a0.y, a0.z, a0.w, a1.x, a1.y, a1.z, a1.w};
            float bv[4] = {b4.x, b4.y, b4.z, b4.w};
#pragma unroll
            for (int i = 0; i < 8; i++)
#pragma unroll
                for (int j = 0; j < 4; j++)
                    acc[i][j] += av[i] * bv[j];
        }
        __syncthreads();
    }

    int cbase = col0 + colg * 4;
    float4 bb = *(const float4*)&bias[cbase];
#pragma unroll
    for (int i = 0; i < 8; i++) {
        int row = row0 + rowg * 8 + i;
        if (row < NN) {
            float4 o;
            o.x = acc[i][0] + bb.x;
            o.y = acc[i][1] + bb.y;
            o.z = acc[i][2] + bb.z;
            o.w = acc[i][3] + bb.w;
            if (EPI == 1) {
                o.x = 0.5f * o.x * (1.0f + erff(o.x * 0.70710678118654752f));
                o.y = 0.5f * o.y * (1.0f + erff(o.y * 0.70710678118654752f));
                o.z = 0.5f * o.z * (1.0f + erff(o.z * 0.70710678118654752f));
                o.w = 0.5f * o.w * (1.0f + erff(o.w * 0.70710678118654752f));
            } else if (EPI == 2) {
                float4 rv = *(const float4*)&R[(size_t)row * 96 + cbase];
                o.x += rv.x; o.y += rv.y; o.z += rv.z; o.w += rv.w;
            }
            *(float4*)&C[(size_t)row * ldc + cbase] = o;
        }
    }
}

// ---------------- Sparse attention gather: one wave per dst node ----------------
__global__ __launch_bounds__(256) void attn_gather(
    const float* __restrict__ q, const float* __restrict__ k,
    const float* __restrict__ v, const int* __restrict__ rowptr,
    const int* __restrict__ srcs, float* __restrict__ a) {
    int wave = (blockIdx.x * blockDim.x + threadIdx.x) >> 6;
    int lane = threadIdx.x & 63;
    if (wave >= NN) return;
    int dst = wave;
    int h = lane & 7;
    int eslot = lane >> 3;
    const float4* qp = (const float4*)(q + (size_t)dst * HIDD + h * HD);
    float4 q0 = qp[0], q1 = qp[1], q2 = qp[2];
    int beg = rowptr[dst], end = rowptr[dst + 1];
    float4 a0 = {0, 0, 0, 0}, a1 = {0, 0, 0, 0}, a2 = {0, 0, 0, 0};
    float zz = 0.0f;
    for (int e = beg + eslot; e < end; e += 8) {
        int src = srcs[e];
        const float4* kp = (const float4*)(k + (size_t)src * HIDD + h * HD);
        float4 k0 = kp[0], k1 = kp[1], k2 = kp[2];
        float dot = k0.x * q0.x + k0.y * q0.y + k0.z * q0.z + k0.w * q0.w
                  + k1.x * q1.x + k1.y * q1.y + k1.z * q1.z + k1.w * q1.w
                  + k2.x * q2.x + k2.y * q2.y + k2.z * q2.z + k2.w * q2.w;
        float s = fminf(fmaxf(dot * INV_SCALE, -5.0f), 5.0f);
        float sc = expf(s);
        const float4* vp = (const float4*)(v + (size_t)src * HIDD + h * HD);
        float4 v0 = vp[0], v1 = vp[1], v2 = vp[2];
        a0.x += v0.x * sc; a0.y += v0.y * sc; a0.z += v0.z * sc; a0.w += v0.w * sc;
        a1.x += v1.x * sc; a1.y += v1.y * sc; a1.z += v1.z * sc; a1.w += v1.w * sc;
        a2.x += v2.x * sc; a2.y += v2.y * sc; a2.z += v2.z * sc; a2.w += v2.w * sc;
        zz += sc;
    }
#pragma unroll
    for (int m = 8; m < 64; m <<= 1) {
        a0.x += __shfl_xor(a0.x, m); a0.y += __shfl_xor(a0.y, m);
        a0.z += __shfl_xor(a0.z, m); a0.w += __shfl_xor(a0.w, m);
        a1.x += __shfl_xor(a1.x, m); a1.y += __shfl_xor(a1.y, m);
        a1.z += __shfl_xor(a1.z, m); a1.w += __shfl_xor(a1.w, m);
        a2.x += __shfl_xor(a2.x, m); a2.y += __shfl_xor(a2.y, m);
        a2.z += __shfl_xor(a2.z, m); a2.w += __shfl_xor(a2.w, m);
        zz += __shfl_xor(zz, m);
    }
    if (eslot == 0) {
        float inv = 1.0f / (zz + 1e-6f);
        a0.x *= inv; a0.y *= inv; a0.z *= inv; a0.w *= inv;
        a1.x *= inv; a1.y *= inv; a1.z *= inv; a1.w *= inv;
        a2.x *= inv; a2.y *= inv; a2.z *= inv; a2.w *= inv;
        float4* ar = (float4*)(a + (size_t)dst * HIDD + h * HD);
        ar[0] = a0; ar[1] = a1; ar[2] = a2;
    }
}

extern "C" void kernel_launch(void* const* d_in, const int* in_sizes, int n_in,
                              void* d_out, int out_size, void* d_ws, size_t ws_size,
                              hipStream_t stream) {
    const float* x     = (const float*)d_in[0];
    const int*   ei    = (const int*)d_in[1];
    const float* ln1_g = (const float*)d_in[2];
    const float* ln1_b = (const float*)d_in[3];
    const float* Wq    = (const float*)d_in[4];
    const float* bq    = (const float*)d_in[5];
    const float* Wk    = (const float*)d_in[6];
    const float* bk    = (const float*)d_in[7];
    const float* Wv    = (const float*)d_in[8];
    const float* bv    = (const float*)d_in[9];
    const float* Wo    = (const float*)d_in[10];
    const float* bo    = (const float*)d_in[11];
    const float* ln2_g = (const float*)d_in[12];
    const float* ln2_b = (const float*)d_in[13];
    const float* W1    = (const float*)d_in[14];
    const float* b1    = (const float*)d_in[15];
    const float* W2    = (const float*)d_in[16];
    const float* b2    = (const float*)d_in[17];
    float* out = (float*)d_out;

    // Workspace layout (floats):
    //   q [0,4.8M)  k [4.8M,9.6M)  v [9.6M,14.4M)  a [14.4M,19.2M)
    //   h aliases [0,19.2M)   x2 [19.2M,24M)   ybuf [24M,28.8M)
    // CSR ints alias x2's region (dead before proj writes x2)
    float* ws = (float*)d_ws;
    const size_t NF = (size_t)NN * HIDD;   // 4.8M
    float* q    = ws;
    float* k    = ws + NF;
    float* v    = ws + 2 * NF;
    float* a    = ws + 3 * NF;
    float* h    = ws;                       // aliases q..a
    float* x2   = ws + 4 * NF;
    float* ybuf = ws + 5 * NF;

    int* ibase  = (int*)(ws + 4 * NF);      // aliases x2
    int* deg    = ibase;                    // NN
    int* rowptr = ibase + NN;               // NN+1
    int* cursor = ibase + 2 * NN + 1;       // NN
    int* srcs   = ibase + 3 * NN + 1;       // NE
    int* bsum   = ibase + 3 * NN + 1 + NE;  // 64

    const int MT = (NN + 63) / 64;          // 782
    const int SCAN_BLOCKS = (NN + 1023) / 1024;  // 49

    // --- CSR build ---
    zero_kernel<<<(NN + 255) / 256, 256, 0, stream>>>(deg, NN);
    deg_hist<<<(NE + 255) / 256, 256, 0, stream>>>(ei, deg);
    scan1<<<SCAN_BLOCKS, 256, 0, stream>>>(deg, rowptr, bsum);
    scan2<<<1, 64, 0, stream>>>(bsum, SCAN_BLOCKS);
    scan3<<<(NN + 255) / 256, 256, 0, stream>>>(rowptr, bsum, cursor);
    scatter_kernel<<<(NE + 255) / 256, 256, 0, stream>>>(ei, cursor, srcs);

    // --- transformer block ---
    ln_kernel<<<(NN + 3) / 4, 256, 0, stream>>>(x, ln1_g, ln1_b, ybuf, NN);
    gemm_tile<96, 0><<<MT, 192, 0, stream>>>(ybuf, Wq, bq, nullptr, q, 96, 96);
    gemm_tile<96, 0><<<MT, 192, 0, stream>>>(ybuf, Wk, bk, nullptr, k, 96, 96);
    gemm_tile<96, 0><<<MT, 192, 0, stream>>>(ybuf, Wv, bv, nullptr, v, 96, 96);
    attn_gather<<<(NN + 3) / 4, 256, 0, stream>>>(q, k, v, rowptr, srcs, a);
    gemm_tile<96, 2><<<MT, 192, 0, stream>>>(a, Wo, bo, x, x2, 96, 96);
    ln_kernel<<<(NN + 3) / 4, 256, 0, stream>>>(x2, ln2_g, ln2_b, ybuf, NN);
    {
        dim3 g(MT, 4);
        gemm_tile<96, 1><<<g, 192, 0, stream>>>(ybuf, W1, b1, nullptr, h, FFND, FFND);
    }
    gemm_tile<384, 2><<<MT, 192, 0, stream>>>(h, W2, b2, x2, out, 96, 96);
}

// Round 4
// 309.315 us; speedup vs baseline: 12.6411x; 1.4805x over previous
//
#include <hip/hip_runtime.h>
#include <hip/hip_bf16.h>
#include <math.h>

#define NN 50000
#define HIDD 96
#define NH 8
#define HD 12
#define FFND 384
#define NE 800000

#define INV_SCALE 0.28867513459481287f

typedef short short8 __attribute__((ext_vector_type(8)));
typedef float f32x4 __attribute__((ext_vector_type(4)));

// ---------------- zero kernel ----------------
__global__ void zero_kernel(int* __restrict__ p, int n) {
    int i = blockIdx.x * blockDim.x + threadIdx.x;
    if (i < n) p[i] = 0;
}

// ---------------- degree histogram ----------------
__global__ void deg_hist(const int* __restrict__ ei, int* __restrict__ deg) {
    int e = blockIdx.x * blockDim.x + threadIdx.x;
    if (e < NE) atomicAdd(&deg[ei[NE + e]], 1);
}

// ---------------- scan step 1 ----------------
__global__ __launch_bounds__(256) void scan1(const int* __restrict__ deg,
                                             int* __restrict__ rowptr,
                                             int* __restrict__ bsum) {
    __shared__ int lds[256];
    int t = threadIdx.x;
    int base = blockIdx.x * 1024 + t * 4;
    int v0 = (base + 0 < NN) ? deg[base + 0] : 0;
    int v1 = (base + 1 < NN) ? deg[base + 1] : 0;
    int v2 = (base + 2 < NN) ? deg[base + 2] : 0;
    int v3 = (base + 3 < NN) ? deg[base + 3] : 0;
    int p0 = v0, p1 = p0 + v1, p2 = p1 + v2, p3 = p2 + v3;
    lds[t] = p3;
    __syncthreads();
    for (int off = 1; off < 256; off <<= 1) {
        int val = (t >= off) ? lds[t - off] : 0;
        __syncthreads();
        lds[t] += val;
        __syncthreads();
    }
    int prefix = (t > 0) ? lds[t - 1] : 0;
    if (base + 0 < NN) rowptr[base + 1] = prefix + p0;
    if (base + 1 < NN) rowptr[base + 2] = prefix + p1;
    if (base + 2 < NN) rowptr[base + 3] = prefix + p2;
    if (base + 3 < NN) rowptr[base + 4] = prefix + p3;
    if (t == 255) bsum[blockIdx.x] = lds[255];
}

// ---------------- scan step 2 ----------------
__global__ void scan2(int* __restrict__ bsum, int nblk) {
    if (threadIdx.x == 0 && blockIdx.x == 0) {
        int run = 0;
        for (int i = 0; i < nblk; i++) { int s = bsum[i]; bsum[i] = run; run += s; }
    }
}

// ---------------- scan step 3 ----------------
__global__ __launch_bounds__(256) void scan3(int* __restrict__ rowptr,
                                             const int* __restrict__ bsum,
                                             int* __restrict__ cursor) {
    int i = blockIdx.x * blockDim.x + threadIdx.x;
    if (i < NN) {
        int val = rowptr[i + 1] + bsum[i / 1024];
        rowptr[i + 1] = val;
        if (i + 1 < NN) cursor[i + 1] = val;
    }
    if (i == 0) { rowptr[0] = 0; cursor[0] = 0; }
}

// ---------------- scatter: group src indices by dst ----------------
__global__ void scatter_kernel(const int* __restrict__ ei, int* __restrict__ cursor,
                               int* __restrict__ srcs) {
    int e = blockIdx.x * blockDim.x + threadIdx.x;
    if (e >= NE) return;
    int dst = ei[NE + e];
    int pos = atomicAdd(&cursor[dst], 1);
    srcs[pos] = ei[e];
}

// ---------------- weight convert+transpose to bf16: WT[n][k] = bf16(W[k][n]) ----------------
__global__ __launch_bounds__(256) void wconv(
    const float* __restrict__ Wq, const float* __restrict__ Wk,
    const float* __restrict__ Wv, const float* __restrict__ Wo,
    const float* __restrict__ W1, const float* __restrict__ W2,
    __hip_bfloat16* __restrict__ dst) {
    int y = blockIdx.y;
    int i = blockIdx.x * 256 + threadIdx.x;
    const float* W; __hip_bfloat16* D; int K, N;
    if (y == 0)      { W = Wq; D = dst;                 K = 96;  N = 96;  }
    else if (y == 1) { W = Wk; D = dst + 9216;          K = 96;  N = 96;  }
    else if (y == 2) { W = Wv; D = dst + 18432;         K = 96;  N = 96;  }
    else if (y == 3) { W = Wo; D = dst + 27648;         K = 96;  N = 96;  }
    else if (y == 4) { W = W1; D = dst + 36864;         K = 96;  N = 384; }
    else             { W = W2; D = dst + 36864 + 36864; K = 384; N = 96;  }
    if (i < K * N) {
        int n = i / K, k = i % K;
        D[i] = __float2bfloat16(W[k * N + n]);
    }
}

// ---------------- LayerNorm: one wave per row, bf16 output ----------------
__global__ void ln_kernel(const float* __restrict__ x, const float* __restrict__ g,
                          const float* __restrict__ b, __hip_bfloat16* __restrict__ y,
                          int nrows) {
    int wave = (blockIdx.x * blockDim.x + threadIdx.x) >> 6;
    int lane = threadIdx.x & 63;
    if (wave >= nrows) return;
    const float* xr = x + (size_t)wave * HIDD;
    float v0 = xr[lane];
    float v1 = (lane < 32) ? xr[64 + lane] : 0.0f;
    float s = v0 + v1;
    float q = v0 * v0 + v1 * v1;
    for (int o = 32; o > 0; o >>= 1) {
        s += __shfl_xor(s, o);
        q += __shfl_xor(q, o);
    }
    float mean = s * (1.0f / 96.0f);
    float var = q * (1.0f / 96.0f) - mean * mean;
    float rs = rsqrtf(var + 1e-5f);
    __hip_bfloat16* yr = y + (size_t)wave * HIDD;
    yr[lane] = __float2bfloat16((v0 - mean) * rs * g[lane] + b[lane]);
    if (lane < 32)
        yr[64 + lane] = __float2bfloat16((v1 - mean) * rs * g[64 + lane] + b[64 + lane]);
}

// ---------------- MFMA GEMM body ----------------
// C[M x ldc] = A[M x K](bf16) @ BT[N x K](bf16)^T + bias (+ epilogue)
// Block: 256 thr = 4 waves, each wave 16 rows x 96 cols (6 mfma tiles).
// A-frag: lane reads A[row0 + (lane&15)][kc + (lane>>4)*8 ..+7]  (16B)
// B-frag: lane reads BT[col0+ct*16+(lane&15)][kc + (lane>>4)*8 ..+7]
// C/D:    col = lane&15, row = (lane>>4)*4 + reg    [m89-verified]
template<int K, int EPI, bool OBF>
__device__ __forceinline__ void gemm_body(
    const __hip_bfloat16* __restrict__ A, const __hip_bfloat16* __restrict__ BT,
    const float* __restrict__ bias, const float* __restrict__ R,
    void* __restrict__ Cptr, int ldc, int col0) {
    int lane = threadIdx.x & 63;
    int wave = threadIdx.x >> 6;
    int row0 = blockIdx.x * 64 + wave * 16;
    if (row0 >= NN) return;                 // NN % 16 == 0: all-or-nothing strips
    int lr = lane & 15, kg = lane >> 4;
    const __hip_bfloat16* Ar = A + (size_t)(row0 + lr) * K + kg * 8;
    f32x4 acc[6];
#pragma unroll
    for (int ct = 0; ct < 6; ct++) acc[ct] = (f32x4){0.f, 0.f, 0.f, 0.f};
#pragma unroll
    for (int kc = 0; kc < K; kc += 32) {
        short8 af = *(const short8*)(Ar + kc);
#pragma unroll
        for (int ct = 0; ct < 6; ct++) {
            short8 bf_ = *(const short8*)(BT + (size_t)(col0 + ct * 16 + lr) * K + kc + kg * 8);
            acc[ct] = __builtin_amdgcn_mfma_f32_16x16x32_bf16(af, bf_, acc[ct], 0, 0, 0);
        }
    }
    int crow = row0 + kg * 4;
#pragma unroll
    for (int ct = 0; ct < 6; ct++) {
        int col = col0 + ct * 16 + lr;
        float bb = bias[col];
#pragma unroll
        for (int r = 0; r < 4; r++) {
            float o = acc[ct][r] + bb;
            if (EPI == 1)
                o = 0.5f * o * (1.0f + erff(o * 0.70710678118654752f));
            if (EPI == 2)
                o += R[(size_t)(crow + r) * 96 + col];
            if (OBF)
                ((__hip_bfloat16*)Cptr)[(size_t)(crow + r) * ldc + col] = __float2bfloat16(o);
            else
                ((float*)Cptr)[(size_t)(crow + r) * ldc + col] = o;
        }
    }
}

template<int K, int EPI, bool OBF>
__global__ __launch_bounds__(256) void mfma_gemm(
    const __hip_bfloat16* __restrict__ A, const __hip_bfloat16* __restrict__ BT,
    const float* __restrict__ bias, const float* __restrict__ R,
    void* __restrict__ Cptr, int ldc) {
    gemm_body<K, EPI, OBF>(A, BT, bias, R, Cptr, ldc, blockIdx.y * 96);
}

// fused q/k/v: blockIdx.y selects weight slab / bias / output buffer
__global__ __launch_bounds__(256) void qkv_mfma(
    const __hip_bfloat16* __restrict__ A, const __hip_bfloat16* __restrict__ wbuf,
    const float* __restrict__ bq, const float* __restrict__ bk,
    const float* __restrict__ bv, float* __restrict__ q) {
    int y = blockIdx.y;
    const __hip_bfloat16* BT = wbuf + y * 9216;
    const float* bias = (y == 0) ? bq : (y == 1) ? bk : bv;
    float* outp = q + (size_t)y * NN * HIDD;
    gemm_body<96, 0, false>(A, BT, bias, nullptr, outp, 96, 0);
}

// ---------------- Sparse attention gather: one wave per dst node, bf16 a-out ----------------
__global__ __launch_bounds__(256) void attn_gather(
    const float* __restrict__ q, const float* __restrict__ k,
    const float* __restrict__ v, const int* __restrict__ rowptr,
    const int* __restrict__ srcs, __hip_bfloat16* __restrict__ abf) {
    int wave = (blockIdx.x * blockDim.x + threadIdx.x) >> 6;
    int lane = threadIdx.x & 63;
    if (wave >= NN) return;
    int dst = wave;
    int h = lane & 7;
    int eslot = lane >> 3;
    const float4* qp = (const float4*)(q + (size_t)dst * HIDD + h * HD);
    float4 q0 = qp[0], q1 = qp[1], q2 = qp[2];
    int beg = rowptr[dst], end = rowptr[dst + 1];
    float4 a0 = {0, 0, 0, 0}, a1 = {0, 0, 0, 0}, a2 = {0, 0, 0, 0};
    float zz = 0.0f;
    for (int e = beg + eslot; e < end; e += 8) {
        int src = srcs[e];
        const float4* kp = (const float4*)(k + (size_t)src * HIDD + h * HD);
        float4 k0 = kp[0], k1 = kp[1], k2 = kp[2];
        float dot = k0.x * q0.x + k0.y * q0.y + k0.z * q0.z + k0.w * q0.w
                  + k1.x * q1.x + k1.y * q1.y + k1.z * q1.z + k1.w * q1.w
                  + k2.x * q2.x + k2.y * q2.y + k2.z * q2.z + k2.w * q2.w;
        float s = fminf(fmaxf(dot * INV_SCALE, -5.0f), 5.0f);
        float sc = expf(s);
        const float4* vp = (const float4*)(v + (size_t)src * HIDD + h * HD);
        float4 v0 = vp[0], v1 = vp[1], v2 = vp[2];
        a0.x += v0.x * sc; a0.y += v0.y * sc; a0.z += v0.z * sc; a0.w += v0.w * sc;
        a1.x += v1.x * sc; a1.y += v1.y * sc; a1.z += v1.z * sc; a1.w += v1.w * sc;
        a2.x += v2.x * sc; a2.y += v2.y * sc; a2.z += v2.z * sc; a2.w += v2.w * sc;
        zz += sc;
    }
#pragma unroll
    for (int m = 8; m < 64; m <<= 1) {
        a0.x += __shfl_xor(a0.x, m); a0.y += __shfl_xor(a0.y, m);
        a0.z += __shfl_xor(a0.z, m); a0.w += __shfl_xor(a0.w, m);
        a1.x += __shfl_xor(a1.x, m); a1.y += __shfl_xor(a1.y, m);
        a1.z += __shfl_xor(a1.z, m); a1.w += __shfl_xor(a1.w, m);
        a2.x += __shfl_xor(a2.x, m); a2.y += __shfl_xor(a2.y, m);
        a2.z += __shfl_xor(a2.z, m); a2.w += __shfl_xor(a2.w, m);
        zz += __shfl_xor(zz, m);
    }
    if (eslot == 0) {
        float inv = 1.0f / (zz + 1e-6f);
        __hip_bfloat16* ar = abf + (size_t)dst * HIDD + h * HD;
        ar[0]  = __float2bfloat16(a0.x * inv);
        ar[1]  = __float2bfloat16(a0.y * inv);
        ar[2]  = __float2bfloat16(a0.z * inv);
        ar[3]  = __float2bfloat16(a0.w * inv);
        ar[4]  = __float2bfloat16(a1.x * inv);
        ar[5]  = __float2bfloat16(a1.y * inv);
        ar[6]  = __float2bfloat16(a1.z * inv);
        ar[7]  = __float2bfloat16(a1.w * inv);
        ar[8]  = __float2bfloat16(a2.x * inv);
        ar[9]  = __float2bfloat16(a2.y * inv);
        ar[10] = __float2bfloat16(a2.z * inv);
        ar[11] = __float2bfloat16(a2.w * inv);
    }
}

extern "C" void kernel_launch(void* const* d_in, const int* in_sizes, int n_in,
                              void* d_out, int out_size, void* d_ws, size_t ws_size,
                              hipStream_t stream) {
    const float* x     = (const float*)d_in[0];
    const int*   ei    = (const int*)d_in[1];
    const float* ln1_g = (const float*)d_in[2];
    const float* ln1_b = (const float*)d_in[3];
    const float* Wq    = (const float*)d_in[4];
    const float* bq    = (const float*)d_in[5];
    const float* Wk    = (const float*)d_in[6];
    const float* bk    = (const float*)d_in[7];
    const float* Wv    = (const float*)d_in[8];
    const float* bv    = (const float*)d_in[9];
    const float* Wo    = (const float*)d_in[10];
    const float* bo    = (const float*)d_in[11];
    const float* ln2_g = (const float*)d_in[12];
    const float* ln2_b = (const float*)d_in[13];
    const float* W1    = (const float*)d_in[14];
    const float* b1    = (const float*)d_in[15];
    const float* W2    = (const float*)d_in[16];
    const float* b2    = (const float*)d_in[17];
    float* out = (float*)d_out;

    // Workspace layout (float units, NF = NN*96 = 4.8M):
    //   q [0,NF)  k [NF,2NF)  v [2NF,3NF)                    fp32
    //   abf: bf16 at 3NF (NN*96 bf16 = 0.5NF floats)
    //   hbf: bf16 at 0 (NN*384 bf16 = 2NF floats) — aliases q,k (dead)
    //   x2 [4NF,5NF) fp32;  CSR ints alias x2 (dead before proj writes)
    //   ybf: bf16 at 5NF (0.5NF floats)
    //   weights bf16 at 5.5NF: WqT,WkT,WvT,WoT (9216 ea), W1T(36864), W2T(36864)
    float* ws = (float*)d_ws;
    const size_t NF = (size_t)NN * HIDD;
    float* q  = ws;
    float* k  = ws + NF;
    float* v  = ws + 2 * NF;
    __hip_bfloat16* abf = (__hip_bfloat16*)(ws + 3 * NF);
    __hip_bfloat16* hbf = (__hip_bfloat16*)ws;
    float* x2 = ws + 4 * NF;
    __hip_bfloat16* ybf = (__hip_bfloat16*)(ws + 5 * NF);
    __hip_bfloat16* wbuf = (__hip_bfloat16*)(ws + 5 * NF + NF / 2);
    __hip_bfloat16* WoT = wbuf + 27648;
    __hip_bfloat16* W1T = wbuf + 36864;
    __hip_bfloat16* W2T = wbuf + 73728;

    int* ibase  = (int*)(ws + 4 * NF);      // aliases x2
    int* deg    = ibase;
    int* rowptr = ibase + NN;
    int* cursor = ibase + 2 * NN + 1;
    int* srcs   = ibase + 3 * NN + 1;
    int* bsum   = ibase + 3 * NN + 1 + NE;

    const int MT = (NN + 63) / 64;               // 782
    const int SCAN_BLOCKS = (NN + 1023) / 1024;  // 49

    // --- CSR build ---
    zero_kernel<<<(NN + 255) / 256, 256, 0, stream>>>(deg, NN);
    deg_hist<<<(NE + 255) / 256, 256, 0, stream>>>(ei, deg);
    scan1<<<SCAN_BLOCKS, 256, 0, stream>>>(deg, rowptr, bsum);
    scan2<<<1, 64, 0, stream>>>(bsum, SCAN_BLOCKS);
    scan3<<<(NN + 255) / 256, 256, 0, stream>>>(rowptr, bsum, cursor);
    scatter_kernel<<<(NE + 255) / 256, 256, 0, stream>>>(ei, cursor, srcs);

    // --- weights -> bf16 transposed ---
    {
        dim3 g((36864 + 255) / 256, 6);
        wconv<<<g, 256, 0, stream>>>(Wq, Wk, Wv, Wo, W1, W2, wbuf);
    }

    // --- transformer block ---
    ln_kernel<<<(NN + 3) / 4, 256, 0, stream>>>(x, ln1_g, ln1_b, ybf, NN);
    {
        dim3 g(MT, 3);
        qkv_mfma<<<g, 256, 0, stream>>>(ybf, wbuf, bq, bk, bv, q);
    }
    attn_gather<<<(NN + 3) / 4, 256, 0, stream>>>(q, k, v, rowptr, srcs, abf);
    mfma_gemm<96, 2, false><<<MT, 256, 0, stream>>>(abf, WoT, bo, x, x2, 96);
    ln_kernel<<<(NN + 3) / 4, 256, 0, stream>>>(x2, ln2_g, ln2_b, ybf, NN);
    {
        dim3 g(MT, 4);
        mfma_gemm<96, 1, true><<<g, 256, 0, stream>>>(ybf, W1T, b1, nullptr, hbf, FFND);
    }
    mfma_gemm<384, 2, false><<<MT, 256, 0, stream>>>(hbf, W2T, b2, x2, out, 96);
}

// Round 5
// 268.081 us; speedup vs baseline: 14.5854x; 1.1538x over previous
//
#include <hip/hip_runtime.h>
#include <hip/hip_bf16.h>
#include <math.h>

#define NN 50000
#define HIDD 96
#define NH 8
#define HD 12
#define FFND 384
#define NE 800000

#define INV_SCALE 0.28867513459481287f

typedef short short8 __attribute__((ext_vector_type(8)));
typedef unsigned short ushort8 __attribute__((ext_vector_type(8)));
typedef float f32x4 __attribute__((ext_vector_type(4)));

__device__ __forceinline__ float bf2f(unsigned short u) {
    union { unsigned int i; float f; } c;
    c.i = ((unsigned int)u) << 16;
    return c.f;
}

// ---------------- zero kernel ----------------
__global__ void zero_kernel(int* __restrict__ p, int n) {
    int i = blockIdx.x * blockDim.x + threadIdx.x;
    if (i < n) p[i] = 0;
}

// ---------------- degree histogram ----------------
__global__ void deg_hist(const int* __restrict__ ei, int* __restrict__ deg) {
    int e = blockIdx.x * blockDim.x + threadIdx.x;
    if (e < NE) atomicAdd(&deg[ei[NE + e]], 1);
}

// ---------------- scan step 1 ----------------
__global__ __launch_bounds__(256) void scan1(const int* __restrict__ deg,
                                             int* __restrict__ rowptr,
                                             int* __restrict__ bsum) {
    __shared__ int lds[256];
    int t = threadIdx.x;
    int base = blockIdx.x * 1024 + t * 4;
    int v0 = (base + 0 < NN) ? deg[base + 0] : 0;
    int v1 = (base + 1 < NN) ? deg[base + 1] : 0;
    int v2 = (base + 2 < NN) ? deg[base + 2] : 0;
    int v3 = (base + 3 < NN) ? deg[base + 3] : 0;
    int p0 = v0, p1 = p0 + v1, p2 = p1 + v2, p3 = p2 + v3;
    lds[t] = p3;
    __syncthreads();
    for (int off = 1; off < 256; off <<= 1) {
        int val = (t >= off) ? lds[t - off] : 0;
        __syncthreads();
        lds[t] += val;
        __syncthreads();
    }
    int prefix = (t > 0) ? lds[t - 1] : 0;
    if (base + 0 < NN) rowptr[base + 1] = prefix + p0;
    if (base + 1 < NN) rowptr[base + 2] = prefix + p1;
    if (base + 2 < NN) rowptr[base + 3] = prefix + p2;
    if (base + 3 < NN) rowptr[base + 4] = prefix + p3;
    if (t == 255) bsum[blockIdx.x] = lds[255];
}

// ---------------- scan step 2 ----------------
__global__ void scan2(int* __restrict__ bsum, int nblk) {
    if (threadIdx.x == 0 && blockIdx.x == 0) {
        int run = 0;
        for (int i = 0; i < nblk; i++) { int s = bsum[i]; bsum[i] = run; run += s; }
    }
}

// ---------------- scan step 3 ----------------
__global__ __launch_bounds__(256) void scan3(int* __restrict__ rowptr,
                                             const int* __restrict__ bsum,
                                             int* __restrict__ cursor) {
    int i = blockIdx.x * blockDim.x + threadIdx.x;
    if (i < NN) {
        int val = rowptr[i + 1] + bsum[i / 1024];
        rowptr[i + 1] = val;
        if (i + 1 < NN) cursor[i + 1] = val;
    }
    if (i == 0) { rowptr[0] = 0; cursor[0] = 0; }
}

// ---------------- scatter: group src indices by dst ----------------
__global__ void scatter_kernel(const int* __restrict__ ei, int* __restrict__ cursor,
                               int* __restrict__ srcs) {
    int e = blockIdx.x * blockDim.x + threadIdx.x;
    if (e >= NE) return;
    int dst = ei[NE + e];
    int pos = atomicAdd(&cursor[dst], 1);
    srcs[pos] = ei[e];
}

// ---------------- weight convert+transpose to bf16: WT[n][k] = bf16(W[k][n]) ----------------
__global__ __launch_bounds__(256) void wconv(
    const float* __restrict__ Wq, const float* __restrict__ Wk,
    const float* __restrict__ Wv, const float* __restrict__ Wo,
    const float* __restrict__ W1, const float* __restrict__ W2,
    __hip_bfloat16* __restrict__ dst) {
    int y = blockIdx.y;
    int i = blockIdx.x * 256 + threadIdx.x;
    const float* W; __hip_bfloat16* D; int K, N;
    if (y == 0)      { W = Wq; D = dst;                 K = 96;  N = 96;  }
    else if (y == 1) { W = Wk; D = dst + 9216;          K = 96;  N = 96;  }
    else if (y == 2) { W = Wv; D = dst + 18432;         K = 96;  N = 96;  }
    else if (y == 3) { W = Wo; D = dst + 27648;         K = 96;  N = 96;  }
    else if (y == 4) { W = W1; D = dst + 36864;         K = 96;  N = 384; }
    else             { W = W2; D = dst + 36864 + 36864; K = 384; N = 96;  }
    if (i < K * N) {
        int n = i / K, k = i % K;
        D[i] = __float2bfloat16(W[k * N + n]);
    }
}

// ---------------- LayerNorm: one wave per row, bf16 output ----------------
__global__ void ln_kernel(const float* __restrict__ x, const float* __restrict__ g,
                          const float* __restrict__ b, __hip_bfloat16* __restrict__ y,
                          int nrows) {
    int wave = (blockIdx.x * blockDim.x + threadIdx.x) >> 6;
    int lane = threadIdx.x & 63;
    if (wave >= nrows) return;
    const float* xr = x + (size_t)wave * HIDD;
    float v0 = xr[lane];
    float v1 = (lane < 32) ? xr[64 + lane] : 0.0f;
    float s = v0 + v1;
    float q = v0 * v0 + v1 * v1;
    for (int o = 32; o > 0; o >>= 1) {
        s += __shfl_xor(s, o);
        q += __shfl_xor(q, o);
    }
    float mean = s * (1.0f / 96.0f);
    float var = q * (1.0f / 96.0f) - mean * mean;
    float rs = rsqrtf(var + 1e-5f);
    __hip_bfloat16* yr = y + (size_t)wave * HIDD;
    yr[lane] = __float2bfloat16((v0 - mean) * rs * g[lane] + b[lane]);
    if (lane < 32)
        yr[64 + lane] = __float2bfloat16((v1 - mean) * rs * g[64 + lane] + b[64 + lane]);
}

// ---------------- MFMA GEMM body ----------------
// C = A[M x K](bf16) @ BT[N x K]^T + bias (+ epilogue)
// Block: 256 thr = 4 waves, each wave 16 rows x 96 cols (6 mfma tiles).
// C/D frag: col = lane&15, row = (lane>>4)*4 + reg   [m89-verified]
// SMODE: 0 = fp32 flat, 1 = bf16 flat, 2 = bf16 kv-interleaved (+koff)
template<int K, int EPI, int SMODE>
__device__ __forceinline__ void gemm_body(
    const __hip_bfloat16* __restrict__ A, const __hip_bfloat16* __restrict__ BT,
    const float* __restrict__ bias, const float* __restrict__ R,
    void* __restrict__ Cptr, int ldc, int col0, int koff) {
    int lane = threadIdx.x & 63;
    int wave = threadIdx.x >> 6;
    int row0 = blockIdx.x * 64 + wave * 16;
    if (row0 >= NN) return;                 // NN % 16 == 0
    int lr = lane & 15, kg = lane >> 4;
    const __hip_bfloat16* Ar = A + (size_t)(row0 + lr) * K + kg * 8;
    f32x4 acc[6];
#pragma unroll
    for (int ct = 0; ct < 6; ct++) acc[ct] = (f32x4){0.f, 0.f, 0.f, 0.f};
#pragma unroll
    for (int kc = 0; kc < K; kc += 32) {
        short8 af = *(const short8*)(Ar + kc);
#pragma unroll
        for (int ct = 0; ct < 6; ct++) {
            short8 bf_ = *(const short8*)(BT + (size_t)(col0 + ct * 16 + lr) * K + kc + kg * 8);
            acc[ct] = __builtin_amdgcn_mfma_f32_16x16x32_bf16(af, bf_, acc[ct], 0, 0, 0);
        }
    }
    int crow = row0 + kg * 4;
#pragma unroll
    for (int ct = 0; ct < 6; ct++) {
        int col = col0 + ct * 16 + lr;
        float bb = bias[col];
#pragma unroll
        for (int r = 0; r < 4; r++) {
            float o = acc[ct][r] + bb;
            if (EPI == 1)
                o = 0.5f * o * (1.0f + erff(o * 0.70710678118654752f));
            if (EPI == 2)
                o += R[(size_t)(crow + r) * 96 + col];
            if (SMODE == 0)
                ((float*)Cptr)[(size_t)(crow + r) * ldc + col] = o;
            else if (SMODE == 1)
                ((__hip_bfloat16*)Cptr)[(size_t)(crow + r) * ldc + col] = __float2bfloat16(o);
            else
                ((__hip_bfloat16*)Cptr)[(size_t)(crow + r) * 192 + (col / 12) * 24 + koff + (col % 12)]
                    = __float2bfloat16(o);
        }
    }
}

template<int K, int EPI, int SMODE>
__global__ __launch_bounds__(256) void mfma_gemm(
    const __hip_bfloat16* __restrict__ A, const __hip_bfloat16* __restrict__ BT,
    const float* __restrict__ bias, const float* __restrict__ R,
    void* __restrict__ Cptr, int ldc) {
    gemm_body<K, EPI, SMODE>(A, BT, bias, R, Cptr, ldc, blockIdx.y * 96, 0);
}

// fused q/k/v: blockIdx.y selects weight slab / bias / output layout
__global__ __launch_bounds__(256) void qkv_mfma(
    const __hip_bfloat16* __restrict__ A, const __hip_bfloat16* __restrict__ wbuf,
    const float* __restrict__ bq, const float* __restrict__ bk,
    const float* __restrict__ bv,
    __hip_bfloat16* __restrict__ qbf, __hip_bfloat16* __restrict__ kv) {
    int y = blockIdx.y;
    if (y == 0)
        gemm_body<96, 0, 1>(A, wbuf, bq, nullptr, qbf, 96, 0, 0);
    else if (y == 1)
        gemm_body<96, 0, 2>(A, wbuf + 9216, bk, nullptr, kv, 0, 0, 0);
    else
        gemm_body<96, 0, 2>(A, wbuf + 18432, bv, nullptr, kv, 0, 0, 12);
}

// ---------------- Sparse attention gather (bf16 kv interleaved) ----------------
// one wave per dst; lane: h = lane&7, eslot = lane>>3
// kv row: [node][h][k0..k11, v0..v11] -> lane reads 48B contiguous, 16B-aligned
__global__ __launch_bounds__(256) void attn_gather(
    const __hip_bfloat16* __restrict__ qbf, const __hip_bfloat16* __restrict__ kv,
    const int* __restrict__ rowptr, const int* __restrict__ srcs,
    __hip_bfloat16* __restrict__ abf) {
    int wave = (blockIdx.x * blockDim.x + threadIdx.x) >> 6;
    int lane = threadIdx.x & 63;
    if (wave >= NN) return;
    int dst = wave;
    int h = lane & 7;
    int eslot = lane >> 3;
    // q head: 12 bf16, 8B-aligned
    float qf[12];
    {
        const uint2* qp = (const uint2*)(qbf + (size_t)dst * HIDD + h * HD);
        uint2 u0 = qp[0], u1 = qp[1], u2 = qp[2];
        unsigned int w[6] = {u0.x, u0.y, u1.x, u1.y, u2.x, u2.y};
#pragma unroll
        for (int i = 0; i < 6; i++) {
            qf[2 * i]     = bf2f((unsigned short)(w[i] & 0xffffu));
            qf[2 * i + 1] = bf2f((unsigned short)(w[i] >> 16));
        }
    }
    int beg = rowptr[dst], end = rowptr[dst + 1];
    float acc[12];
#pragma unroll
    for (int i = 0; i < 12; i++) acc[i] = 0.0f;
    float zz = 0.0f;
    for (int e = beg + eslot; e < end; e += 8) {
        int src = srcs[e];
        const ushort8* kp = (const ushort8*)(kv + (size_t)src * 192 + h * 24);
        ushort8 A = kp[0], B = kp[1], C = kp[2];
        float dot = 0.0f;
#pragma unroll
        for (int i = 0; i < 8; i++) dot += bf2f(A[i]) * qf[i];
#pragma unroll
        for (int i = 0; i < 4; i++) dot += bf2f(B[i]) * qf[8 + i];
        float s = fminf(fmaxf(dot * INV_SCALE, -5.0f), 5.0f);
        float sc = expf(s);
#pragma unroll
        for (int i = 0; i < 4; i++) acc[i] += bf2f(B[4 + i]) * sc;
#pragma unroll
        for (int i = 0; i < 8; i++) acc[4 + i] += bf2f(C[i]) * sc;
        zz += sc;
    }
#pragma unroll
    for (int m = 8; m < 64; m <<= 1) {
#pragma unroll
        for (int i = 0; i < 12; i++) acc[i] += __shfl_xor(acc[i], m);
        zz += __shfl_xor(zz, m);
    }
    if (eslot == 0) {
        float inv = 1.0f / (zz + 1e-6f);
        __hip_bfloat16* ar = abf + (size_t)dst * HIDD + h * HD;
#pragma unroll
        for (int i = 0; i < 12; i++) ar[i] = __float2bfloat16(acc[i] * inv);
    }
}

extern "C" void kernel_launch(void* const* d_in, const int* in_sizes, int n_in,
                              void* d_out, int out_size, void* d_ws, size_t ws_size,
                              hipStream_t stream) {
    const float* x     = (const float*)d_in[0];
    const int*   ei    = (const int*)d_in[1];
    const float* ln1_g = (const float*)d_in[2];
    const float* ln1_b = (const float*)d_in[3];
    const float* Wq    = (const float*)d_in[4];
    const float* bq    = (const float*)d_in[5];
    const float* Wk    = (const float*)d_in[6];
    const float* bk    = (const float*)d_in[7];
    const float* Wv    = (const float*)d_in[8];
    const float* bv    = (const float*)d_in[9];
    const float* Wo    = (const float*)d_in[10];
    const float* bo    = (const float*)d_in[11];
    const float* ln2_g = (const float*)d_in[12];
    const float* ln2_b = (const float*)d_in[13];
    const float* W1    = (const float*)d_in[14];
    const float* b1    = (const float*)d_in[15];
    const float* W2    = (const float*)d_in[16];
    const float* b2    = (const float*)d_in[17];
    float* out = (float*)d_out;

    // Workspace layout (float units, NF = NN*96 = 4.8M floats):
    //   qbf  bf16 [0, 0.5NF)
    //   kv   bf16 [0.5NF, 1.5NF)   (NN*192 bf16)
    //   abf  bf16 [1.5NF, 2NF)
    //   hbf  bf16 [0, 2NF)          aliases qbf/kv/abf (all dead by ffn1)
    //   x2   fp32 [2NF, 3NF)
    //   ybf  bf16 [3NF, 3.5NF)
    //   CSR ints at 3.5NF  (deg NN, rowptr NN+1, cursor NN, srcs NE, bsum 64)
    //   wbuf bf16 at 4NF   (110592 bf16)
    float* ws = (float*)d_ws;
    const size_t NF = (size_t)NN * HIDD;
    __hip_bfloat16* qbf = (__hip_bfloat16*)ws;
    __hip_bfloat16* kv  = (__hip_bfloat16*)(ws + NF / 2);
    __hip_bfloat16* abf = (__hip_bfloat16*)(ws + NF / 2 + NF);
    __hip_bfloat16* hbf = (__hip_bfloat16*)ws;
    float* x2 = ws + 2 * NF;
    __hip_bfloat16* ybf = (__hip_bfloat16*)(ws + 3 * NF);
    int* ibase  = (int*)(ws + 3 * NF + NF / 2);
    int* deg    = ibase;
    int* rowptr = ibase + NN;
    int* cursor = ibase + 2 * NN + 1;
    int* srcs   = ibase + 3 * NN + 1;
    int* bsum   = ibase + 3 * NN + 1 + NE;
    __hip_bfloat16* wbuf = (__hip_bfloat16*)(ws + 4 * NF);
    __hip_bfloat16* WoT = wbuf + 27648;
    __hip_bfloat16* W1T = wbuf + 36864;
    __hip_bfloat16* W2T = wbuf + 73728;

    const int MT = (NN + 63) / 64;               // 782
    const int SCAN_BLOCKS = (NN + 1023) / 1024;  // 49

    // --- CSR build ---
    zero_kernel<<<(NN + 255) / 256, 256, 0, stream>>>(deg, NN);
    deg_hist<<<(NE + 255) / 256, 256, 0, stream>>>(ei, deg);
    scan1<<<SCAN_BLOCKS, 256, 0, stream>>>(deg, rowptr, bsum);
    scan2<<<1, 64, 0, stream>>>(bsum, SCAN_BLOCKS);
    scan3<<<(NN + 255) / 256, 256, 0, stream>>>(rowptr, bsum, cursor);
    scatter_kernel<<<(NE + 255) / 256, 256, 0, stream>>>(ei, cursor, srcs);

    // --- weights -> bf16 transposed ---
    {
        dim3 g((36864 + 255) / 256, 6);
        wconv<<<g, 256, 0, stream>>>(Wq, Wk, Wv, Wo, W1, W2, wbuf);
    }

    // --- transformer block ---
    ln_kernel<<<(NN + 3) / 4, 256, 0, stream>>>(x, ln1_g, ln1_b, ybf, NN);
    {
        dim3 g(MT, 3);
        qkv_mfma<<<g, 256, 0, stream>>>(ybf, wbuf, bq, bk, bv, qbf, kv);
    }
    attn_gather<<<(NN + 3) / 4, 256, 0, stream>>>(qbf, kv, rowptr, srcs, abf);
    mfma_gemm<96, 2, 0><<<MT, 256, 0, stream>>>(abf, WoT, bo, x, x2, 96);
    ln_kernel<<<(NN + 3) / 4, 256, 0, stream>>>(x2, ln2_g, ln2_b, ybf, NN);
    {
        dim3 g(MT, 4);
        mfma_gemm<96, 1, 1><<<g, 256, 0, stream>>>(ybf, W1T, b1, nullptr, hbf, FFND);
    }
    mfma_gemm<384, 2, 0><<<MT, 256, 0, stream>>>(hbf, W2T, b2, x2, out, 96);
}

// Round 6
// 239.623 us; speedup vs baseline: 16.3176x; 1.1188x over previous
//
#include <hip/hip_runtime.h>
#include <hip/hip_bf16.h>
#include <math.h>

#define NN 50000
#define HIDD 96
#define NH 8
#define HD 12
#define FFND 384
#define NE 800000
#define NB 98           // buckets of 512 dst nodes

#define INV_SCALE 0.28867513459481287f

typedef short short8 __attribute__((ext_vector_type(8)));
typedef unsigned short ushort8 __attribute__((ext_vector_type(8)));
typedef float f32x4 __attribute__((ext_vector_type(4)));

__device__ __forceinline__ float bf2f(unsigned short u) {
    union { unsigned int i; float f; } c;
    c.i = ((unsigned int)u) << 16;
    return c.f;
}

// ---------------- zero kernel ----------------
__global__ void zero_kernel(int* __restrict__ p, int n) {
    int i = blockIdx.x * blockDim.x + threadIdx.x;
    if (i < n) p[i] = 0;
}

// ---------------- degree histogram ----------------
__global__ void deg_hist(const int* __restrict__ ei, int* __restrict__ deg) {
    int e = blockIdx.x * blockDim.x + threadIdx.x;
    if (e < NE) atomicAdd(&deg[ei[NE + e]], 1);
}

// ---------------- scan step 1 ----------------
__global__ __launch_bounds__(256) void scan1(const int* __restrict__ deg,
                                             int* __restrict__ rowptr,
                                             int* __restrict__ bsum) {
    __shared__ int lds[256];
    int t = threadIdx.x;
    int base = blockIdx.x * 1024 + t * 4;
    int v0 = (base + 0 < NN) ? deg[base + 0] : 0;
    int v1 = (base + 1 < NN) ? deg[base + 1] : 0;
    int v2 = (base + 2 < NN) ? deg[base + 2] : 0;
    int v3 = (base + 3 < NN) ? deg[base + 3] : 0;
    int p0 = v0, p1 = p0 + v1, p2 = p1 + v2, p3 = p2 + v3;
    lds[t] = p3;
    __syncthreads();
    for (int off = 1; off < 256; off <<= 1) {
        int val = (t >= off) ? lds[t - off] : 0;
        __syncthreads();
        lds[t] += val;
        __syncthreads();
    }
    int prefix = (t > 0) ? lds[t - 1] : 0;
    if (base + 0 < NN) rowptr[base + 1] = prefix + p0;
    if (base + 1 < NN) rowptr[base + 2] = prefix + p1;
    if (base + 2 < NN) rowptr[base + 3] = prefix + p2;
    if (base + 3 < NN) rowptr[base + 4] = prefix + p3;
    if (t == 255) bsum[blockIdx.x] = lds[255];
}

// ---------------- scan step 2 ----------------
__global__ void scan2(int* __restrict__ bsum, int nblk) {
    if (threadIdx.x == 0 && blockIdx.x == 0) {
        int run = 0;
        for (int i = 0; i < nblk; i++) { int s = bsum[i]; bsum[i] = run; run += s; }
    }
}

// ---------------- scan step 3 ----------------
__global__ __launch_bounds__(256) void scan3(int* __restrict__ rowptr,
                                             const int* __restrict__ bsum,
                                             int* __restrict__ cursor) {
    int i = blockIdx.x * blockDim.x + threadIdx.x;
    if (i < NN) {
        int val = rowptr[i + 1] + bsum[i / 1024];
        rowptr[i + 1] = val;
        if (i + 1 < NN) cursor[i + 1] = val;
    }
    if (i == 0) { rowptr[0] = 0; cursor[0] = 0; }
}

// ---------------- gcursor init: bucket bases from rowptr ----------------
__global__ void gcinit(const int* __restrict__ rowptr, int* __restrict__ gcursor) {
    int i = threadIdx.x;
    if (i < 128) {
        int n = i * 512; if (n > NN) n = NN;
        gcursor[i] = rowptr[n];
    }
}

// ---------------- bucket scatter pass A: edges -> bucket-major ebuf ----------------
__global__ __launch_bounds__(256) void bucket_scatter(
    const int* __restrict__ ei, int* __restrict__ gcursor, uint2* __restrict__ ebuf) {
    __shared__ int lcount[128];
    __shared__ int lbase[128];
    int t = threadIdx.x;
    int e0 = blockIdx.x * 2048;
    if (t < 128) lcount[t] = 0;
    __syncthreads();
    int rank[8], dsts[8], srcv[8];
#pragma unroll
    for (int i = 0; i < 8; i++) {
        int e = e0 + t + i * 256;
        if (e < NE) {
            srcv[i] = ei[e];
            int d = ei[NE + e];
            dsts[i] = d;
            rank[i] = atomicAdd(&lcount[d >> 9], 1);
        } else dsts[i] = -1;
    }
    __syncthreads();
    if (t < 128) lbase[t] = lcount[t] ? atomicAdd(&gcursor[t], lcount[t]) : 0;
    __syncthreads();
#pragma unroll
    for (int i = 0; i < 8; i++) {
        if (dsts[i] >= 0) {
            int b = dsts[i] >> 9;
            ebuf[lbase[b] + rank[i]] = make_uint2((unsigned)srcv[i], (unsigned)dsts[i]);
        }
    }
}

// ---------------- bucket scatter pass B: within-bucket final CSR scatter ----------------
__global__ __launch_bounds__(512) void bucket_final(
    const uint2* __restrict__ ebuf, const int* __restrict__ rowptr,
    int* __restrict__ cursor, int* __restrict__ srcs) {
    int b = blockIdx.x;
    int n0 = b * 512;       if (n0 > NN) n0 = NN;
    int n1 = (b + 1) * 512; if (n1 > NN) n1 = NN;
    int beg = rowptr[n0], end = rowptr[n1];
    for (int e = beg + threadIdx.x; e < end; e += 512) {
        uint2 ed = ebuf[e];
        int pos = atomicAdd(&cursor[ed.y], 1);
        srcs[pos] = (int)ed.x;
    }
}

// ---------------- weight convert+transpose to bf16: WT[n][k] = bf16(W[k][n]) ----------------
__global__ __launch_bounds__(256) void wconv(
    const float* __restrict__ Wq, const float* __restrict__ Wk,
    const float* __restrict__ Wv, const float* __restrict__ Wo,
    const float* __restrict__ W1, const float* __restrict__ W2,
    __hip_bfloat16* __restrict__ dst) {
    int y = blockIdx.y;
    int i = blockIdx.x * 256 + threadIdx.x;
    const float* W; __hip_bfloat16* D; int K, N;
    if (y == 0)      { W = Wq; D = dst;                 K = 96;  N = 96;  }
    else if (y == 1) { W = Wk; D = dst + 9216;          K = 96;  N = 96;  }
    else if (y == 2) { W = Wv; D = dst + 18432;         K = 96;  N = 96;  }
    else if (y == 3) { W = Wo; D = dst + 27648;         K = 96;  N = 96;  }
    else if (y == 4) { W = W1; D = dst + 36864;         K = 96;  N = 384; }
    else             { W = W2; D = dst + 36864 + 36864; K = 384; N = 96;  }
    if (i < K * N) {
        int n = i / K, k = i % K;
        D[i] = __float2bfloat16(W[k * N + n]);
    }
}

// ---------------- LayerNorm: one wave per row, bf16 output ----------------
__global__ void ln_kernel(const float* __restrict__ x, const float* __restrict__ g,
                          const float* __restrict__ b, __hip_bfloat16* __restrict__ y,
                          int nrows) {
    int wave = (blockIdx.x * blockDim.x + threadIdx.x) >> 6;
    int lane = threadIdx.x & 63;
    if (wave >= nrows) return;
    const float* xr = x + (size_t)wave * HIDD;
    float v0 = xr[lane];
    float v1 = (lane < 32) ? xr[64 + lane] : 0.0f;
    float s = v0 + v1;
    float q = v0 * v0 + v1 * v1;
    for (int o = 32; o > 0; o >>= 1) {
        s += __shfl_xor(s, o);
        q += __shfl_xor(q, o);
    }
    float mean = s * (1.0f / 96.0f);
    float var = q * (1.0f / 96.0f) - mean * mean;
    float rs = rsqrtf(var + 1e-5f);
    __hip_bfloat16* yr = y + (size_t)wave * HIDD;
    yr[lane] = __float2bfloat16((v0 - mean) * rs * g[lane] + b[lane]);
    if (lane < 32)
        yr[64 + lane] = __float2bfloat16((v1 - mean) * rs * g[64 + lane] + b[64 + lane]);
}

// ---------------- MFMA GEMM body (LDS-staged B) ----------------
// C = A[M x K](bf16) @ BT[96-col slab x K]^T + bias (+ epilogue)
// Block: 256 thr = 4 waves, BM=128; wave owns 32 rows (2x 16-row frags) x 96 cols.
// B^T slab staged in LDS, padded (+8) => 8 dwords/bank optimal for ds_read_b128.
// C/D frag: col = lane&15, row = (lane>>4)*4 + reg   [m89-verified]
// SMODE: 0 = fp32 flat, 1 = bf16 flat, 2 = bf16 kv-interleaved (+koff)
template<int K, int EPI, int SMODE>
__device__ __forceinline__ void gemm_body(
    const __hip_bfloat16* __restrict__ A, const __hip_bfloat16* __restrict__ BT,
    const float* __restrict__ bias, const float* __restrict__ R,
    void* __restrict__ Cptr, int ldc, int col0, int koff) {
    constexpr int BK = (K > 192) ? 192 : K;
    __shared__ __hip_bfloat16 Bs[96][BK + 8];
    int t = threadIdx.x;
    int lane = t & 63, wave = t >> 6;
    int row0 = blockIdx.x * 128 + wave * 32;
    int lr = lane & 15, kg = lane >> 4;
    bool val0 = (row0 + 16 <= NN);          // NN % 16 == 0: all-or-nothing frags
    bool val1 = (row0 + 32 <= NN);
    int ra0 = val0 ? row0 : 0;
    int ra1 = val1 ? (row0 + 16) : 0;
    const __hip_bfloat16* A0 = A + (size_t)(ra0 + lr) * K + kg * 8;
    const __hip_bfloat16* A1 = A + (size_t)(ra1 + lr) * K + kg * 8;
    f32x4 acc[2][6];
#pragma unroll
    for (int f = 0; f < 2; f++)
#pragma unroll
        for (int ct = 0; ct < 6; ct++) acc[f][ct] = (f32x4){0.f, 0.f, 0.f, 0.f};

    for (int k0 = 0; k0 < K; k0 += BK) {
        // stage B^T slab chunk: rows 0..95 (slab-local cols), K-chunk [k0, k0+BK)
        for (int i = t * 8; i < 96 * BK; i += 256 * 8) {
            int r = i / BK, c = i % BK;
            *(short8*)&Bs[r][c] = *(const short8*)&BT[(size_t)r * K + k0 + c];
        }
        __syncthreads();
#pragma unroll
        for (int kc = 0; kc < BK; kc += 32) {
            short8 a0 = *(const short8*)(A0 + k0 + kc);
            short8 a1 = *(const short8*)(A1 + k0 + kc);
#pragma unroll
            for (int ct = 0; ct < 6; ct++) {
                short8 bf_ = *(const short8*)&Bs[ct * 16 + lr][kc + kg * 8];
                acc[0][ct] = __builtin_amdgcn_mfma_f32_16x16x32_bf16(a0, bf_, acc[0][ct], 0, 0, 0);
                acc[1][ct] = __builtin_amdgcn_mfma_f32_16x16x32_bf16(a1, bf_, acc[1][ct], 0, 0, 0);
            }
        }
        __syncthreads();
    }

#pragma unroll
    for (int f = 0; f < 2; f++) {
        if (f == 0 ? !val0 : !val1) continue;
        int crow = row0 + f * 16 + kg * 4;
#pragma unroll
        for (int ct = 0; ct < 6; ct++) {
            int col = col0 + ct * 16 + lr;
            float bb = bias[col];
#pragma unroll
            for (int r = 0; r < 4; r++) {
                float o = acc[f][ct][r] + bb;
                if (EPI == 1)
                    o = 0.5f * o * (1.0f + erff(o * 0.70710678118654752f));
                if (EPI == 2)
                    o += R[(size_t)(crow + r) * 96 + col];
                if (SMODE == 0)
                    ((float*)Cptr)[(size_t)(crow + r) * ldc + col] = o;
                else if (SMODE == 1)
                    ((__hip_bfloat16*)Cptr)[(size_t)(crow + r) * ldc + col] = __float2bfloat16(o);
                else
                    ((__hip_bfloat16*)Cptr)[(size_t)(crow + r) * 192 + (col / 12) * 24 + koff + (col % 12)]
                        = __float2bfloat16(o);
            }
        }
    }
}

template<int K, int EPI, int SMODE>
__global__ __launch_bounds__(256) void mfma_gemm(
    const __hip_bfloat16* __restrict__ A, const __hip_bfloat16* __restrict__ BT,
    const float* __restrict__ bias, const float* __restrict__ R,
    void* __restrict__ Cptr, int ldc) {
    int col0 = blockIdx.y * 96;
    gemm_body<K, EPI, SMODE>(A, BT + (size_t)col0 * K, bias, R, Cptr, ldc, col0, 0);
}

// fused q/k/v: blockIdx.y selects weight slab / bias / output layout
__global__ __launch_bounds__(256) void qkv_mfma(
    const __hip_bfloat16* __restrict__ A, const __hip_bfloat16* __restrict__ wbuf,
    const float* __restrict__ bq, const float* __restrict__ bk,
    const float* __restrict__ bv,
    __hip_bfloat16* __restrict__ qbf, __hip_bfloat16* __restrict__ kv) {
    int y = blockIdx.y;
    if (y == 0)
        gemm_body<96, 0, 1>(A, wbuf, bq, nullptr, qbf, 96, 0, 0);
    else if (y == 1)
        gemm_body<96, 0, 2>(A, wbuf + 9216, bk, nullptr, kv, 0, 0, 0);
    else
        gemm_body<96, 0, 2>(A, wbuf + 18432, bv, nullptr, kv, 0, 0, 12);
}

// ---------------- Sparse attention gather (bf16 kv interleaved) ----------------
// one wave per dst; lane: h = lane&7, eslot = lane>>3
// kv row: [node][h][k0..k11, v0..v11] -> lane reads 48B contiguous, 16B-aligned
__global__ __launch_bounds__(256) void attn_gather(
    const __hip_bfloat16* __restrict__ qbf, const __hip_bfloat16* __restrict__ kv,
    const int* __restrict__ rowptr, const int* __restrict__ srcs,
    __hip_bfloat16* __restrict__ abf) {
    int wave = (blockIdx.x * blockDim.x + threadIdx.x) >> 6;
    int lane = threadIdx.x & 63;
    if (wave >= NN) return;
    int dst = wave;
    int h = lane & 7;
    int eslot = lane >> 3;
    float qf[12];
    {
        const uint2* qp = (const uint2*)(qbf + (size_t)dst * HIDD + h * HD);
        uint2 u0 = qp[0], u1 = qp[1], u2 = qp[2];
        unsigned int w[6] = {u0.x, u0.y, u1.x, u1.y, u2.x, u2.y};
#pragma unroll
        for (int i = 0; i < 6; i++) {
            qf[2 * i]     = bf2f((unsigned short)(w[i] & 0xffffu));
            qf[2 * i + 1] = bf2f((unsigned short)(w[i] >> 16));
        }
    }
    int beg = rowptr[dst], end = rowptr[dst + 1];
    float acc[12];
#pragma unroll
    for (int i = 0; i < 12; i++) acc[i] = 0.0f;
    float zz = 0.0f;
    for (int e = beg + eslot; e < end; e += 8) {
        int src = srcs[e];
        const ushort8* kp = (const ushort8*)(kv + (size_t)src * 192 + h * 24);
        ushort8 A = kp[0], B = kp[1], C = kp[2];
        float dot = 0.0f;
#pragma unroll
        for (int i = 0; i < 8; i++) dot += bf2f(A[i]) * qf[i];
#pragma unroll
        for (int i = 0; i < 4; i++) dot += bf2f(B[i]) * qf[8 + i];
        float s = fminf(fmaxf(dot * INV_SCALE, -5.0f), 5.0f);
        float sc = expf(s);
#pragma unroll
        for (int i = 0; i < 4; i++) acc[i] += bf2f(B[4 + i]) * sc;
#pragma unroll
        for (int i = 0; i < 8; i++) acc[4 + i] += bf2f(C[i]) * sc;
        zz += sc;
    }
#pragma unroll
    for (int m = 8; m < 64; m <<= 1) {
#pragma unroll
        for (int i = 0; i < 12; i++) acc[i] += __shfl_xor(acc[i], m);
        zz += __shfl_xor(zz, m);
    }
    if (eslot == 0) {
        float inv = 1.0f / (zz + 1e-6f);
        __hip_bfloat16* ar = abf + (size_t)dst * HIDD + h * HD;
#pragma unroll
        for (int i = 0; i < 12; i++) ar[i] = __float2bfloat16(acc[i] * inv);
    }
}

extern "C" void kernel_launch(void* const* d_in, const int* in_sizes, int n_in,
                              void* d_out, int out_size, void* d_ws, size_t ws_size,
                              hipStream_t stream) {
    const float* x     = (const float*)d_in[0];
    const int*   ei    = (const int*)d_in[1];
    const float* ln1_g = (const float*)d_in[2];
    const float* ln1_b = (const float*)d_in[3];
    const float* Wq    = (const float*)d_in[4];
    const float* bq    = (const float*)d_in[5];
    const float* Wk    = (const float*)d_in[6];
    const float* bk    = (const float*)d_in[7];
    const float* Wv    = (const float*)d_in[8];
    const float* bv    = (const float*)d_in[9];
    const float* Wo    = (const float*)d_in[10];
    const float* bo    = (const float*)d_in[11];
    const float* ln2_g = (const float*)d_in[12];
    const float* ln2_b = (const float*)d_in[13];
    const float* W1    = (const float*)d_in[14];
    const float* b1    = (const float*)d_in[15];
    const float* W2    = (const float*)d_in[16];
    const float* b2    = (const float*)d_in[17];
    float* out = (float*)d_out;

    // Workspace layout (float units, NF = NN*96 = 4.8M floats):
    //   qbf  bf16 [0, 0.5NF)
    //   kv   bf16 [0.5NF, 1.5NF)
    //   abf  bf16 [1.5NF, 2NF)
    //   hbf  bf16 [0, 2NF)          aliases qbf/kv/abf (dead by ffn1)
    //   x2   fp32 [2NF, 3NF)
    //   ybf  bf16 [3NF, 3.5NF)
    //   CSR ints at 3.5NF  (deg NN, rowptr NN+1, cursor NN, srcs NE, bsum 64)
    //   wbuf bf16 at 4NF   (110592 bf16 = 55296 floats)
    //   gcursor(128) + ebuf(NE uint2) at 4NF + 60000
    float* ws = (float*)d_ws;
    const size_t NF = (size_t)NN * HIDD;
    __hip_bfloat16* qbf = (__hip_bfloat16*)ws;
    __hip_bfloat16* kv  = (__hip_bfloat16*)(ws + NF / 2);
    __hip_bfloat16* abf = (__hip_bfloat16*)(ws + NF / 2 + NF);
    __hip_bfloat16* hbf = (__hip_bfloat16*)ws;
    float* x2 = ws + 2 * NF;
    __hip_bfloat16* ybf = (__hip_bfloat16*)(ws + 3 * NF);
    int* ibase  = (int*)(ws + 3 * NF + NF / 2);
    int* deg    = ibase;
    int* rowptr = ibase + NN;
    int* cursor = ibase + 2 * NN + 1;
    int* srcs   = ibase + 3 * NN + 1;
    int* bsum   = ibase + 3 * NN + 1 + NE;
    __hip_bfloat16* wbuf = (__hip_bfloat16*)(ws + 4 * NF);
    __hip_bfloat16* WoT = wbuf + 27648;
    __hip_bfloat16* W1T = wbuf + 36864;
    __hip_bfloat16* W2T = wbuf + 73728;
    int* gcursor = (int*)(ws + 4 * NF + 60000);
    uint2* ebuf  = (uint2*)(ws + 4 * NF + 60000 + 128);

    const int MT = (NN + 127) / 128;             // 391
    const int SCAN_BLOCKS = (NN + 1023) / 1024;  // 49

    // --- CSR build (bucket radix) ---
    zero_kernel<<<(NN + 255) / 256, 256, 0, stream>>>(deg, NN);
    deg_hist<<<(NE + 255) / 256, 256, 0, stream>>>(ei, deg);
    scan1<<<SCAN_BLOCKS, 256, 0, stream>>>(deg, rowptr, bsum);
    scan2<<<1, 64, 0, stream>>>(bsum, SCAN_BLOCKS);
    scan3<<<(NN + 255) / 256, 256, 0, stream>>>(rowptr, bsum, cursor);
    gcinit<<<1, 128, 0, stream>>>(rowptr, gcursor);
    bucket_scatter<<<(NE + 2047) / 2048, 256, 0, stream>>>(ei, gcursor, ebuf);
    bucket_final<<<NB, 512, 0, stream>>>(ebuf, rowptr, cursor, srcs);

    // --- weights -> bf16 transposed ---
    {
        dim3 g((36864 + 255) / 256, 6);
        wconv<<<g, 256, 0, stream>>>(Wq, Wk, Wv, Wo, W1, W2, wbuf);
    }

    // --- transformer block ---
    ln_kernel<<<(NN + 3) / 4, 256, 0, stream>>>(x, ln1_g, ln1_b, ybf, NN);
    {
        dim3 g(MT, 3);
        qkv_mfma<<<g, 256, 0, stream>>>(ybf, wbuf, bq, bk, bv, qbf, kv);
    }
    attn_gather<<<(NN + 3) / 4, 256, 0, stream>>>(qbf, kv, rowptr, srcs, abf);
    mfma_gemm<96, 2, 0><<<MT, 256, 0, stream>>>(abf, WoT, bo, x, x2, 96);
    ln_kernel<<<(NN + 3) / 4, 256, 0, stream>>>(x2, ln2_g, ln2_b, ybf, NN);
    {
        dim3 g(MT, 4);
        mfma_gemm<96, 1, 1><<<g, 256, 0, stream>>>(ybf, W1T, b1, nullptr, hbf, FFND);
    }
    mfma_gemm<384, 2, 0><<<MT, 256, 0, stream>>>(hbf, W2T, b2, x2, out, 96);
}

// Round 7
// 216.684 us; speedup vs baseline: 18.0450x; 1.1059x over previous
//
#include <hip/hip_runtime.h>
#include <hip/hip_bf16.h>
#include <math.h>

#define NN 50000
#define HIDD 96
#define NH 8
#define HD 12
#define FFND 384
#define NE 800000
#define NB 98           // buckets of 512 dst nodes

#define INV_SCALE 0.28867513459481287f

typedef short short8 __attribute__((ext_vector_type(8)));
typedef float f32x4 __attribute__((ext_vector_type(4)));
typedef float f32x2 __attribute__((ext_vector_type(2)));

__device__ __forceinline__ float bf2f(unsigned short u) {
    union { unsigned int i; float f; } c;
    c.i = ((unsigned int)u) << 16;
    return c.f;
}

// ---------------- zero kernel ----------------
__global__ void zero_kernel(int* __restrict__ p, int n) {
    int i = blockIdx.x * blockDim.x + threadIdx.x;
    if (i < n) p[i] = 0;
}

// ---------------- degree histogram ----------------
__global__ void deg_hist(const int* __restrict__ ei, int* __restrict__ deg) {
    int e = blockIdx.x * blockDim.x + threadIdx.x;
    if (e < NE) atomicAdd(&deg[ei[NE + e]], 1);
}

// ---------------- scan step 1 ----------------
__global__ __launch_bounds__(256) void scan1(const int* __restrict__ deg,
                                             int* __restrict__ rowptr,
                                             int* __restrict__ bsum) {
    __shared__ int lds[256];
    int t = threadIdx.x;
    int base = blockIdx.x * 1024 + t * 4;
    int v0 = (base + 0 < NN) ? deg[base + 0] : 0;
    int v1 = (base + 1 < NN) ? deg[base + 1] : 0;
    int v2 = (base + 2 < NN) ? deg[base + 2] : 0;
    int v3 = (base + 3 < NN) ? deg[base + 3] : 0;
    int p0 = v0, p1 = p0 + v1, p2 = p1 + v2, p3 = p2 + v3;
    lds[t] = p3;
    __syncthreads();
    for (int off = 1; off < 256; off <<= 1) {
        int val = (t >= off) ? lds[t - off] : 0;
        __syncthreads();
        lds[t] += val;
        __syncthreads();
    }
    int prefix = (t > 0) ? lds[t - 1] : 0;
    if (base + 0 < NN) rowptr[base + 1] = prefix + p0;
    if (base + 1 < NN) rowptr[base + 2] = prefix + p1;
    if (base + 2 < NN) rowptr[base + 3] = prefix + p2;
    if (base + 3 < NN) rowptr[base + 4] = prefix + p3;
    if (t == 255) bsum[blockIdx.x] = lds[255];
}

// ---------------- scan step 2 ----------------
__global__ void scan2(int* __restrict__ bsum, int nblk) {
    if (threadIdx.x == 0 && blockIdx.x == 0) {
        int run = 0;
        for (int i = 0; i < nblk; i++) { int s = bsum[i]; bsum[i] = run; run += s; }
    }
}

// ---------------- scan step 3 ----------------
__global__ __launch_bounds__(256) void scan3(int* __restrict__ rowptr,
                                             const int* __restrict__ bsum,
                                             int* __restrict__ cursor) {
    int i = blockIdx.x * blockDim.x + threadIdx.x;
    if (i < NN) {
        int val = rowptr[i + 1] + bsum[i / 1024];
        rowptr[i + 1] = val;
        if (i + 1 < NN) cursor[i + 1] = val;
    }
    if (i == 0) { rowptr[0] = 0; cursor[0] = 0; }
}

// ---------------- gcursor init: bucket bases from rowptr ----------------
__global__ void gcinit(const int* __restrict__ rowptr, int* __restrict__ gcursor) {
    int i = threadIdx.x;
    if (i < 128) {
        int n = i * 512; if (n > NN) n = NN;
        gcursor[i] = rowptr[n];
    }
}

// ---------------- bucket scatter pass A: edges -> bucket-major ebuf ----------------
__global__ __launch_bounds__(256) void bucket_scatter(
    const int* __restrict__ ei, int* __restrict__ gcursor, uint2* __restrict__ ebuf) {
    __shared__ int lcount[128];
    __shared__ int lbase[128];
    int t = threadIdx.x;
    int e0 = blockIdx.x * 2048;
    if (t < 128) lcount[t] = 0;
    __syncthreads();
    int rank[8], dsts[8], srcv[8];
#pragma unroll
    for (int i = 0; i < 8; i++) {
        int e = e0 + t + i * 256;
        if (e < NE) {
            srcv[i] = ei[e];
            int d = ei[NE + e];
            dsts[i] = d;
            rank[i] = atomicAdd(&lcount[d >> 9], 1);
        } else dsts[i] = -1;
    }
    __syncthreads();
    if (t < 128) lbase[t] = lcount[t] ? atomicAdd(&gcursor[t], lcount[t]) : 0;
    __syncthreads();
#pragma unroll
    for (int i = 0; i < 8; i++) {
        if (dsts[i] >= 0) {
            int b = dsts[i] >> 9;
            ebuf[lbase[b] + rank[i]] = make_uint2((unsigned)srcv[i], (unsigned)dsts[i]);
        }
    }
}

// ---------------- bucket scatter pass B: within-bucket final CSR scatter ----------------
__global__ __launch_bounds__(512) void bucket_final(
    const uint2* __restrict__ ebuf, const int* __restrict__ rowptr,
    int* __restrict__ cursor, int* __restrict__ srcs) {
    int b = blockIdx.x;
    int n0 = b * 512;       if (n0 > NN) n0 = NN;
    int n1 = (b + 1) * 512; if (n1 > NN) n1 = NN;
    int beg = rowptr[n0], end = rowptr[n1];
    for (int e = beg + threadIdx.x; e < end; e += 512) {
        uint2 ed = ebuf[e];
        int pos = atomicAdd(&cursor[ed.y], 1);
        srcs[pos] = (int)ed.x;
    }
}

// ---------------- weight convert+transpose to bf16: WT[n][k] = bf16(W[k][n]) ----------------
__global__ __launch_bounds__(256) void wconv(
    const float* __restrict__ Wq, const float* __restrict__ Wk,
    const float* __restrict__ Wv, const float* __restrict__ Wo,
    const float* __restrict__ W1, const float* __restrict__ W2,
    __hip_bfloat16* __restrict__ dst) {
    int y = blockIdx.y;
    int i = blockIdx.x * 256 + threadIdx.x;
    const float* W; __hip_bfloat16* D; int K, N;
    if (y == 0)      { W = Wq; D = dst;                 K = 96;  N = 96;  }
    else if (y == 1) { W = Wk; D = dst + 9216;          K = 96;  N = 96;  }
    else if (y == 2) { W = Wv; D = dst + 18432;         K = 96;  N = 96;  }
    else if (y == 3) { W = Wo; D = dst + 27648;         K = 96;  N = 96;  }
    else if (y == 4) { W = W1; D = dst + 36864;         K = 96;  N = 384; }
    else             { W = W2; D = dst + 36864 + 36864; K = 384; N = 96;  }
    if (i < K * N) {
        int n = i / K, k = i % K;
        D[i] = __float2bfloat16(W[k * N + n]);
    }
}

// ---------------- LayerNorm: one wave per row, bf16 output ----------------
__global__ void ln_kernel(const float* __restrict__ x, const float* __restrict__ g,
                          const float* __restrict__ b, __hip_bfloat16* __restrict__ y,
                          int nrows) {
    int wave = (blockIdx.x * blockDim.x + threadIdx.x) >> 6;
    int lane = threadIdx.x & 63;
    if (wave >= nrows) return;
    const float* xr = x + (size_t)wave * HIDD;
    float v0 = xr[lane];
    float v1 = (lane < 32) ? xr[64 + lane] : 0.0f;
    float s = v0 + v1;
    float q = v0 * v0 + v1 * v1;
    for (int o = 32; o > 0; o >>= 1) {
        s += __shfl_xor(s, o);
        q += __shfl_xor(q, o);
    }
    float mean = s * (1.0f / 96.0f);
    float var = q * (1.0f / 96.0f) - mean * mean;
    float rs = rsqrtf(var + 1e-5f);
    __hip_bfloat16* yr = y + (size_t)wave * HIDD;
    yr[lane] = __float2bfloat16((v0 - mean) * rs * g[lane] + b[lane]);
    if (lane < 32)
        yr[64 + lane] = __float2bfloat16((v1 - mean) * rs * g[64 + lane] + b[64 + lane]);
}

// ---------------- MFMA GEMM body (LDS-staged B) ----------------
// C = A[M x K](bf16) @ BT[96-col slab x K]^T + bias (+ epilogue)
// Block: 256 thr = 4 waves, BM=128; wave owns 32 rows (2x 16-row frags) x 96 cols.
// NOTE: no early return — invalid waves must still stage B and hit barriers.
// C/D frag: col = lane&15, row = (lane>>4)*4 + reg   [m89-verified]
// SMODE: 0 = fp32 flat, 1 = bf16 flat, 2 = fp8 kv-interleaved (+koff)
template<int K, int EPI, int SMODE>
__device__ __forceinline__ void gemm_body(
    const __hip_bfloat16* __restrict__ A, const __hip_bfloat16* __restrict__ BT,
    const float* __restrict__ bias, const float* __restrict__ R,
    void* __restrict__ Cptr, int ldc, int col0, int koff) {
    constexpr int BK = (K > 192) ? 192 : K;
    __shared__ __hip_bfloat16 Bs[96][BK + 8];
    int t = threadIdx.x;
    int lane = t & 63, wave = t >> 6;
    int row0 = blockIdx.x * 128 + wave * 32;
    int lr = lane & 15, kg = lane >> 4;
    bool val0 = (row0 + 16 <= NN);          // NN % 16 == 0: all-or-nothing frags
    bool val1 = (row0 + 32 <= NN);
    int ra0 = val0 ? row0 : 0;
    int ra1 = val1 ? (row0 + 16) : 0;
    const __hip_bfloat16* A0 = A + (size_t)(ra0 + lr) * K + kg * 8;
    const __hip_bfloat16* A1 = A + (size_t)(ra1 + lr) * K + kg * 8;
    f32x4 acc[2][6];
#pragma unroll
    for (int f = 0; f < 2; f++)
#pragma unroll
        for (int ct = 0; ct < 6; ct++) acc[f][ct] = (f32x4){0.f, 0.f, 0.f, 0.f};

    for (int k0 = 0; k0 < K; k0 += BK) {
        for (int i = t * 8; i < 96 * BK; i += 256 * 8) {
            int r = i / BK, c = i % BK;
            *(short8*)&Bs[r][c] = *(const short8*)&BT[(size_t)r * K + k0 + c];
        }
        __syncthreads();
#pragma unroll
        for (int kc = 0; kc < BK; kc += 32) {
            short8 a0 = *(const short8*)(A0 + k0 + kc);
            short8 a1 = *(const short8*)(A1 + k0 + kc);
#pragma unroll
            for (int ct = 0; ct < 6; ct++) {
                short8 bf_ = *(const short8*)&Bs[ct * 16 + lr][kc + kg * 8];
                acc[0][ct] = __builtin_amdgcn_mfma_f32_16x16x32_bf16(a0, bf_, acc[0][ct], 0, 0, 0);
                acc[1][ct] = __builtin_amdgcn_mfma_f32_16x16x32_bf16(a1, bf_, acc[1][ct], 0, 0, 0);
            }
        }
        __syncthreads();
    }

#pragma unroll
    for (int f = 0; f < 2; f++) {
        if (f == 0 ? !val0 : !val1) continue;
        int crow = row0 + f * 16 + kg * 4;
#pragma unroll
        for (int ct = 0; ct < 6; ct++) {
            int col = col0 + ct * 16 + lr;
            float bb = bias[col];
#pragma unroll
            for (int r = 0; r < 4; r++) {
                float o = acc[f][ct][r] + bb;
                if (EPI == 1)
                    o = 0.5f * o * (1.0f + erff(o * 0.70710678118654752f));
                if (EPI == 2)
                    o += R[(size_t)(crow + r) * 96 + col];
                if (SMODE == 0)
                    ((float*)Cptr)[(size_t)(crow + r) * ldc + col] = o;
                else if (SMODE == 1)
                    ((__hip_bfloat16*)Cptr)[(size_t)(crow + r) * ldc + col] = __float2bfloat16(o);
                else {
                    unsigned int enc = (unsigned int)__builtin_amdgcn_cvt_pk_fp8_f32(o, o, 0, false);
                    ((unsigned char*)Cptr)[(size_t)(crow + r) * 192 + (col / 12) * 24 + koff + (col % 12)]
                        = (unsigned char)(enc & 0xffu);
                }
            }
        }
    }
}

template<int K, int EPI, int SMODE>
__global__ __launch_bounds__(256) void mfma_gemm(
    const __hip_bfloat16* __restrict__ A, const __hip_bfloat16* __restrict__ BT,
    const float* __restrict__ bias, const float* __restrict__ R,
    void* __restrict__ Cptr, int ldc) {
    int col0 = blockIdx.y * 96;
    gemm_body<K, EPI, SMODE>(A, BT + (size_t)col0 * K, bias, R, Cptr, ldc, col0, 0);
}

// fused q/k/v: blockIdx.y selects weight slab / bias / output layout
__global__ __launch_bounds__(256) void qkv_mfma(
    const __hip_bfloat16* __restrict__ A, const __hip_bfloat16* __restrict__ wbuf,
    const float* __restrict__ bq, const float* __restrict__ bk,
    const float* __restrict__ bv,
    __hip_bfloat16* __restrict__ qbf, unsigned char* __restrict__ kv) {
    int y = blockIdx.y;
    if (y == 0)
        gemm_body<96, 0, 1>(A, wbuf, bq, nullptr, qbf, 96, 0, 0);
    else if (y == 1)
        gemm_body<96, 0, 2>(A, wbuf + 9216, bk, nullptr, kv, 0, 0, 0);
    else
        gemm_body<96, 0, 2>(A, wbuf + 18432, bv, nullptr, kv, 0, 0, 12);
}

// ---------------- proj + LN2 fused ----------------
// x2 = x + abf @ WoT^T + bo ; ybf = LN2(x2)
// One block = 128 rows x all 96 cols; each row lives in 16 lr-lanes (6 regs each).
__global__ __launch_bounds__(256) void proj_ln(
    const __hip_bfloat16* __restrict__ A, const __hip_bfloat16* __restrict__ BT,
    const float* __restrict__ bias, const float* __restrict__ R,
    const float* __restrict__ g2, const float* __restrict__ b2v,
    float* __restrict__ x2, __hip_bfloat16* __restrict__ ybf) {
    constexpr int K = 96;
    __shared__ __hip_bfloat16 Bs[96][K + 8];
    int t = threadIdx.x;
    int lane = t & 63, wave = t >> 6;
    int row0 = blockIdx.x * 128 + wave * 32;
    int lr = lane & 15, kg = lane >> 4;
    bool val0 = (row0 + 16 <= NN);
    bool val1 = (row0 + 32 <= NN);
    int ra0 = val0 ? row0 : 0;
    int ra1 = val1 ? (row0 + 16) : 0;
    const __hip_bfloat16* A0 = A + (size_t)(ra0 + lr) * K + kg * 8;
    const __hip_bfloat16* A1 = A + (size_t)(ra1 + lr) * K + kg * 8;
    f32x4 acc[2][6];
#pragma unroll
    for (int f = 0; f < 2; f++)
#pragma unroll
        for (int ct = 0; ct < 6; ct++) acc[f][ct] = (f32x4){0.f, 0.f, 0.f, 0.f};

    for (int i = t * 8; i < 96 * K; i += 256 * 8) {
        int r = i / K, c = i % K;
        *(short8*)&Bs[r][c] = *(const short8*)&BT[(size_t)r * K + c];
    }
    __syncthreads();
#pragma unroll
    for (int kc = 0; kc < K; kc += 32) {
        short8 a0 = *(const short8*)(A0 + kc);
        short8 a1 = *(const short8*)(A1 + kc);
#pragma unroll
        for (int ct = 0; ct < 6; ct++) {
            short8 bf_ = *(const short8*)&Bs[ct * 16 + lr][kc + kg * 8];
            acc[0][ct] = __builtin_amdgcn_mfma_f32_16x16x32_bf16(a0, bf_, acc[0][ct], 0, 0, 0);
            acc[1][ct] = __builtin_amdgcn_mfma_f32_16x16x32_bf16(a1, bf_, acc[1][ct], 0, 0, 0);
        }
    }

    float bo_[6], gv[6], bv_[6];
#pragma unroll
    for (int ct = 0; ct < 6; ct++) {
        int col = ct * 16 + lr;
        bo_[ct] = bias[col];
        gv[ct]  = g2[col];
        bv_[ct] = b2v[col];
    }
#pragma unroll
    for (int f = 0; f < 2; f++) {
        if (f == 0 ? !val0 : !val1) continue;
        int crow = row0 + f * 16 + kg * 4;
#pragma unroll
        for (int r = 0; r < 4; r++) {
            int row = crow + r;
            float o[6], s1 = 0.f, s2 = 0.f;
#pragma unroll
            for (int ct = 0; ct < 6; ct++) {
                int col = ct * 16 + lr;
                float val = acc[f][ct][r] + bo_[ct] + R[(size_t)row * 96 + col];
                o[ct] = val; s1 += val; s2 += val * val;
            }
#pragma unroll
            for (int m = 1; m < 16; m <<= 1) {
                s1 += __shfl_xor(s1, m);
                s2 += __shfl_xor(s2, m);
            }
            float mu = s1 * (1.0f / 96.0f);
            float var = s2 * (1.0f / 96.0f) - mu * mu;
            float rs = rsqrtf(var + 1e-5f);
#pragma unroll
            for (int ct = 0; ct < 6; ct++) {
                int col = ct * 16 + lr;
                x2[(size_t)row * 96 + col] = o[ct];
                ybf[(size_t)row * 96 + col] =
                    __float2bfloat16((o[ct] - mu) * rs * gv[ct] + bv_[ct]);
            }
        }
    }
}

// ---------------- Sparse attention gather (fp8 kv interleaved) ----------------
// one wave per dst; lane: h = lane&7, eslot = lane>>3
// kv row: [node][h][k0..k11, v0..v11] fp8 -> lane reads 24B contiguous (8B-aligned)
__global__ __launch_bounds__(256) void attn_gather(
    const __hip_bfloat16* __restrict__ qbf, const unsigned char* __restrict__ kv,
    const int* __restrict__ rowptr, const int* __restrict__ srcs,
    __hip_bfloat16* __restrict__ abf) {
    int wave = (blockIdx.x * blockDim.x + threadIdx.x) >> 6;
    int lane = threadIdx.x & 63;
    if (wave >= NN) return;
    int dst = wave;
    int h = lane & 7;
    int eslot = lane >> 3;
    float qf[12];
    {
        const uint2* qp = (const uint2*)(qbf + (size_t)dst * HIDD + h * HD);
        uint2 u0 = qp[0], u1 = qp[1], u2 = qp[2];
        unsigned int w[6] = {u0.x, u0.y, u1.x, u1.y, u2.x, u2.y};
#pragma unroll
        for (int i = 0; i < 6; i++) {
            qf[2 * i]     = bf2f((unsigned short)(w[i] & 0xffffu));
            qf[2 * i + 1] = bf2f((unsigned short)(w[i] >> 16));
        }
    }
    int beg = rowptr[dst], end = rowptr[dst + 1];
    float acc[12];
#pragma unroll
    for (int i = 0; i < 12; i++) acc[i] = 0.0f;
    float zz = 0.0f;
    for (int e = beg + eslot; e < end; e += 8) {
        int src = srcs[e];
        const uint2* kp = (const uint2*)(kv + (size_t)src * 192 + h * 24);
        uint2 wA = kp[0], wB = kp[1], wC = kp[2];
        f32x2 p;
        float dot = 0.0f;
        p = __builtin_amdgcn_cvt_pk_f32_fp8(wA.x, false); dot += p[0] * qf[0]  + p[1] * qf[1];
        p = __builtin_amdgcn_cvt_pk_f32_fp8(wA.x, true);  dot += p[0] * qf[2]  + p[1] * qf[3];
        p = __builtin_amdgcn_cvt_pk_f32_fp8(wA.y, false); dot += p[0] * qf[4]  + p[1] * qf[5];
        p = __builtin_amdgcn_cvt_pk_f32_fp8(wA.y, true);  dot += p[0] * qf[6]  + p[1] * qf[7];
        p = __builtin_amdgcn_cvt_pk_f32_fp8(wB.x, false); dot += p[0] * qf[8]  + p[1] * qf[9];
        p = __builtin_amdgcn_cvt_pk_f32_fp8(wB.x, true);  dot += p[0] * qf[10] + p[1] * qf[11];
        float s = fminf(fmaxf(dot * INV_SCALE, -5.0f), 5.0f);
        float sc = expf(s);
        p = __builtin_amdgcn_cvt_pk_f32_fp8(wB.y, false); acc[0]  += p[0] * sc; acc[1]  += p[1] * sc;
        p = __builtin_amdgcn_cvt_pk_f32_fp8(wB.y, true);  acc[2]  += p[0] * sc; acc[3]  += p[1] * sc;
        p = __builtin_amdgcn_cvt_pk_f32_fp8(wC.x, false); acc[4]  += p[0] * sc; acc[5]  += p[1] * sc;
        p = __builtin_amdgcn_cvt_pk_f32_fp8(wC.x, true);  acc[6]  += p[0] * sc; acc[7]  += p[1] * sc;
        p = __builtin_amdgcn_cvt_pk_f32_fp8(wC.y, false); acc[8]  += p[0] * sc; acc[9]  += p[1] * sc;
        p = __builtin_amdgcn_cvt_pk_f32_fp8(wC.y, true);  acc[10] += p[0] * sc; acc[11] += p[1] * sc;
        zz += sc;
    }
#pragma unroll
    for (int m = 8; m < 64; m <<= 1) {
#pragma unroll
        for (int i = 0; i < 12; i++) acc[i] += __shfl_xor(acc[i], m);
        zz += __shfl_xor(zz, m);
    }
    if (eslot == 0) {
        float inv = 1.0f / (zz + 1e-6f);
        __hip_bfloat16* ar = abf + (size_t)dst * HIDD + h * HD;
#pragma unroll
        for (int i = 0; i < 12; i++) ar[i] = __float2bfloat16(acc[i] * inv);
    }
}

extern "C" void kernel_launch(void* const* d_in, const int* in_sizes, int n_in,
                              void* d_out, int out_size, void* d_ws, size_t ws_size,
                              hipStream_t stream) {
    const float* x     = (const float*)d_in[0];
    const int*   ei    = (const int*)d_in[1];
    const float* ln1_g = (const float*)d_in[2];
    const float* ln1_b = (const float*)d_in[3];
    const float* Wq    = (const float*)d_in[4];
    const float* bq    = (const float*)d_in[5];
    const float* Wk    = (const float*)d_in[6];
    const float* bk    = (const float*)d_in[7];
    const float* Wv    = (const float*)d_in[8];
    const float* bv    = (const float*)d_in[9];
    const float* Wo    = (const float*)d_in[10];
    const float* bo    = (const float*)d_in[11];
    const float* ln2_g = (const float*)d_in[12];
    const float* ln2_b = (const float*)d_in[13];
    const float* W1    = (const float*)d_in[14];
    const float* b1    = (const float*)d_in[15];
    const float* W2    = (const float*)d_in[16];
    const float* b2    = (const float*)d_in[17];
    float* out = (float*)d_out;

    // Workspace layout (float units, NF = NN*96 = 4.8M floats):
    //   qbf  bf16 [0, 0.5NF)
    //   kv   fp8  [0.5NF, NF)       (NN*192 bytes)
    //   abf  bf16 [1.5NF, 2NF)
    //   hbf  bf16 [0, 2NF)          aliases qbf/kv/abf (dead by ffn1)
    //   x2   fp32 [2NF, 3NF)
    //   ybf  bf16 [3NF, 3.5NF)
    //   CSR ints at 3.5NF  (deg NN, rowptr NN+1, cursor NN, srcs NE, bsum 64)
    //   wbuf bf16 at 4NF   (110592 bf16 = 55296 floats)
    //   gcursor(128) + ebuf(NE uint2) at 4NF + 60000
    float* ws = (float*)d_ws;
    const size_t NF = (size_t)NN * HIDD;
    __hip_bfloat16* qbf = (__hip_bfloat16*)ws;
    unsigned char*  kv  = (unsigned char*)(ws + NF / 2);
    __hip_bfloat16* abf = (__hip_bfloat16*)(ws + NF / 2 + NF);
    __hip_bfloat16* hbf = (__hip_bfloat16*)ws;
    float* x2 = ws + 2 * NF;
    __hip_bfloat16* ybf = (__hip_bfloat16*)(ws + 3 * NF);
    int* ibase  = (int*)(ws + 3 * NF + NF / 2);
    int* deg    = ibase;
    int* rowptr = ibase + NN;
    int* cursor = ibase + 2 * NN + 1;
    int* srcs   = ibase + 3 * NN + 1;
    int* bsum   = ibase + 3 * NN + 1 + NE;
    __hip_bfloat16* wbuf = (__hip_bfloat16*)(ws + 4 * NF);
    __hip_bfloat16* WoT = wbuf + 27648;
    __hip_bfloat16* W1T = wbuf + 36864;
    __hip_bfloat16* W2T = wbuf + 73728;
    int* gcursor = (int*)(ws + 4 * NF + 60000);
    uint2* ebuf  = (uint2*)(ws + 4 * NF + 60000 + 128);

    const int MT = (NN + 127) / 128;             // 391
    const int SCAN_BLOCKS = (NN + 1023) / 1024;  // 49

    // --- CSR build (bucket radix) ---
    zero_kernel<<<(NN + 255) / 256, 256, 0, stream>>>(deg, NN);
    deg_hist<<<(NE + 255) / 256, 256, 0, stream>>>(ei, deg);
    scan1<<<SCAN_BLOCKS, 256, 0, stream>>>(deg, rowptr, bsum);
    scan2<<<1, 64, 0, stream>>>(bsum, SCAN_BLOCKS);
    scan3<<<(NN + 255) / 256, 256, 0, stream>>>(rowptr, bsum, cursor);
    gcinit<<<1, 128, 0, stream>>>(rowptr, gcursor);
    bucket_scatter<<<(NE + 2047) / 2048, 256, 0, stream>>>(ei, gcursor, ebuf);
    bucket_final<<<NB, 512, 0, stream>>>(ebuf, rowptr, cursor, srcs);

    // --- weights -> bf16 transposed ---
    {
        dim3 g((36864 + 255) / 256, 6);
        wconv<<<g, 256, 0, stream>>>(Wq, Wk, Wv, Wo, W1, W2, wbuf);
    }

    // --- transformer block ---
    ln_kernel<<<(NN + 3) / 4, 256, 0, stream>>>(x, ln1_g, ln1_b, ybf, NN);
    {
        dim3 g(MT, 3);
        qkv_mfma<<<g, 256, 0, stream>>>(ybf, wbuf, bq, bk, bv, qbf, kv);
    }
    attn_gather<<<(NN + 3) / 4, 256, 0, stream>>>(qbf, kv, rowptr, srcs, abf);
    proj_ln<<<MT, 256, 0, stream>>>(abf, WoT, bo, x, ln2_g, ln2_b, x2, ybf);
    {
        dim3 g(MT, 4);
        mfma_gemm<96, 1, 1><<<g, 256, 0, stream>>>(ybf, W1T, b1, nullptr, hbf, FFND);
    }
    mfma_gemm<384, 2, 0><<<MT, 256, 0, stream>>>(hbf, W2T, b2, x2, out, 96);
}

// Round 8
// 195.995 us; speedup vs baseline: 19.9498x; 1.1056x over previous
//
#include <hip/hip_runtime.h>
#include <hip/hip_bf16.h>
#include <math.h>

#define NN 50000
#define HIDD 96
#define NH 8
#define HD 12
#define FFND 384
#define NE 800000
#define NB 98           // buckets of 512 dst nodes

#define INV_SCALE 0.28867513459481287f

typedef short short8 __attribute__((ext_vector_type(8)));
typedef float f32x4 __attribute__((ext_vector_type(4)));
typedef float f32x2 __attribute__((ext_vector_type(2)));

__device__ __forceinline__ float bf2f(unsigned short u) {
    union { unsigned int i; float f; } c;
    c.i = ((unsigned int)u) << 16;
    return c.f;
}

// ---------------- zero kernel ----------------
__global__ void zero_kernel(int* __restrict__ p, int n) {
    int i = blockIdx.x * blockDim.x + threadIdx.x;
    if (i < n) p[i] = 0;
}

// ---------------- bucket histogram (128 bins, LDS-reduced) ----------------
__global__ __launch_bounds__(256) void bucket_count(const int* __restrict__ ei,
                                                    int* __restrict__ bcnt) {
    __shared__ int h[128];
    int t = threadIdx.x;
    if (t < 128) h[t] = 0;
    __syncthreads();
#pragma unroll
    for (int i = 0; i < 4; i++) {
        int e = blockIdx.x * 1024 + t + i * 256;
        if (e < NE) atomicAdd(&h[ei[NE + e] >> 9], 1);
    }
    __syncthreads();
    if (t < 128 && h[t]) atomicAdd(&bcnt[t], h[t]);
}

// ---------------- scan 128 bucket counts; init bbase + gcursor ----------------
__global__ __launch_bounds__(128) void bucket_scan(const int* __restrict__ bcnt,
                                                   int* __restrict__ bbase,
                                                   int* __restrict__ gcursor) {
    __shared__ int s[128];
    int t = threadIdx.x;
    s[t] = bcnt[t];
    __syncthreads();
    for (int off = 1; off < 128; off <<= 1) {
        int v = (t >= off) ? s[t - off] : 0;
        __syncthreads();
        s[t] += v;
        __syncthreads();
    }
    int excl = (t > 0) ? s[t - 1] : 0;
    bbase[t] = excl;
    gcursor[t] = excl;
    if (t == 127) bbase[128] = s[127];
}

// ---------------- bucket scatter pass A: edges -> bucket-major ebuf (u32 packed) ----------------
__global__ __launch_bounds__(256) void bucket_scatter(
    const int* __restrict__ ei, int* __restrict__ gcursor,
    unsigned int* __restrict__ ebuf) {
    __shared__ int lcount[128];
    __shared__ int lbase[128];
    int t = threadIdx.x;
    int e0 = blockIdx.x * 2048;
    if (t < 128) lcount[t] = 0;
    __syncthreads();
    int rank[8], dsts[8], srcv[8];
#pragma unroll
    for (int i = 0; i < 8; i++) {
        int e = e0 + t + i * 256;
        if (e < NE) {
            srcv[i] = ei[e];
            int d = ei[NE + e];
            dsts[i] = d;
            rank[i] = atomicAdd(&lcount[d >> 9], 1);
        } else dsts[i] = -1;
    }
    __syncthreads();
    if (t < 128) lbase[t] = lcount[t] ? atomicAdd(&gcursor[t], lcount[t]) : 0;
    __syncthreads();
#pragma unroll
    for (int i = 0; i < 8; i++) {
        if (dsts[i] >= 0) {
            int b = dsts[i] >> 9;
            ebuf[lbase[b] + rank[i]] =
                ((unsigned int)dsts[i] << 16) | (unsigned int)srcv[i];
        }
    }
}

// ---------------- bucket build: per-bucket rowptr + ordered u16 srcs ----------------
__global__ __launch_bounds__(512) void bucket_build(
    const unsigned int* __restrict__ ebuf, const int* __restrict__ bbase,
    int* __restrict__ rowptr, unsigned short* __restrict__ srcs) {
    __shared__ int cnt[512];
    int b = blockIdx.x;
    int t = threadIdx.x;
    int n0 = b * 512;
    int n1 = (b + 1) * 512; if (n1 > NN) n1 = NN;
    int beg = bbase[b], end = bbase[b + 1];
    cnt[t] = 0;
    __syncthreads();
    for (int e = beg + t; e < end; e += 512)
        atomicAdd(&cnt[(ebuf[e] >> 16) - n0], 1);
    __syncthreads();
    for (int off = 1; off < 512; off <<= 1) {
        int v = (t >= off) ? cnt[t - off] : 0;
        __syncthreads();
        cnt[t] += v;
        __syncthreads();
    }
    int excl = (t > 0) ? cnt[t - 1] : 0;
    __syncthreads();
    int base = beg + excl;
    if (t < n1 - n0) rowptr[n0 + t] = base;
    if (b == NB - 1 && t == 0) rowptr[NN] = NE;
    cnt[t] = base;
    __syncthreads();
    for (int e = beg + t; e < end; e += 512) {
        unsigned int u = ebuf[e];
        int pos = atomicAdd(&cnt[(u >> 16) - n0], 1);
        srcs[pos] = (unsigned short)(u & 0xffffu);
    }
}

// ---------------- weight convert+transpose to bf16: WT[n][k] = bf16(W[k][n]) ----------------
__global__ __launch_bounds__(256) void wconv(
    const float* __restrict__ Wq, const float* __restrict__ Wk,
    const float* __restrict__ Wv, const float* __restrict__ Wo,
    const float* __restrict__ W1, const float* __restrict__ W2,
    __hip_bfloat16* __restrict__ dst) {
    int y = blockIdx.y;
    int i = blockIdx.x * 256 + threadIdx.x;
    const float* W; __hip_bfloat16* D; int K, N;
    if (y == 0)      { W = Wq; D = dst;                 K = 96;  N = 96;  }
    else if (y == 1) { W = Wk; D = dst + 9216;          K = 96;  N = 96;  }
    else if (y == 2) { W = Wv; D = dst + 18432;         K = 96;  N = 96;  }
    else if (y == 3) { W = Wo; D = dst + 27648;         K = 96;  N = 96;  }
    else if (y == 4) { W = W1; D = dst + 36864;         K = 96;  N = 384; }
    else             { W = W2; D = dst + 36864 + 36864; K = 384; N = 96;  }
    if (i < K * N) {
        int n = i / K, k = i % K;
        D[i] = __float2bfloat16(W[k * N + n]);
    }
}

// ---------------- fused LN1 + QKV ----------------
// Block: 256 thr, 128 rows. LN(x rows) -> LDS A-tile (bf16) once; then 3 MFMA
// passes (Wq/Wk/Wv slabs staged in LDS) writing qbf (bf16 flat) and kv (fp8
// interleaved [node][h][k0..11,v0..11]).
__global__ __launch_bounds__(256) void lnqkv(
    const float* __restrict__ x, const float* __restrict__ g1,
    const float* __restrict__ bb1, const __hip_bfloat16* __restrict__ wbuf,
    const float* __restrict__ bq, const float* __restrict__ bk,
    const float* __restrict__ bv,
    __hip_bfloat16* __restrict__ qbf, unsigned char* __restrict__ kv) {
    __shared__ __hip_bfloat16 As[128][104];
    __shared__ __hip_bfloat16 Bs[96][104];
    int t = threadIdx.x, lane = t & 63, wave = t >> 6;
    int row0 = blockIdx.x * 128;
    // --- LN phase: each wave normalizes 32 rows ---
    for (int r = wave * 32; r < wave * 32 + 32; r++) {
        int row = row0 + r;
        if (row < NN) {
            const float* xr = x + (size_t)row * HIDD;
            float v0 = xr[lane];
            float v1 = (lane < 32) ? xr[64 + lane] : 0.0f;
            float s = v0 + v1, q = v0 * v0 + v1 * v1;
#pragma unroll
            for (int o = 32; o > 0; o >>= 1) {
                s += __shfl_xor(s, o);
                q += __shfl_xor(q, o);
            }
            float mean = s * (1.0f / 96.0f);
            float var = q * (1.0f / 96.0f) - mean * mean;
            float rs = rsqrtf(var + 1e-5f);
            As[r][lane] = __float2bfloat16((v0 - mean) * rs * g1[lane] + bb1[lane]);
            if (lane < 32)
                As[r][64 + lane] =
                    __float2bfloat16((v1 - mean) * rs * g1[64 + lane] + bb1[64 + lane]);
        } else {
            As[r][lane] = __float2bfloat16(0.0f);
            if (lane < 32) As[r][64 + lane] = __float2bfloat16(0.0f);
        }
    }
    __syncthreads();

    int lr = lane & 15, kg = lane >> 4;
    bool val0 = (row0 + wave * 32 + 16 <= NN);
    bool val1 = (row0 + wave * 32 + 32 <= NN);
    for (int y = 0; y < 3; y++) {
        // stage weight slab
        const __hip_bfloat16* slab = wbuf + y * 9216;
        for (int i = t * 8; i < 96 * 96; i += 256 * 8) {
            int r = i / 96, c = i % 96;
            *(short8*)&Bs[r][c] = *(const short8*)&slab[r * 96 + c];
        }
        __syncthreads();
        f32x4 acc[2][6];
#pragma unroll
        for (int f = 0; f < 2; f++)
#pragma unroll
            for (int ct = 0; ct < 6; ct++) acc[f][ct] = (f32x4){0.f, 0.f, 0.f, 0.f};
#pragma unroll
        for (int kc = 0; kc < 96; kc += 32) {
            short8 a0 = *(const short8*)&As[wave * 32 + lr][kc + kg * 8];
            short8 a1 = *(const short8*)&As[wave * 32 + 16 + lr][kc + kg * 8];
#pragma unroll
            for (int ct = 0; ct < 6; ct++) {
                short8 bf_ = *(const short8*)&Bs[ct * 16 + lr][kc + kg * 8];
                acc[0][ct] = __builtin_amdgcn_mfma_f32_16x16x32_bf16(a0, bf_, acc[0][ct], 0, 0, 0);
                acc[1][ct] = __builtin_amdgcn_mfma_f32_16x16x32_bf16(a1, bf_, acc[1][ct], 0, 0, 0);
            }
        }
        const float* bias = (y == 0) ? bq : (y == 1) ? bk : bv;
        int koff = (y == 2) ? 12 : 0;
#pragma unroll
        for (int f = 0; f < 2; f++) {
            if (f == 0 ? !val0 : !val1) continue;
            int crow = row0 + wave * 32 + f * 16 + kg * 4;
#pragma unroll
            for (int ct = 0; ct < 6; ct++) {
                int col = ct * 16 + lr;
                float bb = bias[col];
#pragma unroll
                for (int r = 0; r < 4; r++) {
                    float o = acc[f][ct][r] + bb;
                    if (y == 0) {
                        qbf[(size_t)(crow + r) * HIDD + col] = __float2bfloat16(o);
                    } else {
                        unsigned int enc =
                            (unsigned int)__builtin_amdgcn_cvt_pk_fp8_f32(o, o, 0, false);
                        kv[(size_t)(crow + r) * 192 + (col / 12) * 24 + koff + (col % 12)]
                            = (unsigned char)(enc & 0xffu);
                    }
                }
            }
        }
        __syncthreads();
    }
}

// ---------------- MFMA GEMM body (LDS-staged B) ----------------
// SMODE: 0 = fp32 flat, 1 = bf16 flat
template<int K, int EPI, int SMODE>
__device__ __forceinline__ void gemm_body(
    const __hip_bfloat16* __restrict__ A, const __hip_bfloat16* __restrict__ BT,
    const float* __restrict__ bias, const float* __restrict__ R,
    void* __restrict__ Cptr, int ldc, int col0) {
    constexpr int BK = (K > 192) ? 192 : K;
    __shared__ __hip_bfloat16 Bs[96][BK + 8];
    int t = threadIdx.x;
    int lane = t & 63, wave = t >> 6;
    int row0 = blockIdx.x * 128 + wave * 32;
    int lr = lane & 15, kg = lane >> 4;
    bool val0 = (row0 + 16 <= NN);
    bool val1 = (row0 + 32 <= NN);
    int ra0 = val0 ? row0 : 0;
    int ra1 = val1 ? (row0 + 16) : 0;
    const __hip_bfloat16* A0 = A + (size_t)(ra0 + lr) * K + kg * 8;
    const __hip_bfloat16* A1 = A + (size_t)(ra1 + lr) * K + kg * 8;
    f32x4 acc[2][6];
#pragma unroll
    for (int f = 0; f < 2; f++)
#pragma unroll
        for (int ct = 0; ct < 6; ct++) acc[f][ct] = (f32x4){0.f, 0.f, 0.f, 0.f};

    for (int k0 = 0; k0 < K; k0 += BK) {
        for (int i = t * 8; i < 96 * BK; i += 256 * 8) {
            int r = i / BK, c = i % BK;
            *(short8*)&Bs[r][c] = *(const short8*)&BT[(size_t)r * K + k0 + c];
        }
        __syncthreads();
#pragma unroll
        for (int kc = 0; kc < BK; kc += 32) {
            short8 a0 = *(const short8*)(A0 + k0 + kc);
            short8 a1 = *(const short8*)(A1 + k0 + kc);
#pragma unroll
            for (int ct = 0; ct < 6; ct++) {
                short8 bf_ = *(const short8*)&Bs[ct * 16 + lr][kc + kg * 8];
                acc[0][ct] = __builtin_amdgcn_mfma_f32_16x16x32_bf16(a0, bf_, acc[0][ct], 0, 0, 0);
                acc[1][ct] = __builtin_amdgcn_mfma_f32_16x16x32_bf16(a1, bf_, acc[1][ct], 0, 0, 0);
            }
        }
        __syncthreads();
    }

#pragma unroll
    for (int f = 0; f < 2; f++) {
        if (f == 0 ? !val0 : !val1) continue;
        int crow = row0 + f * 16 + kg * 4;
#pragma unroll
        for (int ct = 0; ct < 6; ct++) {
            int col = col0 + ct * 16 + lr;
            float bb = bias[col];
#pragma unroll
            for (int r = 0; r < 4; r++) {
                float o = acc[f][ct][r] + bb;
                if (EPI == 1)
                    o = 0.5f * o * (1.0f + erff(o * 0.70710678118654752f));
                if (EPI == 2)
                    o += R[(size_t)(crow + r) * 96 + col];
                if (SMODE == 0)
                    ((float*)Cptr)[(size_t)(crow + r) * ldc + col] = o;
                else
                    ((__hip_bfloat16*)Cptr)[(size_t)(crow + r) * ldc + col] = __float2bfloat16(o);
            }
        }
    }
}

template<int K, int EPI, int SMODE>
__global__ __launch_bounds__(256) void mfma_gemm(
    const __hip_bfloat16* __restrict__ A, const __hip_bfloat16* __restrict__ BT,
    const float* __restrict__ bias, const float* __restrict__ R,
    void* __restrict__ Cptr, int ldc) {
    int col0 = blockIdx.y * 96;
    gemm_body<K, EPI, SMODE>(A, BT + (size_t)col0 * K, bias, R, Cptr, ldc, col0);
}

// ---------------- proj + LN2 fused ----------------
__global__ __launch_bounds__(256) void proj_ln(
    const __hip_bfloat16* __restrict__ A, const __hip_bfloat16* __restrict__ BT,
    const float* __restrict__ bias, const float* __restrict__ R,
    const float* __restrict__ g2, const float* __restrict__ b2v,
    float* __restrict__ x2, __hip_bfloat16* __restrict__ ybf) {
    constexpr int K = 96;
    __shared__ __hip_bfloat16 Bs[96][K + 8];
    int t = threadIdx.x;
    int lane = t & 63, wave = t >> 6;
    int row0 = blockIdx.x * 128 + wave * 32;
    int lr = lane & 15, kg = lane >> 4;
    bool val0 = (row0 + 16 <= NN);
    bool val1 = (row0 + 32 <= NN);
    int ra0 = val0 ? row0 : 0;
    int ra1 = val1 ? (row0 + 16) : 0;
    const __hip_bfloat16* A0 = A + (size_t)(ra0 + lr) * K + kg * 8;
    const __hip_bfloat16* A1 = A + (size_t)(ra1 + lr) * K + kg * 8;
    f32x4 acc[2][6];
#pragma unroll
    for (int f = 0; f < 2; f++)
#pragma unroll
        for (int ct = 0; ct < 6; ct++) acc[f][ct] = (f32x4){0.f, 0.f, 0.f, 0.f};

    for (int i = t * 8; i < 96 * K; i += 256 * 8) {
        int r = i / K, c = i % K;
        *(short8*)&Bs[r][c] = *(const short8*)&BT[(size_t)r * K + c];
    }
    __syncthreads();
#pragma unroll
    for (int kc = 0; kc < K; kc += 32) {
        short8 a0 = *(const short8*)(A0 + kc);
        short8 a1 = *(const short8*)(A1 + kc);
#pragma unroll
        for (int ct = 0; ct < 6; ct++) {
            short8 bf_ = *(const short8*)&Bs[ct * 16 + lr][kc + kg * 8];
            acc[0][ct] = __builtin_amdgcn_mfma_f32_16x16x32_bf16(a0, bf_, acc[0][ct], 0, 0, 0);
            acc[1][ct] = __builtin_amdgcn_mfma_f32_16x16x32_bf16(a1, bf_, acc[1][ct], 0, 0, 0);
        }
    }

    float bo_[6], gv[6], bv_[6];
#pragma unroll
    for (int ct = 0; ct < 6; ct++) {
        int col = ct * 16 + lr;
        bo_[ct] = bias[col];
        gv[ct]  = g2[col];
        bv_[ct] = b2v[col];
    }
#pragma unroll
    for (int f = 0; f < 2; f++) {
        if (f == 0 ? !val0 : !val1) continue;
        int crow = row0 + f * 16 + kg * 4;
#pragma unroll
        for (int r = 0; r < 4; r++) {
            int row = crow + r;
            float o[6], s1 = 0.f, s2 = 0.f;
#pragma unroll
            for (int ct = 0; ct < 6; ct++) {
                int col = ct * 16 + lr;
                float val = acc[f][ct][r] + bo_[ct] + R[(size_t)row * 96 + col];
                o[ct] = val; s1 += val; s2 += val * val;
            }
#pragma unroll
            for (int m = 1; m < 16; m <<= 1) {
                s1 += __shfl_xor(s1, m);
                s2 += __shfl_xor(s2, m);
            }
            float mu = s1 * (1.0f / 96.0f);
            float var = s2 * (1.0f / 96.0f) - mu * mu;
            float rs = rsqrtf(var + 1e-5f);
#pragma unroll
            for (int ct = 0; ct < 6; ct++) {
                int col = ct * 16 + lr;
                x2[(size_t)row * 96 + col] = o[ct];
                ybf[(size_t)row * 96 + col] =
                    __float2bfloat16((o[ct] - mu) * rs * gv[ct] + bv_[ct]);
            }
        }
    }
}

// ---------------- Sparse attention gather (fp8 kv interleaved, u16 srcs) ----------------
__global__ __launch_bounds__(256) void attn_gather(
    const __hip_bfloat16* __restrict__ qbf, const unsigned char* __restrict__ kv,
    const int* __restrict__ rowptr, const unsigned short* __restrict__ srcs,
    __hip_bfloat16* __restrict__ abf) {
    int wave = (blockIdx.x * blockDim.x + threadIdx.x) >> 6;
    int lane = threadIdx.x & 63;
    if (wave >= NN) return;
    int dst = wave;
    int h = lane & 7;
    int eslot = lane >> 3;
    float qf[12];
    {
        const uint2* qp = (const uint2*)(qbf + (size_t)dst * HIDD + h * HD);
        uint2 u0 = qp[0], u1 = qp[1], u2 = qp[2];
        unsigned int w[6] = {u0.x, u0.y, u1.x, u1.y, u2.x, u2.y};
#pragma unroll
        for (int i = 0; i < 6; i++) {
            qf[2 * i]     = bf2f((unsigned short)(w[i] & 0xffffu));
            qf[2 * i + 1] = bf2f((unsigned short)(w[i] >> 16));
        }
    }
    int beg = rowptr[dst], end = rowptr[dst + 1];
    float acc[12];
#pragma unroll
    for (int i = 0; i < 12; i++) acc[i] = 0.0f;
    float zz = 0.0f;
    for (int e = beg + eslot; e < end; e += 8) {
        int src = (int)srcs[e];
        const uint2* kp = (const uint2*)(kv + (size_t)src * 192 + h * 24);
        uint2 wA = kp[0], wB = kp[1], wC = kp[2];
        f32x2 p;
        float dot = 0.0f;
        p = __builtin_amdgcn_cvt_pk_f32_fp8(wA.x, false); dot += p[0] * qf[0]  + p[1] * qf[1];
        p = __builtin_amdgcn_cvt_pk_f32_fp8(wA.x, true);  dot += p[0] * qf[2]  + p[1] * qf[3];
        p = __builtin_amdgcn_cvt_pk_f32_fp8(wA.y, false); dot += p[0] * qf[4]  + p[1] * qf[5];
        p = __builtin_amdgcn_cvt_pk_f32_fp8(wA.y, true);  dot += p[0] * qf[6]  + p[1] * qf[7];
        p = __builtin_amdgcn_cvt_pk_f32_fp8(wB.x, false); dot += p[0] * qf[8]  + p[1] * qf[9];
        p = __builtin_amdgcn_cvt_pk_f32_fp8(wB.x, true);  dot += p[0] * qf[10] + p[1] * qf[11];
        float s = fminf(fmaxf(dot * INV_SCALE, -5.0f), 5.0f);
        float sc = expf(s);
        p = __builtin_amdgcn_cvt_pk_f32_fp8(wB.y, false); acc[0]  += p[0] * sc; acc[1]  += p[1] * sc;
        p = __builtin_amdgcn_cvt_pk_f32_fp8(wB.y, true);  acc[2]  += p[0] * sc; acc[3]  += p[1] * sc;
        p = __builtin_amdgcn_cvt_pk_f32_fp8(wC.x, false); acc[4]  += p[0] * sc; acc[5]  += p[1] * sc;
        p = __builtin_amdgcn_cvt_pk_f32_fp8(wC.x, true);  acc[6]  += p[0] * sc; acc[7]  += p[1] * sc;
        p = __builtin_amdgcn_cvt_pk_f32_fp8(wC.y, false); acc[8]  += p[0] * sc; acc[9]  += p[1] * sc;
        p = __builtin_amdgcn_cvt_pk_f32_fp8(wC.y, true);  acc[10] += p[0] * sc; acc[11] += p[1] * sc;
        zz += sc;
    }
#pragma unroll
    for (int m = 8; m < 64; m <<= 1) {
#pragma unroll
        for (int i = 0; i < 12; i++) acc[i] += __shfl_xor(acc[i], m);
        zz += __shfl_xor(zz, m);
    }
    if (eslot == 0) {
        float inv = 1.0f / (zz + 1e-6f);
        __hip_bfloat16* ar = abf + (size_t)dst * HIDD + h * HD;
#pragma unroll
        for (int i = 0; i < 12; i++) ar[i] = __float2bfloat16(acc[i] * inv);
    }
}

extern "C" void kernel_launch(void* const* d_in, const int* in_sizes, int n_in,
                              void* d_out, int out_size, void* d_ws, size_t ws_size,
                              hipStream_t stream) {
    const float* x     = (const float*)d_in[0];
    const int*   ei    = (const int*)d_in[1];
    const float* ln1_g = (const float*)d_in[2];
    const float* ln1_b = (const float*)d_in[3];
    const float* Wq    = (const float*)d_in[4];
    const float* bq    = (const float*)d_in[5];
    const float* Wk    = (const float*)d_in[6];
    const float* bk    = (const float*)d_in[7];
    const float* Wv    = (const float*)d_in[8];
    const float* bv    = (const float*)d_in[9];
    const float* Wo    = (const float*)d_in[10];
    const float* bo    = (const float*)d_in[11];
    const float* ln2_g = (const float*)d_in[12];
    const float* ln2_b = (const float*)d_in[13];
    const float* W1    = (const float*)d_in[14];
    const float* b1    = (const float*)d_in[15];
    const float* W2    = (const float*)d_in[16];
    const float* b2    = (const float*)d_in[17];
    float* out = (float*)d_out;

    // Workspace layout (float units, NF = NN*96 = 4.8M floats):
    //   qbf  bf16 [0, 0.5NF)
    //   kv   fp8  [0.5NF, NF)       (NN*192 bytes)
    //   abf  bf16 [1.5NF, 2NF)
    //   hbf  bf16 [0, 2NF)          aliases qbf/kv/abf (dead by ffn1)
    //   x2   fp32 [2NF, 3NF)
    //   ybf  bf16 [3NF, 3.5NF)
    //   CSR at 3.5NF: rowptr[NN+1] int, srcs[NE] u16, bcnt[128], bbase[129],
    //                 gcursor[128], ebuf[NE] u32   (~5 MB, fits in 0.5NF)
    //   wbuf bf16 at 4NF   (110592 bf16)
    float* ws = (float*)d_ws;
    const size_t NF = (size_t)NN * HIDD;
    __hip_bfloat16* qbf = (__hip_bfloat16*)ws;
    unsigned char*  kv  = (unsigned char*)(ws + NF / 2);
    __hip_bfloat16* abf = (__hip_bfloat16*)(ws + NF / 2 + NF);
    __hip_bfloat16* hbf = (__hip_bfloat16*)ws;
    float* x2 = ws + 2 * NF;
    __hip_bfloat16* ybf = (__hip_bfloat16*)(ws + 3 * NF);
    int* ibase = (int*)(ws + 3 * NF + NF / 2);
    int* rowptr = ibase;                       // NN+1
    unsigned short* srcs = (unsigned short*)(ibase + NN + 1);   // NE u16 = NE/2 ints
    int* bcnt    = ibase + NN + 1 + NE / 2;    // 128
    int* bbase   = bcnt + 128;                 // 129
    int* gcursor = bbase + 129;                // 128
    unsigned int* ebuf = (unsigned int*)(gcursor + 128);        // NE u32
    __hip_bfloat16* wbuf = (__hip_bfloat16*)(ws + 4 * NF);
    __hip_bfloat16* WoT = wbuf + 27648;
    __hip_bfloat16* W1T = wbuf + 36864;
    __hip_bfloat16* W2T = wbuf + 73728;

    const int MT = (NN + 127) / 128;             // 391

    // --- CSR build (bucketized, scan-free) ---
    zero_kernel<<<1, 128, 0, stream>>>(bcnt, 128);
    bucket_count<<<(NE + 1023) / 1024, 256, 0, stream>>>(ei, bcnt);
    bucket_scan<<<1, 128, 0, stream>>>(bcnt, bbase, gcursor);
    bucket_scatter<<<(NE + 2047) / 2048, 256, 0, stream>>>(ei, gcursor, ebuf);
    bucket_build<<<NB, 512, 0, stream>>>(ebuf, bbase, rowptr, srcs);

    // --- weights -> bf16 transposed ---
    {
        dim3 g((36864 + 255) / 256, 6);
        wconv<<<g, 256, 0, stream>>>(Wq, Wk, Wv, Wo, W1, W2, wbuf);
    }

    // --- transformer block ---
    lnqkv<<<MT, 256, 0, stream>>>(x, ln1_g, ln1_b, wbuf, bq, bk, bv, qbf, kv);
    attn_gather<<<(NN + 3) / 4, 256, 0, stream>>>(qbf, kv, rowptr, srcs, abf);
    proj_ln<<<MT, 256, 0, stream>>>(abf, WoT, bo, x, ln2_g, ln2_b, x2, ybf);
    {
        dim3 g(MT, 4);
        mfma_gemm<96, 1, 1><<<g, 256, 0, stream>>>(ybf, W1T, b1, nullptr, hbf, FFND);
    }
    mfma_gemm<384, 2, 0><<<MT, 256, 0, stream>>>(hbf, W2T, b2, x2, out, 96);
}

// Round 9
// 184.746 us; speedup vs baseline: 21.1645x; 1.0609x over previous
//
#include <hip/hip_runtime.h>
#include <hip/hip_bf16.h>
#include <math.h>

#define NN 50000
#define HIDD 96
#define NH 8
#define HD 12
#define FFND 384
#define NE 800000
#define NB 98           // buckets of 512 dst nodes

#define INV_SCALE 0.28867513459481287f

typedef short short8 __attribute__((ext_vector_type(8)));
typedef float f32x4 __attribute__((ext_vector_type(4)));
typedef float f32x2 __attribute__((ext_vector_type(2)));

__device__ __forceinline__ float bf2f(unsigned short u) {
    union { unsigned int i; float f; } c;
    c.i = ((unsigned int)u) << 16;
    return c.f;
}

// ---------------- zero kernel ----------------
__global__ void zero_kernel(int* __restrict__ p, int n) {
    int i = blockIdx.x * blockDim.x + threadIdx.x;
    if (i < n) p[i] = 0;
}

// ---------------- bucket histogram (128 bins, LDS-reduced) ----------------
__global__ __launch_bounds__(256) void bucket_count(const int* __restrict__ ei,
                                                    int* __restrict__ bcnt) {
    __shared__ int h[128];
    int t = threadIdx.x;
    if (t < 128) h[t] = 0;
    __syncthreads();
#pragma unroll
    for (int i = 0; i < 4; i++) {
        int e = blockIdx.x * 1024 + t + i * 256;
        if (e < NE) atomicAdd(&h[ei[NE + e] >> 9], 1);
    }
    __syncthreads();
    if (t < 128 && h[t]) atomicAdd(&bcnt[t], h[t]);
}

// ---------------- scan 128 bucket counts; init bbase + gcursor ----------------
__global__ __launch_bounds__(128) void bucket_scan(const int* __restrict__ bcnt,
                                                   int* __restrict__ bbase,
                                                   int* __restrict__ gcursor) {
    __shared__ int s[128];
    int t = threadIdx.x;
    s[t] = bcnt[t];
    __syncthreads();
    for (int off = 1; off < 128; off <<= 1) {
        int v = (t >= off) ? s[t - off] : 0;
        __syncthreads();
        s[t] += v;
        __syncthreads();
    }
    int excl = (t > 0) ? s[t - 1] : 0;
    bbase[t] = excl;
    gcursor[t] = excl;
    if (t == 127) bbase[128] = s[127];
}

// ---------------- bucket scatter pass A: edges -> bucket-major ebuf (u32 packed) ----------------
__global__ __launch_bounds__(256) void bucket_scatter(
    const int* __restrict__ ei, int* __restrict__ gcursor,
    unsigned int* __restrict__ ebuf) {
    __shared__ int lcount[128];
    __shared__ int lbase[128];
    int t = threadIdx.x;
    int e0 = blockIdx.x * 2048;
    if (t < 128) lcount[t] = 0;
    __syncthreads();
    int rank[8], dsts[8], srcv[8];
#pragma unroll
    for (int i = 0; i < 8; i++) {
        int e = e0 + t + i * 256;
        if (e < NE) {
            srcv[i] = ei[e];
            int d = ei[NE + e];
            dsts[i] = d;
            rank[i] = atomicAdd(&lcount[d >> 9], 1);
        } else dsts[i] = -1;
    }
    __syncthreads();
    if (t < 128) lbase[t] = lcount[t] ? atomicAdd(&gcursor[t], lcount[t]) : 0;
    __syncthreads();
#pragma unroll
    for (int i = 0; i < 8; i++) {
        if (dsts[i] >= 0) {
            int b = dsts[i] >> 9;
            ebuf[lbase[b] + rank[i]] =
                ((unsigned int)dsts[i] << 16) | (unsigned int)srcv[i];
        }
    }
}

// ---------------- bucket build: per-bucket rowptr + ordered u16 srcs ----------------
__global__ __launch_bounds__(512) void bucket_build(
    const unsigned int* __restrict__ ebuf, const int* __restrict__ bbase,
    int* __restrict__ rowptr, unsigned short* __restrict__ srcs) {
    __shared__ int cnt[512];
    int b = blockIdx.x;
    int t = threadIdx.x;
    int n0 = b * 512;
    int n1 = (b + 1) * 512; if (n1 > NN) n1 = NN;
    int beg = bbase[b], end = bbase[b + 1];
    cnt[t] = 0;
    __syncthreads();
    for (int e = beg + t; e < end; e += 512)
        atomicAdd(&cnt[(ebuf[e] >> 16) - n0], 1);
    __syncthreads();
    for (int off = 1; off < 512; off <<= 1) {
        int v = (t >= off) ? cnt[t - off] : 0;
        __syncthreads();
        cnt[t] += v;
        __syncthreads();
    }
    int excl = (t > 0) ? cnt[t - 1] : 0;
    __syncthreads();
    int base = beg + excl;
    if (t < n1 - n0) rowptr[n0 + t] = base;
    if (b == NB - 1 && t == 0) rowptr[NN] = NE;
    cnt[t] = base;
    __syncthreads();
    for (int e = beg + t; e < end; e += 512) {
        unsigned int u = ebuf[e];
        int pos = atomicAdd(&cnt[(u >> 16) - n0], 1);
        srcs[pos] = (unsigned short)(u & 0xffffu);
    }
}

// ---------------- weight convert+transpose to bf16: WT[n][k] = bf16(W[k][n]) ----------------
__global__ __launch_bounds__(256) void wconv(
    const float* __restrict__ Wq, const float* __restrict__ Wk,
    const float* __restrict__ Wv, const float* __restrict__ Wo,
    const float* __restrict__ W1, const float* __restrict__ W2,
    __hip_bfloat16* __restrict__ dst) {
    int y = blockIdx.y;
    int i = blockIdx.x * 256 + threadIdx.x;
    const float* W; __hip_bfloat16* D; int K, N;
    if (y == 0)      { W = Wq; D = dst;                 K = 96;  N = 96;  }
    else if (y == 1) { W = Wk; D = dst + 9216;          K = 96;  N = 96;  }
    else if (y == 2) { W = Wv; D = dst + 18432;         K = 96;  N = 96;  }
    else if (y == 3) { W = Wo; D = dst + 27648;         K = 96;  N = 96;  }
    else if (y == 4) { W = W1; D = dst + 36864;         K = 96;  N = 384; }
    else             { W = W2; D = dst + 36864 + 36864; K = 384; N = 96;  }
    if (i < K * N) {
        int n = i / K, k = i % K;
        D[i] = __float2bfloat16(W[k * N + n]);
    }
}

// ---------------- LayerNorm: one wave per row, bf16 output ----------------
__global__ void ln_kernel(const float* __restrict__ x, const float* __restrict__ g,
                          const float* __restrict__ b, __hip_bfloat16* __restrict__ y,
                          int nrows) {
    int wave = (blockIdx.x * blockDim.x + threadIdx.x) >> 6;
    int lane = threadIdx.x & 63;
    if (wave >= nrows) return;
    const float* xr = x + (size_t)wave * HIDD;
    float v0 = xr[lane];
    float v1 = (lane < 32) ? xr[64 + lane] : 0.0f;
    float s = v0 + v1;
    float q = v0 * v0 + v1 * v1;
    for (int o = 32; o > 0; o >>= 1) {
        s += __shfl_xor(s, o);
        q += __shfl_xor(q, o);
    }
    float mean = s * (1.0f / 96.0f);
    float var = q * (1.0f / 96.0f) - mean * mean;
    float rs = rsqrtf(var + 1e-5f);
    __hip_bfloat16* yr = y + (size_t)wave * HIDD;
    yr[lane] = __float2bfloat16((v0 - mean) * rs * g[lane] + b[lane]);
    if (lane < 32)
        yr[64 + lane] = __float2bfloat16((v1 - mean) * rs * g[64 + lane] + b[64 + lane]);
}

// ---------------- MFMA GEMM body (LDS-staged B) ----------------
// C = A[M x K](bf16) @ BT[96-col slab x K]^T + bias (+ epilogue)
// Block: 256 thr = 4 waves, BM=128; wave owns 32 rows (2x 16-row frags) x 96 cols.
// NOTE: no early return — all waves must stage B and hit barriers.
// C/D frag: col = lane&15, row = (lane>>4)*4 + reg   [m89-verified]
// SMODE: 0 = fp32 flat, 1 = bf16 flat, 2 = fp8 kv-interleaved (+koff)
template<int K, int EPI, int SMODE>
__device__ __forceinline__ void gemm_body(
    const __hip_bfloat16* __restrict__ A, const __hip_bfloat16* __restrict__ BT,
    const float* __restrict__ bias, const float* __restrict__ R,
    void* __restrict__ Cptr, int ldc, int col0, int koff) {
    constexpr int BK = (K > 192) ? 192 : K;
    __shared__ __hip_bfloat16 Bs[96][BK + 8];
    int t = threadIdx.x;
    int lane = t & 63, wave = t >> 6;
    int row0 = blockIdx.x * 128 + wave * 32;
    int lr = lane & 15, kg = lane >> 4;
    bool val0 = (row0 + 16 <= NN);
    bool val1 = (row0 + 32 <= NN);
    int ra0 = val0 ? row0 : 0;
    int ra1 = val1 ? (row0 + 16) : 0;
    const __hip_bfloat16* A0 = A + (size_t)(ra0 + lr) * K + kg * 8;
    const __hip_bfloat16* A1 = A + (size_t)(ra1 + lr) * K + kg * 8;
    f32x4 acc[2][6];
#pragma unroll
    for (int f = 0; f < 2; f++)
#pragma unroll
        for (int ct = 0; ct < 6; ct++) acc[f][ct] = (f32x4){0.f, 0.f, 0.f, 0.f};

    for (int k0 = 0; k0 < K; k0 += BK) {
        for (int i = t * 8; i < 96 * BK; i += 256 * 8) {
            int r = i / BK, c = i % BK;
            *(short8*)&Bs[r][c] = *(const short8*)&BT[(size_t)r * K + k0 + c];
        }
        __syncthreads();
#pragma unroll
        for (int kc = 0; kc < BK; kc += 32) {
            short8 a0 = *(const short8*)(A0 + k0 + kc);
            short8 a1 = *(const short8*)(A1 + k0 + kc);
#pragma unroll
            for (int ct = 0; ct < 6; ct++) {
                short8 bf_ = *(const short8*)&Bs[ct * 16 + lr][kc + kg * 8];
                acc[0][ct] = __builtin_amdgcn_mfma_f32_16x16x32_bf16(a0, bf_, acc[0][ct], 0, 0, 0);
                acc[1][ct] = __builtin_amdgcn_mfma_f32_16x16x32_bf16(a1, bf_, acc[1][ct], 0, 0, 0);
            }
        }
        __syncthreads();
    }

#pragma unroll
    for (int f = 0; f < 2; f++) {
        if (f == 0 ? !val0 : !val1) continue;
        int crow = row0 + f * 16 + kg * 4;
#pragma unroll
        for (int ct = 0; ct < 6; ct++) {
            int col = col0 + ct * 16 + lr;
            float bb = bias[col];
#pragma unroll
            for (int r = 0; r < 4; r++) {
                float o = acc[f][ct][r] + bb;
                if (EPI == 1)
                    o = 0.5f * o * (1.0f + erff(o * 0.70710678118654752f));
                if (EPI == 2)
                    o += R[(size_t)(crow + r) * 96 + col];
                if (SMODE == 0)
                    ((float*)Cptr)[(size_t)(crow + r) * ldc + col] = o;
                else if (SMODE == 1)
                    ((__hip_bfloat16*)Cptr)[(size_t)(crow + r) * ldc + col] = __float2bfloat16(o);
                else {
                    unsigned int enc = (unsigned int)__builtin_amdgcn_cvt_pk_fp8_f32(o, o, 0, false);
                    ((unsigned char*)Cptr)[(size_t)(crow + r) * 192 + ((col - col0) / 12) * 24 + koff + ((col - col0) % 12)]
                        = (unsigned char)(enc & 0xffu);
                }
            }
        }
    }
}

template<int K, int EPI, int SMODE>
__global__ __launch_bounds__(256) void mfma_gemm(
    const __hip_bfloat16* __restrict__ A, const __hip_bfloat16* __restrict__ BT,
    const float* __restrict__ bias, const float* __restrict__ R,
    void* __restrict__ Cptr, int ldc) {
    int col0 = blockIdx.y * 96;
    gemm_body<K, EPI, SMODE>(A, BT + (size_t)col0 * K, bias, R, Cptr, ldc, col0, 0);
}

// fused q/k/v: blockIdx.y selects weight slab / bias / output layout
__global__ __launch_bounds__(256) void qkv_mfma(
    const __hip_bfloat16* __restrict__ A, const __hip_bfloat16* __restrict__ wbuf,
    const float* __restrict__ bq, const float* __restrict__ bk,
    const float* __restrict__ bv,
    __hip_bfloat16* __restrict__ qbf, unsigned char* __restrict__ kv) {
    int y = blockIdx.y;
    if (y == 0)
        gemm_body<96, 0, 1>(A, wbuf, bq, nullptr, qbf, 96, 0, 0);
    else if (y == 1)
        gemm_body<96, 0, 2>(A, wbuf + 9216, bk, nullptr, kv, 0, 0, 0);
    else
        gemm_body<96, 0, 2>(A, wbuf + 18432, bv, nullptr, kv, 0, 0, 12);
}

// ---------------- proj + LN2 fused ----------------
__global__ __launch_bounds__(256) void proj_ln(
    const __hip_bfloat16* __restrict__ A, const __hip_bfloat16* __restrict__ BT,
    const float* __restrict__ bias, const float* __restrict__ R,
    const float* __restrict__ g2, const float* __restrict__ b2v,
    float* __restrict__ x2, __hip_bfloat16* __restrict__ ybf) {
    constexpr int K = 96;
    __shared__ __hip_bfloat16 Bs[96][K + 8];
    int t = threadIdx.x;
    int lane = t & 63, wave = t >> 6;
    int row0 = blockIdx.x * 128 + wave * 32;
    int lr = lane & 15, kg = lane >> 4;
    bool val0 = (row0 + 16 <= NN);
    bool val1 = (row0 + 32 <= NN);
    int ra0 = val0 ? row0 : 0;
    int ra1 = val1 ? (row0 + 16) : 0;
    const __hip_bfloat16* A0 = A + (size_t)(ra0 + lr) * K + kg * 8;
    const __hip_bfloat16* A1 = A + (size_t)(ra1 + lr) * K + kg * 8;
    f32x4 acc[2][6];
#pragma unroll
    for (int f = 0; f < 2; f++)
#pragma unroll
        for (int ct = 0; ct < 6; ct++) acc[f][ct] = (f32x4){0.f, 0.f, 0.f, 0.f};

    for (int i = t * 8; i < 96 * K; i += 256 * 8) {
        int r = i / K, c = i % K;
        *(short8*)&Bs[r][c] = *(const short8*)&BT[(size_t)r * K + c];
    }
    __syncthreads();
#pragma unroll
    for (int kc = 0; kc < K; kc += 32) {
        short8 a0 = *(const short8*)(A0 + kc);
        short8 a1 = *(const short8*)(A1 + kc);
#pragma unroll
        for (int ct = 0; ct < 6; ct++) {
            short8 bf_ = *(const short8*)&Bs[ct * 16 + lr][kc + kg * 8];
            acc[0][ct] = __builtin_amdgcn_mfma_f32_16x16x32_bf16(a0, bf_, acc[0][ct], 0, 0, 0);
            acc[1][ct] = __builtin_amdgcn_mfma_f32_16x16x32_bf16(a1, bf_, acc[1][ct], 0, 0, 0);
        }
    }

    float bo_[6], gv[6], bv_[6];
#pragma unroll
    for (int ct = 0; ct < 6; ct++) {
        int col = ct * 16 + lr;
        bo_[ct] = bias[col];
        gv[ct]  = g2[col];
        bv_[ct] = b2v[col];
    }
#pragma unroll
    for (int f = 0; f < 2; f++) {
        if (f == 0 ? !val0 : !val1) continue;
        int crow = row0 + f * 16 + kg * 4;
#pragma unroll
        for (int r = 0; r < 4; r++) {
            int row = crow + r;
            float o[6], s1 = 0.f, s2 = 0.f;
#pragma unroll
            for (int ct = 0; ct < 6; ct++) {
                int col = ct * 16 + lr;
                float val = acc[f][ct][r] + bo_[ct] + R[(size_t)row * 96 + col];
                o[ct] = val; s1 += val; s2 += val * val;
            }
#pragma unroll
            for (int m = 1; m < 16; m <<= 1) {
                s1 += __shfl_xor(s1, m);
                s2 += __shfl_xor(s2, m);
            }
            float mu = s1 * (1.0f / 96.0f);
            float var = s2 * (1.0f / 96.0f) - mu * mu;
            float rs = rsqrtf(var + 1e-5f);
#pragma unroll
            for (int ct = 0; ct < 6; ct++) {
                int col = ct * 16 + lr;
                x2[(size_t)row * 96 + col] = o[ct];
                ybf[(size_t)row * 96 + col] =
                    __float2bfloat16((o[ct] - mu) * rs * gv[ct] + bv_[ct]);
            }
        }
    }
}

// ---------------- Sparse attention gather (fp8 kv interleaved, u16 srcs) ----------------
__global__ __launch_bounds__(256) void attn_gather(
    const __hip_bfloat16* __restrict__ qbf, const unsigned char* __restrict__ kv,
    const int* __restrict__ rowptr, const unsigned short* __restrict__ srcs,
    __hip_bfloat16* __restrict__ abf) {
    int wave = (blockIdx.x * blockDim.x + threadIdx.x) >> 6;
    int lane = threadIdx.x & 63;
    if (wave >= NN) return;
    int dst = wave;
    int h = lane & 7;
    int eslot = lane >> 3;
    float qf[12];
    {
        const uint2* qp = (const uint2*)(qbf + (size_t)dst * HIDD + h * HD);
        uint2 u0 = qp[0], u1 = qp[1], u2 = qp[2];
        unsigned int w[6] = {u0.x, u0.y, u1.x, u1.y, u2.x, u2.y};
#pragma unroll
        for (int i = 0; i < 6; i++) {
            qf[2 * i]     = bf2f((unsigned short)(w[i] & 0xffffu));
            qf[2 * i + 1] = bf2f((unsigned short)(w[i] >> 16));
        }
    }
    int beg = rowptr[dst], end = rowptr[dst + 1];
    float acc[12];
#pragma unroll
    for (int i = 0; i < 12; i++) acc[i] = 0.0f;
    float zz = 0.0f;
    for (int e = beg + eslot; e < end; e += 8) {
        int src = (int)srcs[e];
        const uint2* kp = (const uint2*)(kv + (size_t)src * 192 + h * 24);
        uint2 wA = kp[0], wB = kp[1], wC = kp[2];
        f32x2 p;
        float dot = 0.0f;
        p = __builtin_amdgcn_cvt_pk_f32_fp8(wA.x, false); dot += p[0] * qf[0]  + p[1] * qf[1];
        p = __builtin_amdgcn_cvt_pk_f32_fp8(wA.x, true);  dot += p[0] * qf[2]  + p[1] * qf[3];
        p = __builtin_amdgcn_cvt_pk_f32_fp8(wA.y, false); dot += p[0] * qf[4]  + p[1] * qf[5];
        p = __builtin_amdgcn_cvt_pk_f32_fp8(wA.y, true);  dot += p[0] * qf[6]  + p[1] * qf[7];
        p = __builtin_amdgcn_cvt_pk_f32_fp8(wB.x, false); dot += p[0] * qf[8]  + p[1] * qf[9];
        p = __builtin_amdgcn_cvt_pk_f32_fp8(wB.x, true);  dot += p[0] * qf[10] + p[1] * qf[11];
        float s = fminf(fmaxf(dot * INV_SCALE, -5.0f), 5.0f);
        float sc = expf(s);
        p = __builtin_amdgcn_cvt_pk_f32_fp8(wB.y, false); acc[0]  += p[0] * sc; acc[1]  += p[1] * sc;
        p = __builtin_amdgcn_cvt_pk_f32_fp8(wB.y, true);  acc[2]  += p[0] * sc; acc[3]  += p[1] * sc;
        p = __builtin_amdgcn_cvt_pk_f32_fp8(wC.x, false); acc[4]  += p[0] * sc; acc[5]  += p[1] * sc;
        p = __builtin_amdgcn_cvt_pk_f32_fp8(wC.x, true);  acc[6]  += p[0] * sc; acc[7]  += p[1] * sc;
        p = __builtin_amdgcn_cvt_pk_f32_fp8(wC.y, false); acc[8]  += p[0] * sc; acc[9]  += p[1] * sc;
        p = __builtin_amdgcn_cvt_pk_f32_fp8(wC.y, true);  acc[10] += p[0] * sc; acc[11] += p[1] * sc;
        zz += sc;
    }
#pragma unroll
    for (int m = 8; m < 64; m <<= 1) {
#pragma unroll
        for (int i = 0; i < 12; i++) acc[i] += __shfl_xor(acc[i], m);
        zz += __shfl_xor(zz, m);
    }
    if (eslot == 0) {
        float inv = 1.0f / (zz + 1e-6f);
        __hip_bfloat16* ar = abf + (size_t)dst * HIDD + h * HD;
#pragma unroll
        for (int i = 0; i < 12; i++) ar[i] = __float2bfloat16(acc[i] * inv);
    }
}

extern "C" void kernel_launch(void* const* d_in, const int* in_sizes, int n_in,
                              void* d_out, int out_size, void* d_ws, size_t ws_size,
                              hipStream_t stream) {
    const float* x     = (const float*)d_in[0];
    const int*   ei    = (const int*)d_in[1];
    const float* ln1_g = (const float*)d_in[2];
    const float* ln1_b = (const float*)d_in[3];
    const float* Wq    = (const float*)d_in[4];
    const float* bq    = (const float*)d_in[5];
    const float* Wk    = (const float*)d_in[6];
    const float* bk    = (const float*)d_in[7];
    const float* Wv    = (const float*)d_in[8];
    const float* bv    = (const float*)d_in[9];
    const float* Wo    = (const float*)d_in[10];
    const float* bo    = (const float*)d_in[11];
    const float* ln2_g = (const float*)d_in[12];
    const float* ln2_b = (const float*)d_in[13];
    const float* W1    = (const float*)d_in[14];
    const float* b1    = (const float*)d_in[15];
    const float* W2    = (const float*)d_in[16];
    const float* b2    = (const float*)d_in[17];
    float* out = (float*)d_out;

    // Workspace layout (float units, NF = NN*96 = 4.8M floats):
    //   qbf  bf16 [0, 0.5NF)
    //   kv   fp8  [0.5NF, NF)       (NN*192 bytes)
    //   abf  bf16 [1.5NF, 2NF)
    //   hbf  bf16 [0, 2NF)          aliases qbf/kv/abf (dead by ffn1)
    //   x2   fp32 [2NF, 3NF)
    //   ybf  bf16 [3NF, 3.5NF)
    //   CSR at 3.5NF: rowptr[NN+1] int, srcs[NE] u16, bcnt[128], bbase[129],
    //                 gcursor[128], ebuf[NE] u32
    //   wbuf bf16 at 4NF   (110592 bf16)
    float* ws = (float*)d_ws;
    const size_t NF = (size_t)NN * HIDD;
    __hip_bfloat16* qbf = (__hip_bfloat16*)ws;
    unsigned char*  kv  = (unsigned char*)(ws + NF / 2);
    __hip_bfloat16* abf = (__hip_bfloat16*)(ws + NF / 2 + NF);
    __hip_bfloat16* hbf = (__hip_bfloat16*)ws;
    float* x2 = ws + 2 * NF;
    __hip_bfloat16* ybf = (__hip_bfloat16*)(ws + 3 * NF);
    int* ibase = (int*)(ws + 3 * NF + NF / 2);
    int* rowptr = ibase;                       // NN+1
    unsigned short* srcs = (unsigned short*)(ibase + NN + 1);   // NE u16
    int* bcnt    = ibase + NN + 1 + NE / 2;    // 128
    int* bbase   = bcnt + 128;                 // 129
    int* gcursor = bbase + 129;                // 128
    unsigned int* ebuf = (unsigned int*)(gcursor + 128);        // NE u32
    __hip_bfloat16* wbuf = (__hip_bfloat16*)(ws + 4 * NF);
    __hip_bfloat16* WoT = wbuf + 27648;
    __hip_bfloat16* W1T = wbuf + 36864;
    __hip_bfloat16* W2T = wbuf + 73728;

    const int MT = (NN + 127) / 128;             // 391

    // --- CSR build (bucketized, scan-free) ---
    zero_kernel<<<1, 128, 0, stream>>>(bcnt, 128);
    bucket_count<<<(NE + 1023) / 1024, 256, 0, stream>>>(ei, bcnt);
    bucket_scan<<<1, 128, 0, stream>>>(bcnt, bbase, gcursor);
    bucket_scatter<<<(NE + 2047) / 2048, 256, 0, stream>>>(ei, gcursor, ebuf);
    bucket_build<<<NB, 512, 0, stream>>>(ebuf, bbase, rowptr, srcs);

    // --- weights -> bf16 transposed ---
    {
        dim3 g((36864 + 255) / 256, 6);
        wconv<<<g, 256, 0, stream>>>(Wq, Wk, Wv, Wo, W1, W2, wbuf);
    }

    // --- transformer block ---
    ln_kernel<<<(NN + 3) / 4, 256, 0, stream>>>(x, ln1_g, ln1_b, ybf, NN);
    {
        dim3 g(MT, 3);
        qkv_mfma<<<g, 256, 0, stream>>>(ybf, wbuf, bq, bk, bv, qbf, kv);
    }
    attn_gather<<<(NN + 3) / 4, 256, 0, stream>>>(qbf, kv, rowptr, srcs, abf);
    proj_ln<<<MT, 256, 0, stream>>>(abf, WoT, bo, x, ln2_g, ln2_b, x2, ybf);
    {
        dim3 g(MT, 4);
        mfma_gemm<96, 1, 1><<<g, 256, 0, stream>>>(ybf, W1T, b1, nullptr, hbf, FFND);
    }
    mfma_gemm<384, 2, 0><<<MT, 256, 0, stream>>>(hbf, W2T, b2, x2, out, 96);
}

// Round 10
// 180.958 us; speedup vs baseline: 21.6076x; 1.0209x over previous
//
#include <hip/hip_runtime.h>
#include <hip/hip_bf16.h>
#include <math.h>

#define NN 50000
#define HIDD 96
#define NH 8
#define HD 12
#define FFND 384
#define NE 800000
#define NB 98           // buckets of 512 dst nodes

#define INV_SCALE 0.28867513459481287f

typedef short short8 __attribute__((ext_vector_type(8)));
typedef float f32x4 __attribute__((ext_vector_type(4)));
typedef float f32x2 __attribute__((ext_vector_type(2)));

__device__ __forceinline__ float bf2f(unsigned short u) {
    union { unsigned int i; float f; } c;
    c.i = ((unsigned int)u) << 16;
    return c.f;
}

// ---------------- P1: bucket_count ∥ wconv ∥ ln1 (independent works, one launch) ----------------
// blocks [0,782): bucket histogram; [782,1214): weight convert; [1214,13714): LN1.
__global__ __launch_bounds__(256) void prep(
    const int* __restrict__ ei, int* __restrict__ bcnt,
    const float* __restrict__ Wq, const float* __restrict__ Wk,
    const float* __restrict__ Wv, const float* __restrict__ Wo,
    const float* __restrict__ W1, const float* __restrict__ W2,
    __hip_bfloat16* __restrict__ wbuf,
    const float* __restrict__ x, const float* __restrict__ g1,
    const float* __restrict__ b1, __hip_bfloat16* __restrict__ ybf) {
    int b = blockIdx.x;
    int t = threadIdx.x;
    if (b < 782) {
        // --- bucket_count ---
        __shared__ int h[128];
        if (t < 128) h[t] = 0;
        __syncthreads();
#pragma unroll
        for (int i = 0; i < 4; i++) {
            int e = b * 1024 + t + i * 256;
            if (e < NE) atomicAdd(&h[ei[NE + e] >> 9], 1);
        }
        __syncthreads();
        if (t < 128 && h[t]) atomicAdd(&bcnt[t], h[t]);
    } else if (b < 1214) {
        // --- wconv: WT[n][k] = bf16(W[k][n]) ---
        int idx = b - 782;
        const float* W; __hip_bfloat16* D; int K, N; int i;
        if (idx < 144)      { W = W1; D = wbuf + 36864;         K = 96;  N = 384; i = idx * 256 + t; }
        else if (idx < 288) { W = W2; D = wbuf + 73728;         K = 384; N = 96;  i = (idx - 144) * 256 + t; }
        else {
            int slab = (idx - 288) / 36;
            W = (slab == 0) ? Wq : (slab == 1) ? Wk : (slab == 2) ? Wv : Wo;
            D = wbuf + slab * 9216; K = 96; N = 96;
            i = ((idx - 288) % 36) * 256 + t;
        }
        if (i < K * N) {
            int n = i / K, k = i % K;
            D[i] = __float2bfloat16(W[k * N + n]);
        }
    } else {
        // --- LN1: one wave per row ---
        int row = (b - 1214) * 4 + (t >> 6);
        int lane = t & 63;
        if (row >= NN) return;
        const float* xr = x + (size_t)row * HIDD;
        float v0 = xr[lane];
        float v1 = (lane < 32) ? xr[64 + lane] : 0.0f;
        float s = v0 + v1, q = v0 * v0 + v1 * v1;
#pragma unroll
        for (int o = 32; o > 0; o >>= 1) {
            s += __shfl_xor(s, o);
            q += __shfl_xor(q, o);
        }
        float mean = s * (1.0f / 96.0f);
        float var = q * (1.0f / 96.0f) - mean * mean;
        float rs = rsqrtf(var + 1e-5f);
        __hip_bfloat16* yr = ybf + (size_t)row * HIDD;
        yr[lane] = __float2bfloat16((v0 - mean) * rs * g1[lane] + b1[lane]);
        if (lane < 32)
            yr[64 + lane] = __float2bfloat16((v1 - mean) * rs * g1[64 + lane] + b1[64 + lane]);
    }
}

// ---------------- scan 128 bucket counts; init bbase + gcursor ----------------
__global__ __launch_bounds__(128) void bucket_scan(const int* __restrict__ bcnt,
                                                   int* __restrict__ bbase,
                                                   int* __restrict__ gcursor) {
    __shared__ int s[128];
    int t = threadIdx.x;
    s[t] = bcnt[t];
    __syncthreads();
    for (int off = 1; off < 128; off <<= 1) {
        int v = (t >= off) ? s[t - off] : 0;
        __syncthreads();
        s[t] += v;
        __syncthreads();
    }
    int excl = (t > 0) ? s[t - 1] : 0;
    bbase[t] = excl;
    gcursor[t] = excl;
    if (t == 127) bbase[128] = s[127];
}

// ---------------- MFMA GEMM body (LDS-staged B) ----------------
// C = A[M x K](bf16) @ BT[96-col slab x K]^T + bias (+ epilogue)
// Block: 256 thr = 4 waves, BM=128; wave owns 32 rows (2x 16-row frags) x 96 cols.
// NOTE: no early return — all waves must stage B and hit barriers.
// C/D frag: col = lane&15, row = (lane>>4)*4 + reg   [m89-verified]
// SMODE: 0 = fp32 flat, 1 = bf16 flat, 2 = fp8 kv-interleaved (+koff)
template<int K, int EPI, int SMODE>
__device__ __forceinline__ void gemm_body(
    const __hip_bfloat16* __restrict__ A, const __hip_bfloat16* __restrict__ BT,
    const float* __restrict__ bias, const float* __restrict__ R,
    void* __restrict__ Cptr, int ldc, int col0, int koff, int xb) {
    constexpr int BK = (K > 192) ? 192 : K;
    __shared__ __hip_bfloat16 Bs[96][BK + 8];
    int t = threadIdx.x;
    int lane = t & 63, wave = t >> 6;
    int row0 = xb * 128 + wave * 32;
    int lr = lane & 15, kg = lane >> 4;
    bool val0 = (row0 + 16 <= NN);
    bool val1 = (row0 + 32 <= NN);
    int ra0 = val0 ? row0 : 0;
    int ra1 = val1 ? (row0 + 16) : 0;
    const __hip_bfloat16* A0 = A + (size_t)(ra0 + lr) * K + kg * 8;
    const __hip_bfloat16* A1 = A + (size_t)(ra1 + lr) * K + kg * 8;
    f32x4 acc[2][6];
#pragma unroll
    for (int f = 0; f < 2; f++)
#pragma unroll
        for (int ct = 0; ct < 6; ct++) acc[f][ct] = (f32x4){0.f, 0.f, 0.f, 0.f};

    for (int k0 = 0; k0 < K; k0 += BK) {
        for (int i = t * 8; i < 96 * BK; i += 256 * 8) {
            int r = i / BK, c = i % BK;
            *(short8*)&Bs[r][c] = *(const short8*)&BT[(size_t)r * K + k0 + c];
        }
        __syncthreads();
#pragma unroll
        for (int kc = 0; kc < BK; kc += 32) {
            short8 a0 = *(const short8*)(A0 + k0 + kc);
            short8 a1 = *(const short8*)(A1 + k0 + kc);
#pragma unroll
            for (int ct = 0; ct < 6; ct++) {
                short8 bf_ = *(const short8*)&Bs[ct * 16 + lr][kc + kg * 8];
                acc[0][ct] = __builtin_amdgcn_mfma_f32_16x16x32_bf16(a0, bf_, acc[0][ct], 0, 0, 0);
                acc[1][ct] = __builtin_amdgcn_mfma_f32_16x16x32_bf16(a1, bf_, acc[1][ct], 0, 0, 0);
            }
        }
        __syncthreads();
    }

#pragma unroll
    for (int f = 0; f < 2; f++) {
        if (f == 0 ? !val0 : !val1) continue;
        int crow = row0 + f * 16 + kg * 4;
#pragma unroll
        for (int ct = 0; ct < 6; ct++) {
            int col = col0 + ct * 16 + lr;
            float bb = bias[col];
#pragma unroll
            for (int r = 0; r < 4; r++) {
                float o = acc[f][ct][r] + bb;
                if (EPI == 1)
                    o = 0.5f * o * (1.0f + erff(o * 0.70710678118654752f));
                if (EPI == 2)
                    o += R[(size_t)(crow + r) * 96 + col];
                if (SMODE == 0)
                    ((float*)Cptr)[(size_t)(crow + r) * ldc + col] = o;
                else if (SMODE == 1)
                    ((__hip_bfloat16*)Cptr)[(size_t)(crow + r) * ldc + col] = __float2bfloat16(o);
                else {
                    unsigned int enc = (unsigned int)__builtin_amdgcn_cvt_pk_fp8_f32(o, o, 0, false);
                    ((unsigned char*)Cptr)[(size_t)(crow + r) * 192 + ((col - col0) / 12) * 24 + koff + ((col - col0) % 12)]
                        = (unsigned char)(enc & 0xffu);
                }
            }
        }
    }
}

template<int K, int EPI, int SMODE>
__global__ __launch_bounds__(256) void mfma_gemm(
    const __hip_bfloat16* __restrict__ A, const __hip_bfloat16* __restrict__ BT,
    const float* __restrict__ bias, const float* __restrict__ R,
    void* __restrict__ Cptr, int ldc) {
    int col0 = blockIdx.y * 96;
    gemm_body<K, EPI, SMODE>(A, BT + (size_t)col0 * K, bias, R, Cptr, ldc, col0, 0, blockIdx.x);
}

// ---------------- P3: bucket_scatter ∥ qkv MFMA (one launch) ----------------
// blocks [0,391): edge scatter to bucket-major ebuf; [391,1564): qkv slabs.
__global__ __launch_bounds__(256) void scatter_qkv(
    const int* __restrict__ ei, int* __restrict__ gcursor,
    unsigned int* __restrict__ ebuf,
    const __hip_bfloat16* __restrict__ A, const __hip_bfloat16* __restrict__ wbuf,
    const float* __restrict__ bq, const float* __restrict__ bk,
    const float* __restrict__ bv,
    __hip_bfloat16* __restrict__ qbf, unsigned char* __restrict__ kv) {
    int b = blockIdx.x;
    if (b < 391) {
        // --- bucket scatter ---
        __shared__ int lcount[128];
        __shared__ int lbase[128];
        int t = threadIdx.x;
        int e0 = b * 2048;
        if (t < 128) lcount[t] = 0;
        __syncthreads();
        int rank[8], dsts[8], srcv[8];
#pragma unroll
        for (int i = 0; i < 8; i++) {
            int e = e0 + t + i * 256;
            if (e < NE) {
                srcv[i] = ei[e];
                int d = ei[NE + e];
                dsts[i] = d;
                rank[i] = atomicAdd(&lcount[d >> 9], 1);
            } else dsts[i] = -1;
        }
        __syncthreads();
        if (t < 128) lbase[t] = lcount[t] ? atomicAdd(&gcursor[t], lcount[t]) : 0;
        __syncthreads();
#pragma unroll
        for (int i = 0; i < 8; i++) {
            if (dsts[i] >= 0) {
                int bk_ = dsts[i] >> 9;
                ebuf[lbase[bk_] + rank[i]] =
                    ((unsigned int)dsts[i] << 16) | (unsigned int)srcv[i];
            }
        }
    } else {
        int idx = b - 391;
        int y = idx / 391, xb = idx % 391;
        if (y == 0)
            gemm_body<96, 0, 1>(A, wbuf, bq, nullptr, qbf, 96, 0, 0, xb);
        else if (y == 1)
            gemm_body<96, 0, 2>(A, wbuf + 9216, bk, nullptr, kv, 0, 0, 0, xb);
        else
            gemm_body<96, 0, 2>(A, wbuf + 18432, bv, nullptr, kv, 0, 0, 12, xb);
    }
}

// ---------------- bucket build: per-bucket rowptr + ordered u16 srcs ----------------
__global__ __launch_bounds__(512) void bucket_build(
    const unsigned int* __restrict__ ebuf, const int* __restrict__ bbase,
    int* __restrict__ rowptr, unsigned short* __restrict__ srcs) {
    __shared__ int cnt[512];
    int b = blockIdx.x;
    int t = threadIdx.x;
    int n0 = b * 512;
    int n1 = (b + 1) * 512; if (n1 > NN) n1 = NN;
    int beg = bbase[b], end = bbase[b + 1];
    cnt[t] = 0;
    __syncthreads();
    for (int e = beg + t; e < end; e += 512)
        atomicAdd(&cnt[(ebuf[e] >> 16) - n0], 1);
    __syncthreads();
    for (int off = 1; off < 512; off <<= 1) {
        int v = (t >= off) ? cnt[t - off] : 0;
        __syncthreads();
        cnt[t] += v;
        __syncthreads();
    }
    int excl = (t > 0) ? cnt[t - 1] : 0;
    __syncthreads();
    int base = beg + excl;
    if (t < n1 - n0) rowptr[n0 + t] = base;
    if (b == NB - 1 && t == 0) rowptr[NN] = NE;
    cnt[t] = base;
    __syncthreads();
    for (int e = beg + t; e < end; e += 512) {
        unsigned int u = ebuf[e];
        int pos = atomicAdd(&cnt[(u >> 16) - n0], 1);
        srcs[pos] = (unsigned short)(u & 0xffffu);
    }
}

// ---------------- proj + LN2 fused ----------------
__global__ __launch_bounds__(256) void proj_ln(
    const __hip_bfloat16* __restrict__ A, const __hip_bfloat16* __restrict__ BT,
    const float* __restrict__ bias, const float* __restrict__ R,
    const float* __restrict__ g2, const float* __restrict__ b2v,
    float* __restrict__ x2, __hip_bfloat16* __restrict__ ybf) {
    constexpr int K = 96;
    __shared__ __hip_bfloat16 Bs[96][K + 8];
    int t = threadIdx.x;
    int lane = t & 63, wave = t >> 6;
    int row0 = blockIdx.x * 128 + wave * 32;
    int lr = lane & 15, kg = lane >> 4;
    bool val0 = (row0 + 16 <= NN);
    bool val1 = (row0 + 32 <= NN);
    int ra0 = val0 ? row0 : 0;
    int ra1 = val1 ? (row0 + 16) : 0;
    const __hip_bfloat16* A0 = A + (size_t)(ra0 + lr) * K + kg * 8;
    const __hip_bfloat16* A1 = A + (size_t)(ra1 + lr) * K + kg * 8;
    f32x4 acc[2][6];
#pragma unroll
    for (int f = 0; f < 2; f++)
#pragma unroll
        for (int ct = 0; ct < 6; ct++) acc[f][ct] = (f32x4){0.f, 0.f, 0.f, 0.f};

    for (int i = t * 8; i < 96 * K; i += 256 * 8) {
        int r = i / K, c = i % K;
        *(short8*)&Bs[r][c] = *(const short8*)&BT[(size_t)r * K + c];
    }
    __syncthreads();
#pragma unroll
    for (int kc = 0; kc < K; kc += 32) {
        short8 a0 = *(const short8*)(A0 + kc);
        short8 a1 = *(const short8*)(A1 + kc);
#pragma unroll
        for (int ct = 0; ct < 6; ct++) {
            short8 bf_ = *(const short8*)&Bs[ct * 16 + lr][kc + kg * 8];
            acc[0][ct] = __builtin_amdgcn_mfma_f32_16x16x32_bf16(a0, bf_, acc[0][ct], 0, 0, 0);
            acc[1][ct] = __builtin_amdgcn_mfma_f32_16x16x32_bf16(a1, bf_, acc[1][ct], 0, 0, 0);
        }
    }

    float bo_[6], gv[6], bv_[6];
#pragma unroll
    for (int ct = 0; ct < 6; ct++) {
        int col = ct * 16 + lr;
        bo_[ct] = bias[col];
        gv[ct]  = g2[col];
        bv_[ct] = b2v[col];
    }
#pragma unroll
    for (int f = 0; f < 2; f++) {
        if (f == 0 ? !val0 : !val1) continue;
        int crow = row0 + f * 16 + kg * 4;
#pragma unroll
        for (int r = 0; r < 4; r++) {
            int row = crow + r;
            float o[6], s1 = 0.f, s2 = 0.f;
#pragma unroll
            for (int ct = 0; ct < 6; ct++) {
                int col = ct * 16 + lr;
                float val = acc[f][ct][r] + bo_[ct] + R[(size_t)row * 96 + col];
                o[ct] = val; s1 += val; s2 += val * val;
            }
#pragma unroll
            for (int m = 1; m < 16; m <<= 1) {
                s1 += __shfl_xor(s1, m);
                s2 += __shfl_xor(s2, m);
            }
            float mu = s1 * (1.0f / 96.0f);
            float var = s2 * (1.0f / 96.0f) - mu * mu;
            float rs = rsqrtf(var + 1e-5f);
#pragma unroll
            for (int ct = 0; ct < 6; ct++) {
                int col = ct * 16 + lr;
                x2[(size_t)row * 96 + col] = o[ct];
                ybf[(size_t)row * 96 + col] =
                    __float2bfloat16((o[ct] - mu) * rs * gv[ct] + bv_[ct]);
            }
        }
    }
}

// ---------------- Sparse attention gather (fp8 kv interleaved, u16 srcs) ----------------
__global__ __launch_bounds__(256) void attn_gather(
    const __hip_bfloat16* __restrict__ qbf, const unsigned char* __restrict__ kv,
    const int* __restrict__ rowptr, const unsigned short* __restrict__ srcs,
    __hip_bfloat16* __restrict__ abf) {
    int wave = (blockIdx.x * blockDim.x + threadIdx.x) >> 6;
    int lane = threadIdx.x & 63;
    if (wave >= NN) return;
    int dst = wave;
    int h = lane & 7;
    int eslot = lane >> 3;
    float qf[12];
    {
        const uint2* qp = (const uint2*)(qbf + (size_t)dst * HIDD + h * HD);
        uint2 u0 = qp[0], u1 = qp[1], u2 = qp[2];
        unsigned int w[6] = {u0.x, u0.y, u1.x, u1.y, u2.x, u2.y};
#pragma unroll
        for (int i = 0; i < 6; i++) {
            qf[2 * i]     = bf2f((unsigned short)(w[i] & 0xffffu));
            qf[2 * i + 1] = bf2f((unsigned short)(w[i] >> 16));
        }
    }
    int beg = rowptr[dst], end = rowptr[dst + 1];
    float acc[12];
#pragma unroll
    for (int i = 0; i < 12; i++) acc[i] = 0.0f;
    float zz = 0.0f;
    for (int e = beg + eslot; e < end; e += 8) {
        int src = (int)srcs[e];
        const uint2* kp = (const uint2*)(kv + (size_t)src * 192 + h * 24);
        uint2 wA = kp[0], wB = kp[1], wC = kp[2];
        f32x2 p;
        float dot = 0.0f;
        p = __builtin_amdgcn_cvt_pk_f32_fp8(wA.x, false); dot += p[0] * qf[0]  + p[1] * qf[1];
        p = __builtin_amdgcn_cvt_pk_f32_fp8(wA.x, true);  dot += p[0] * qf[2]  + p[1] * qf[3];
        p = __builtin_amdgcn_cvt_pk_f32_fp8(wA.y, false); dot += p[0] * qf[4]  + p[1] * qf[5];
        p = __builtin_amdgcn_cvt_pk_f32_fp8(wA.y, true);  dot += p[0] * qf[6]  + p[1] * qf[7];
        p = __builtin_amdgcn_cvt_pk_f32_fp8(wB.x, false); dot += p[0] * qf[8]  + p[1] * qf[9];
        p = __builtin_amdgcn_cvt_pk_f32_fp8(wB.x, true);  dot += p[0] * qf[10] + p[1] * qf[11];
        float s = fminf(fmaxf(dot * INV_SCALE, -5.0f), 5.0f);
        float sc = expf(s);
        p = __builtin_amdgcn_cvt_pk_f32_fp8(wB.y, false); acc[0]  += p[0] * sc; acc[1]  += p[1] * sc;
        p = __builtin_amdgcn_cvt_pk_f32_fp8(wB.y, true);  acc[2]  += p[0] * sc; acc[3]  += p[1] * sc;
        p = __builtin_amdgcn_cvt_pk_f32_fp8(wC.x, false); acc[4]  += p[0] * sc; acc[5]  += p[1] * sc;
        p = __builtin_amdgcn_cvt_pk_f32_fp8(wC.x, true);  acc[6]  += p[0] * sc; acc[7]  += p[1] * sc;
        p = __builtin_amdgcn_cvt_pk_f32_fp8(wC.y, false); acc[8]  += p[0] * sc; acc[9]  += p[1] * sc;
        p = __builtin_amdgcn_cvt_pk_f32_fp8(wC.y, true);  acc[10] += p[0] * sc; acc[11] += p[1] * sc;
        zz += sc;
    }
#pragma unroll
    for (int m = 8; m < 64; m <<= 1) {
#pragma unroll
        for (int i = 0; i < 12; i++) acc[i] += __shfl_xor(acc[i], m);
        zz += __shfl_xor(zz, m);
    }
    if (eslot == 0) {
        float inv = 1.0f / (zz + 1e-6f);
        __hip_bfloat16* ar = abf + (size_t)dst * HIDD + h * HD;
#pragma unroll
        for (int i = 0; i < 12; i++) ar[i] = __float2bfloat16(acc[i] * inv);
    }
}

extern "C" void kernel_launch(void* const* d_in, const int* in_sizes, int n_in,
                              void* d_out, int out_size, void* d_ws, size_t ws_size,
                              hipStream_t stream) {
    const float* x     = (const float*)d_in[0];
    const int*   ei    = (const int*)d_in[1];
    const float* ln1_g = (const float*)d_in[2];
    const float* ln1_b = (const float*)d_in[3];
    const float* Wq    = (const float*)d_in[4];
    const float* bq    = (const float*)d_in[5];
    const float* Wk    = (const float*)d_in[6];
    const float* bk    = (const float*)d_in[7];
    const float* Wv    = (const float*)d_in[8];
    const float* bv    = (const float*)d_in[9];
    const float* Wo    = (const float*)d_in[10];
    const float* bo    = (const float*)d_in[11];
    const float* ln2_g = (const float*)d_in[12];
    const float* ln2_b = (const float*)d_in[13];
    const float* W1    = (const float*)d_in[14];
    const float* b1    = (const float*)d_in[15];
    const float* W2    = (const float*)d_in[16];
    const float* b2    = (const float*)d_in[17];
    float* out = (float*)d_out;

    // Workspace layout (float units, NF = NN*96 = 4.8M floats):
    //   qbf  bf16 [0, 0.5NF)
    //   kv   fp8  [0.5NF, NF)       (NN*192 bytes)
    //   abf  bf16 [1.5NF, 2NF)
    //   hbf  bf16 [0, 2NF)          aliases qbf/kv/abf (dead by ffn1)
    //   x2   fp32 [2NF, 3NF)
    //   ybf  bf16 [3NF, 3.5NF)
    //   CSR at 3.5NF: rowptr[NN+1] int, srcs[NE] u16, bcnt[128], bbase[129],
    //                 gcursor[128], ebuf[NE] u32
    //   wbuf bf16 at 4NF   (110592 bf16)
    float* ws = (float*)d_ws;
    const size_t NF = (size_t)NN * HIDD;
    __hip_bfloat16* qbf = (__hip_bfloat16*)ws;
    unsigned char*  kv  = (unsigned char*)(ws + NF / 2);
    __hip_bfloat16* abf = (__hip_bfloat16*)(ws + NF / 2 + NF);
    __hip_bfloat16* hbf = (__hip_bfloat16*)ws;
    float* x2 = ws + 2 * NF;
    __hip_bfloat16* ybf = (__hip_bfloat16*)(ws + 3 * NF);
    int* ibase = (int*)(ws + 3 * NF + NF / 2);
    int* rowptr = ibase;                       // NN+1
    unsigned short* srcs = (unsigned short*)(ibase + NN + 1);   // NE u16
    int* bcnt    = ibase + NN + 1 + NE / 2;    // 128
    int* bbase   = bcnt + 128;                 // 129
    int* gcursor = bbase + 129;                // 128
    unsigned int* ebuf = (unsigned int*)(gcursor + 128);        // NE u32
    __hip_bfloat16* wbuf = (__hip_bfloat16*)(ws + 4 * NF);
    __hip_bfloat16* WoT = wbuf + 27648;
    __hip_bfloat16* W1T = wbuf + 36864;
    __hip_bfloat16* W2T = wbuf + 73728;

    const int MT = (NN + 127) / 128;             // 391

    // 1. zero bucket counters (DMA node; precedes prep's atomics)
    hipMemsetAsync(bcnt, 0, 128 * sizeof(int), stream);
    // 2. P1: bucket_count ∥ wconv ∥ LN1
    prep<<<13714, 256, 0, stream>>>(ei, bcnt, Wq, Wk, Wv, Wo, W1, W2, wbuf,
                                    x, ln1_g, ln1_b, ybf);
    // 3. scan bucket counts
    bucket_scan<<<1, 128, 0, stream>>>(bcnt, bbase, gcursor);
    // 4. P3: bucket_scatter ∥ qkv MFMA
    scatter_qkv<<<391 + 3 * MT, 256, 0, stream>>>(ei, gcursor, ebuf,
                                                  ybf, wbuf, bq, bk, bv, qbf, kv);
    // 5. per-bucket CSR finalize
    bucket_build<<<NB, 512, 0, stream>>>(ebuf, bbase, rowptr, srcs);
    // 6. sparse attention
    attn_gather<<<(NN + 3) / 4, 256, 0, stream>>>(qbf, kv, rowptr, srcs, abf);
    // 7. output projection + residual + LN2
    proj_ln<<<MT, 256, 0, stream>>>(abf, WoT, bo, x, ln2_g, ln2_b, x2, ybf);
    // 8. FFN1 (+gelu)
    {
        dim3 g(MT, 4);
        mfma_gemm<96, 1, 1><<<g, 256, 0, stream>>>(ybf, W1T, b1, nullptr, hbf, FFND);
    }
    // 9. FFN2 + residual
    mfma_gemm<384, 2, 0><<<MT, 256, 0, stream>>>(hbf, W2T, b2, x2, out, 96);
}

// Round 11
// 146.937 us; speedup vs baseline: 26.6104x; 1.2315x over previous
//
#include <hip/hip_runtime.h>
#include <hip/hip_bf16.h>
#include <math.h>

#define NN 50000
#define HIDD 96
#define NH 8
#define HD 12
#define FFND 384
#define NE 800000
#define NB 98            // buckets of 512 dst nodes
#define BSTRIDE 12288    // fixed edge capacity per bucket (mean 8192, +45 sigma)

#define INV_SCALE 0.28867513459481287f

typedef short short8 __attribute__((ext_vector_type(8)));
typedef float f32x4 __attribute__((ext_vector_type(4)));
typedef float f32x2 __attribute__((ext_vector_type(2)));

__device__ __forceinline__ float bf2f(unsigned short u) {
    union { unsigned int i; float f; } c;
    c.i = ((unsigned int)u) << 16;
    return c.f;
}

// ---------------- P1: gcursor-init ∥ wconv ∥ ln1 (one launch) ----------------
// block 0: init gcursor to fixed bucket bases; [1,433): weight convert; [433,12933): LN1.
__global__ __launch_bounds__(256) void prep(
    int* __restrict__ gcursor,
    const float* __restrict__ Wq, const float* __restrict__ Wk,
    const float* __restrict__ Wv, const float* __restrict__ Wo,
    const float* __restrict__ W1, const float* __restrict__ W2,
    __hip_bfloat16* __restrict__ wbuf,
    const float* __restrict__ x, const float* __restrict__ g1,
    const float* __restrict__ b1, __hip_bfloat16* __restrict__ ybf) {
    int b = blockIdx.x;
    int t = threadIdx.x;
    if (b == 0) {
        if (t < 128) gcursor[t] = t * BSTRIDE;
        return;
    }
    if (b < 433) {
        // --- wconv: WT[n][k] = bf16(W[k][n]) ---
        int idx = b - 1;
        const float* W; __hip_bfloat16* D; int K, N; int i;
        if (idx < 144)      { W = W1; D = wbuf + 36864; K = 96;  N = 384; i = idx * 256 + t; }
        else if (idx < 288) { W = W2; D = wbuf + 73728; K = 384; N = 96;  i = (idx - 144) * 256 + t; }
        else {
            int slab = (idx - 288) / 36;
            W = (slab == 0) ? Wq : (slab == 1) ? Wk : (slab == 2) ? Wv : Wo;
            D = wbuf + slab * 9216; K = 96; N = 96;
            i = ((idx - 288) % 36) * 256 + t;
        }
        if (i < K * N) {
            int n = i / K, k = i % K;
            D[i] = __float2bfloat16(W[k * N + n]);
        }
    } else {
        // --- LN1: one wave per row ---
        int row = (b - 433) * 4 + (t >> 6);
        int lane = t & 63;
        if (row >= NN) return;
        const float* xr = x + (size_t)row * HIDD;
        float v0 = xr[lane];
        float v1 = (lane < 32) ? xr[64 + lane] : 0.0f;
        float s = v0 + v1, q = v0 * v0 + v1 * v1;
#pragma unroll
        for (int o = 32; o > 0; o >>= 1) {
            s += __shfl_xor(s, o);
            q += __shfl_xor(q, o);
        }
        float mean = s * (1.0f / 96.0f);
        float var = q * (1.0f / 96.0f) - mean * mean;
        float rs = rsqrtf(var + 1e-5f);
        __hip_bfloat16* yr = ybf + (size_t)row * HIDD;
        yr[lane] = __float2bfloat16((v0 - mean) * rs * g1[lane] + b1[lane]);
        if (lane < 32)
            yr[64 + lane] = __float2bfloat16((v1 - mean) * rs * g1[64 + lane] + b1[64 + lane]);
    }
}

// ---------------- MFMA GEMM body (LDS-staged B) ----------------
// C = A[M x K](bf16) @ BT[96-col slab x K]^T + bias (+ epilogue)
// Block: 256 thr = 4 waves, BM=128; wave owns 32 rows (2x 16-row frags) x 96 cols.
// NOTE: no early return — all waves must stage B and hit barriers.
// C/D frag: col = lane&15, row = (lane>>4)*4 + reg   [m89-verified]
// SMODE: 0 = fp32 flat, 1 = bf16 flat, 2 = fp8 kv-interleaved (+koff)
// EPI==2 residual R is bf16.
template<int K, int EPI, int SMODE>
__device__ __forceinline__ void gemm_body(
    const __hip_bfloat16* __restrict__ A, const __hip_bfloat16* __restrict__ BT,
    const float* __restrict__ bias, const __hip_bfloat16* __restrict__ R,
    void* __restrict__ Cptr, int ldc, int col0, int koff, int xb) {
    constexpr int BK = (K > 192) ? 192 : K;
    __shared__ __hip_bfloat16 Bs[96][BK + 8];
    int t = threadIdx.x;
    int lane = t & 63, wave = t >> 6;
    int row0 = xb * 128 + wave * 32;
    int lr = lane & 15, kg = lane >> 4;
    bool val0 = (row0 + 16 <= NN);
    bool val1 = (row0 + 32 <= NN);
    int ra0 = val0 ? row0 : 0;
    int ra1 = val1 ? (row0 + 16) : 0;
    const __hip_bfloat16* A0 = A + (size_t)(ra0 + lr) * K + kg * 8;
    const __hip_bfloat16* A1 = A + (size_t)(ra1 + lr) * K + kg * 8;
    f32x4 acc[2][6];
#pragma unroll
    for (int f = 0; f < 2; f++)
#pragma unroll
        for (int ct = 0; ct < 6; ct++) acc[f][ct] = (f32x4){0.f, 0.f, 0.f, 0.f};

    for (int k0 = 0; k0 < K; k0 += BK) {
        for (int i = t * 8; i < 96 * BK; i += 256 * 8) {
            int r = i / BK, c = i % BK;
            *(short8*)&Bs[r][c] = *(const short8*)&BT[(size_t)r * K + k0 + c];
        }
        __syncthreads();
#pragma unroll
        for (int kc = 0; kc < BK; kc += 32) {
            short8 a0 = *(const short8*)(A0 + k0 + kc);
            short8 a1 = *(const short8*)(A1 + k0 + kc);
#pragma unroll
            for (int ct = 0; ct < 6; ct++) {
                short8 bf_ = *(const short8*)&Bs[ct * 16 + lr][kc + kg * 8];
                acc[0][ct] = __builtin_amdgcn_mfma_f32_16x16x32_bf16(a0, bf_, acc[0][ct], 0, 0, 0);
                acc[1][ct] = __builtin_amdgcn_mfma_f32_16x16x32_bf16(a1, bf_, acc[1][ct], 0, 0, 0);
            }
        }
        __syncthreads();
    }

#pragma unroll
    for (int f = 0; f < 2; f++) {
        if (f == 0 ? !val0 : !val1) continue;
        int crow = row0 + f * 16 + kg * 4;
#pragma unroll
        for (int ct = 0; ct < 6; ct++) {
            int col = col0 + ct * 16 + lr;
            float bb = bias[col];
#pragma unroll
            for (int r = 0; r < 4; r++) {
                float o = acc[f][ct][r] + bb;
                if (EPI == 1)
                    o = 0.5f * o * (1.0f + erff(o * 0.70710678118654752f));
                if (EPI == 2)
                    o += __bfloat162float(R[(size_t)(crow + r) * 96 + col]);
                if (SMODE == 0)
                    ((float*)Cptr)[(size_t)(crow + r) * ldc + col] = o;
                else if (SMODE == 1)
                    ((__hip_bfloat16*)Cptr)[(size_t)(crow + r) * ldc + col] = __float2bfloat16(o);
                else {
                    unsigned int enc = (unsigned int)__builtin_amdgcn_cvt_pk_fp8_f32(o, o, 0, false);
                    ((unsigned char*)Cptr)[(size_t)(crow + r) * 192 + ((col - col0) / 12) * 24 + koff + ((col - col0) % 12)]
                        = (unsigned char)(enc & 0xffu);
                }
            }
        }
    }
}

template<int K, int EPI, int SMODE>
__global__ __launch_bounds__(256) void mfma_gemm(
    const __hip_bfloat16* __restrict__ A, const __hip_bfloat16* __restrict__ BT,
    const float* __restrict__ bias, const __hip_bfloat16* __restrict__ R,
    void* __restrict__ Cptr, int ldc) {
    int col0 = blockIdx.y * 96;
    gemm_body<K, EPI, SMODE>(A, BT + (size_t)col0 * K, bias, R, Cptr, ldc, col0, 0, blockIdx.x);
}

// ---------------- P2: bucket_scatter ∥ qkv MFMA (one launch) ----------------
// blocks [0,391): edge scatter to fixed-stride bucket ebuf; [391,1564): qkv slabs.
__global__ __launch_bounds__(256) void scatter_qkv(
    const int* __restrict__ ei, int* __restrict__ gcursor,
    unsigned int* __restrict__ ebuf,
    const __hip_bfloat16* __restrict__ A, const __hip_bfloat16* __restrict__ wbuf,
    const float* __restrict__ bq, const float* __restrict__ bk,
    const float* __restrict__ bv,
    __hip_bfloat16* __restrict__ qbf, unsigned char* __restrict__ kv) {
    int b = blockIdx.x;
    if (b < 391) {
        __shared__ int lcount[128];
        __shared__ int lbase[128];
        int t = threadIdx.x;
        int e0 = b * 2048;
        if (t < 128) lcount[t] = 0;
        __syncthreads();
        int rank[8], dsts[8], srcv[8];
#pragma unroll
        for (int i = 0; i < 8; i++) {
            int e = e0 + t + i * 256;
            if (e < NE) {
                srcv[i] = ei[e];
                int d = ei[NE + e];
                dsts[i] = d;
                rank[i] = atomicAdd(&lcount[d >> 9], 1);
            } else dsts[i] = -1;
        }
        __syncthreads();
        if (t < 128) lbase[t] = lcount[t] ? atomicAdd(&gcursor[t], lcount[t]) : 0;
        __syncthreads();
#pragma unroll
        for (int i = 0; i < 8; i++) {
            if (dsts[i] >= 0) {
                int bk_ = dsts[i] >> 9;
                ebuf[lbase[bk_] + rank[i]] =
                    ((unsigned int)dsts[i] << 16) | (unsigned int)srcv[i];
            }
        }
    } else {
        int idx = b - 391;
        int y = idx / 391, xb = idx % 391;
        if (y == 0)
            gemm_body<96, 0, 1>(A, wbuf, bq, nullptr, qbf, 96, 0, 0, xb);
        else if (y == 1)
            gemm_body<96, 0, 2>(A, wbuf + 9216, bk, nullptr, kv, 0, 0, 0, xb);
        else
            gemm_body<96, 0, 2>(A, wbuf + 18432, bv, nullptr, kv, 0, 0, 12, xb);
    }
}

// ---------------- bucket build: per-bucket rowrange + ordered u16 srcs ----------------
// Fixed-stride buckets: bucket b edges at ebuf[b*BSTRIDE, gcursor[b]).
__global__ __launch_bounds__(512) void bucket_build(
    const unsigned int* __restrict__ ebuf, const int* __restrict__ gcursor,
    uint2* __restrict__ rowrange, unsigned short* __restrict__ srcs) {
    __shared__ int cnt[512];
    int b = blockIdx.x;
    int t = threadIdx.x;
    int n0 = b * 512;
    int beg = b * BSTRIDE;
    int end = gcursor[b];
    cnt[t] = 0;
    __syncthreads();
    for (int e = beg + t; e < end; e += 512)
        atomicAdd(&cnt[(ebuf[e] >> 16) - n0], 1);
    __syncthreads();
    int my = cnt[t];
    for (int off = 1; off < 512; off <<= 1) {
        int v = (t >= off) ? cnt[t - off] : 0;
        __syncthreads();
        cnt[t] += v;
        __syncthreads();
    }
    int excl = (t > 0) ? cnt[t - 1] : 0;
    int base = beg + excl;
    if (n0 + t < NN) rowrange[n0 + t] = make_uint2((unsigned)base, (unsigned)(base + my));
    __syncthreads();
    cnt[t] = base;
    __syncthreads();
    for (int e = beg + t; e < end; e += 512) {
        unsigned int u = ebuf[e];
        int pos = atomicAdd(&cnt[(u >> 16) - n0], 1);
        srcs[pos] = (unsigned short)(u & 0xffffu);
    }
}

// ---------------- proj + LN2 fused (x2 out in bf16) ----------------
__global__ __launch_bounds__(256) void proj_ln(
    const __hip_bfloat16* __restrict__ A, const __hip_bfloat16* __restrict__ BT,
    const float* __restrict__ bias, const float* __restrict__ R,
    const float* __restrict__ g2, const float* __restrict__ b2v,
    __hip_bfloat16* __restrict__ x2, __hip_bfloat16* __restrict__ ybf) {
    constexpr int K = 96;
    __shared__ __hip_bfloat16 Bs[96][K + 8];
    int t = threadIdx.x;
    int lane = t & 63, wave = t >> 6;
    int row0 = blockIdx.x * 128 + wave * 32;
    int lr = lane & 15, kg = lane >> 4;
    bool val0 = (row0 + 16 <= NN);
    bool val1 = (row0 + 32 <= NN);
    int ra0 = val0 ? row0 : 0;
    int ra1 = val1 ? (row0 + 16) : 0;
    const __hip_bfloat16* A0 = A + (size_t)(ra0 + lr) * K + kg * 8;
    const __hip_bfloat16* A1 = A + (size_t)(ra1 + lr) * K + kg * 8;
    f32x4 acc[2][6];
#pragma unroll
    for (int f = 0; f < 2; f++)
#pragma unroll
        for (int ct = 0; ct < 6; ct++) acc[f][ct] = (f32x4){0.f, 0.f, 0.f, 0.f};

    for (int i = t * 8; i < 96 * K; i += 256 * 8) {
        int r = i / K, c = i % K;
        *(short8*)&Bs[r][c] = *(const short8*)&BT[(size_t)r * K + c];
    }
    __syncthreads();
#pragma unroll
    for (int kc = 0; kc < K; kc += 32) {
        short8 a0 = *(const short8*)(A0 + kc);
        short8 a1 = *(const short8*)(A1 + kc);
#pragma unroll
        for (int ct = 0; ct < 6; ct++) {
            short8 bf_ = *(const short8*)&Bs[ct * 16 + lr][kc + kg * 8];
            acc[0][ct] = __builtin_amdgcn_mfma_f32_16x16x32_bf16(a0, bf_, acc[0][ct], 0, 0, 0);
            acc[1][ct] = __builtin_amdgcn_mfma_f32_16x16x32_bf16(a1, bf_, acc[1][ct], 0, 0, 0);
        }
    }

    float bo_[6], gv[6], bv_[6];
#pragma unroll
    for (int ct = 0; ct < 6; ct++) {
        int col = ct * 16 + lr;
        bo_[ct] = bias[col];
        gv[ct]  = g2[col];
        bv_[ct] = b2v[col];
    }
#pragma unroll
    for (int f = 0; f < 2; f++) {
        if (f == 0 ? !val0 : !val1) continue;
        int crow = row0 + f * 16 + kg * 4;
#pragma unroll
        for (int r = 0; r < 4; r++) {
            int row = crow + r;
            float o[6], s1 = 0.f, s2 = 0.f;
#pragma unroll
            for (int ct = 0; ct < 6; ct++) {
                int col = ct * 16 + lr;
                float val = acc[f][ct][r] + bo_[ct] + R[(size_t)row * 96 + col];
                o[ct] = val; s1 += val; s2 += val * val;
            }
#pragma unroll
            for (int m = 1; m < 16; m <<= 1) {
                s1 += __shfl_xor(s1, m);
                s2 += __shfl_xor(s2, m);
            }
            float mu = s1 * (1.0f / 96.0f);
            float var = s2 * (1.0f / 96.0f) - mu * mu;
            float rs = rsqrtf(var + 1e-5f);
#pragma unroll
            for (int ct = 0; ct < 6; ct++) {
                int col = ct * 16 + lr;
                x2[(size_t)row * 96 + col] = __float2bfloat16(o[ct]);
                ybf[(size_t)row * 96 + col] =
                    __float2bfloat16((o[ct] - mu) * rs * gv[ct] + bv_[ct]);
            }
        }
    }
}

// ---------------- Sparse attention gather (fp8 kv interleaved, u16 srcs, uint2 rowrange) ----------------
__global__ __launch_bounds__(256) void attn_gather(
    const __hip_bfloat16* __restrict__ qbf, const unsigned char* __restrict__ kv,
    const uint2* __restrict__ rowrange, const unsigned short* __restrict__ srcs,
    __hip_bfloat16* __restrict__ abf) {
    int wave = (blockIdx.x * blockDim.x + threadIdx.x) >> 6;
    int lane = threadIdx.x & 63;
    if (wave >= NN) return;
    int dst = wave;
    int h = lane & 7;
    int eslot = lane >> 3;
    float qf[12];
    {
        const uint2* qp = (const uint2*)(qbf + (size_t)dst * HIDD + h * HD);
        uint2 u0 = qp[0], u1 = qp[1], u2 = qp[2];
        unsigned int w[6] = {u0.x, u0.y, u1.x, u1.y, u2.x, u2.y};
#pragma unroll
        for (int i = 0; i < 6; i++) {
            qf[2 * i]     = bf2f((unsigned short)(w[i] & 0xffffu));
            qf[2 * i + 1] = bf2f((unsigned short)(w[i] >> 16));
        }
    }
    uint2 rr = rowrange[dst];
    int beg = (int)rr.x, end = (int)rr.y;
    float acc[12];
#pragma unroll
    for (int i = 0; i < 12; i++) acc[i] = 0.0f;
    float zz = 0.0f;
    for (int e = beg + eslot; e < end; e += 8) {
        int src = (int)srcs[e];
        const uint2* kp = (const uint2*)(kv + (size_t)src * 192 + h * 24);
        uint2 wA = kp[0], wB = kp[1], wC = kp[2];
        f32x2 p;
        float dot = 0.0f;
        p = __builtin_amdgcn_cvt_pk_f32_fp8(wA.x, false); dot += p[0] * qf[0]  + p[1] * qf[1];
        p = __builtin_amdgcn_cvt_pk_f32_fp8(wA.x, true);  dot += p[0] * qf[2]  + p[1] * qf[3];
        p = __builtin_amdgcn_cvt_pk_f32_fp8(wA.y, false); dot += p[0] * qf[4]  + p[1] * qf[5];
        p = __builtin_amdgcn_cvt_pk_f32_fp8(wA.y, true);  dot += p[0] * qf[6]  + p[1] * qf[7];
        p = __builtin_amdgcn_cvt_pk_f32_fp8(wB.x, false); dot += p[0] * qf[8]  + p[1] * qf[9];
        p = __builtin_amdgcn_cvt_pk_f32_fp8(wB.x, true);  dot += p[0] * qf[10] + p[1] * qf[11];
        float s = fminf(fmaxf(dot * INV_SCALE, -5.0f), 5.0f);
        float sc = expf(s);
        p = __builtin_amdgcn_cvt_pk_f32_fp8(wB.y, false); acc[0]  += p[0] * sc; acc[1]  += p[1] * sc;
        p = __builtin_amdgcn_cvt_pk_f32_fp8(wB.y, true);  acc[2]  += p[0] * sc; acc[3]  += p[1] * sc;
        p = __builtin_amdgcn_cvt_pk_f32_fp8(wC.x, false); acc[4]  += p[0] * sc; acc[5]  += p[1] * sc;
        p = __builtin_amdgcn_cvt_pk_f32_fp8(wC.x, true);  acc[6]  += p[0] * sc; acc[7]  += p[1] * sc;
        p = __builtin_amdgcn_cvt_pk_f32_fp8(wC.y, false); acc[8]  += p[0] * sc; acc[9]  += p[1] * sc;
        p = __builtin_amdgcn_cvt_pk_f32_fp8(wC.y, true);  acc[10] += p[0] * sc; acc[11] += p[1] * sc;
        zz += sc;
    }
#pragma unroll
    for (int m = 8; m < 64; m <<= 1) {
#pragma unroll
        for (int i = 0; i < 12; i++) acc[i] += __shfl_xor(acc[i], m);
        zz += __shfl_xor(zz, m);
    }
    if (eslot == 0) {
        float inv = 1.0f / (zz + 1e-6f);
        __hip_bfloat16* ar = abf + (size_t)dst * HIDD + h * HD;
#pragma unroll
        for (int i = 0; i < 12; i++) ar[i] = __float2bfloat16(acc[i] * inv);
    }
}

extern "C" void kernel_launch(void* const* d_in, const int* in_sizes, int n_in,
                              void* d_out, int out_size, void* d_ws, size_t ws_size,
                              hipStream_t stream) {
    const float* x     = (const float*)d_in[0];
    const int*   ei    = (const int*)d_in[1];
    const float* ln1_g = (const float*)d_in[2];
    const float* ln1_b = (const float*)d_in[3];
    const float* Wq    = (const float*)d_in[4];
    const float* bq    = (const float*)d_in[5];
    const float* Wk    = (const float*)d_in[6];
    const float* bk    = (const float*)d_in[7];
    const float* Wv    = (const float*)d_in[8];
    const float* bv    = (const float*)d_in[9];
    const float* Wo    = (const float*)d_in[10];
    const float* bo    = (const float*)d_in[11];
    const float* ln2_g = (const float*)d_in[12];
    const float* ln2_b = (const float*)d_in[13];
    const float* W1    = (const float*)d_in[14];
    const float* b1    = (const float*)d_in[15];
    const float* W2    = (const float*)d_in[16];
    const float* b2    = (const float*)d_in[17];
    float* out = (float*)d_out;

    // Workspace layout (float units, NF = NN*96 = 4.8M floats):
    //   qbf  bf16 [0, 0.5NF)
    //   kv   fp8  [0.5NF, NF)       (NN*192 bytes)
    //   abf  bf16 [1.5NF, 2NF)
    //   hbf  bf16 [0, 2NF)          aliases qbf/kv/abf (dead by ffn1)
    //   x2   bf16 [2NF, 2.5NF)
    //   ybf  bf16 [2.5NF, 3NF)
    //   CSR at 3NF: rowrange[NN] uint2, srcs[NB*BSTRIDE] u16, gcursor[128],
    //               ebuf[NB*BSTRIDE] u32   (~7.6 MB, fits in [3NF, 3.5NF))
    //   wbuf bf16 at 3.5NF (110592 bf16)
    float* ws = (float*)d_ws;
    const size_t NF = (size_t)NN * HIDD;
    __hip_bfloat16* qbf = (__hip_bfloat16*)ws;
    unsigned char*  kv  = (unsigned char*)(ws + NF / 2);
    __hip_bfloat16* abf = (__hip_bfloat16*)(ws + NF / 2 + NF);
    __hip_bfloat16* hbf = (__hip_bfloat16*)ws;
    __hip_bfloat16* x2  = (__hip_bfloat16*)(ws + 2 * NF);
    __hip_bfloat16* ybf = (__hip_bfloat16*)(ws + 2 * NF + NF / 2);
    int* ibase = (int*)(ws + 3 * NF);
    uint2* rowrange = (uint2*)ibase;                              // NN uint2 = 2*NN ints
    unsigned short* srcs = (unsigned short*)(ibase + 2 * NN);     // NB*BSTRIDE u16
    int* gcursor = ibase + 2 * NN + (NB * BSTRIDE + 1) / 2;       // 128
    unsigned int* ebuf = (unsigned int*)(gcursor + 128);          // NB*BSTRIDE u32
    __hip_bfloat16* wbuf = (__hip_bfloat16*)(ws + 3 * NF + NF / 2);
    __hip_bfloat16* WoT = wbuf + 27648;
    __hip_bfloat16* W1T = wbuf + 36864;
    __hip_bfloat16* W2T = wbuf + 73728;

    const int MT = (NN + 127) / 128;             // 391

    // 1. P1: gcursor-init ∥ wconv ∥ LN1
    prep<<<433 + 12500, 256, 0, stream>>>(gcursor, Wq, Wk, Wv, Wo, W1, W2, wbuf,
                                          x, ln1_g, ln1_b, ybf);
    // 2. P2: bucket_scatter (fixed-stride) ∥ qkv MFMA
    scatter_qkv<<<391 + 3 * MT, 256, 0, stream>>>(ei, gcursor, ebuf,
                                                  ybf, wbuf, bq, bk, bv, qbf, kv);
    // 3. per-bucket CSR finalize (no global scan)
    bucket_build<<<NB, 512, 0, stream>>>(ebuf, gcursor, rowrange, srcs);
    // 4. sparse attention
    attn_gather<<<(NN + 3) / 4, 256, 0, stream>>>(qbf, kv, rowrange, srcs, abf);
    // 5. output projection + residual + LN2 (x2 in bf16)
    proj_ln<<<MT, 256, 0, stream>>>(abf, WoT, bo, x, ln2_g, ln2_b, x2, ybf);
    // 6. FFN1 (+gelu)
    {
        dim3 g(MT, 4);
        mfma_gemm<96, 1, 1><<<g, 256, 0, stream>>>(ybf, W1T, b1, nullptr, hbf, FFND);
    }
    // 7. FFN2 + residual (bf16 residual)
    mfma_gemm<384, 2, 0><<<MT, 256, 0, stream>>>(hbf, W2T, b2, x2, out, 96);
}

// Round 12
// 142.907 us; speedup vs baseline: 27.3609x; 1.0282x over previous
//
#include <hip/hip_runtime.h>
#include <hip/hip_bf16.h>
#include <math.h>

#define NN 50000
#define HIDD 96
#define NH 8
#define HD 12
#define FFND 384
#define NE 800000
#define NB 98            // buckets of 512 dst nodes
#define BSTRIDE 12288    // fixed edge capacity per bucket (mean 8192, +45 sigma)

#define INV_SCALE 0.28867513459481287f
#define LOG2E 1.4426950408889634f

typedef short short8 __attribute__((ext_vector_type(8)));
typedef float f32x4 __attribute__((ext_vector_type(4)));
typedef float f32x2 __attribute__((ext_vector_type(2)));

__device__ __forceinline__ float bf2f(unsigned short u) {
    union { unsigned int i; float f; } c;
    c.i = ((unsigned int)u) << 16;
    return c.f;
}

// ---------------- P1: gcursor-init ∥ wconv ∥ ln1 (one launch) ----------------
// block 0: init gcursor to fixed bucket bases; [1,433): weight convert; [433,12933): LN1.
__global__ __launch_bounds__(256) void prep(
    int* __restrict__ gcursor,
    const float* __restrict__ Wq, const float* __restrict__ Wk,
    const float* __restrict__ Wv, const float* __restrict__ Wo,
    const float* __restrict__ W1, const float* __restrict__ W2,
    __hip_bfloat16* __restrict__ wbuf,
    const float* __restrict__ x, const float* __restrict__ g1,
    const float* __restrict__ b1, __hip_bfloat16* __restrict__ ybf) {
    int b = blockIdx.x;
    int t = threadIdx.x;
    if (b == 0) {
        if (t < 128) gcursor[t] = t * BSTRIDE;
        return;
    }
    if (b < 433) {
        // --- wconv: WT[n][k] = bf16(W[k][n]) ---
        int idx = b - 1;
        const float* W; __hip_bfloat16* D; int K, N; int i;
        if (idx < 144)      { W = W1; D = wbuf + 36864; K = 96;  N = 384; i = idx * 256 + t; }
        else if (idx < 288) { W = W2; D = wbuf + 73728; K = 384; N = 96;  i = (idx - 144) * 256 + t; }
        else {
            int slab = (idx - 288) / 36;
            W = (slab == 0) ? Wq : (slab == 1) ? Wk : (slab == 2) ? Wv : Wo;
            D = wbuf + slab * 9216; K = 96; N = 96;
            i = ((idx - 288) % 36) * 256 + t;
        }
        if (i < K * N) {
            int n = i / K, k = i % K;
            D[i] = __float2bfloat16(W[k * N + n]);
        }
    } else {
        // --- LN1: one wave per row ---
        int row = (b - 433) * 4 + (t >> 6);
        int lane = t & 63;
        if (row >= NN) return;
        const float* xr = x + (size_t)row * HIDD;
        float v0 = xr[lane];
        float v1 = (lane < 32) ? xr[64 + lane] : 0.0f;
        float s = v0 + v1, q = v0 * v0 + v1 * v1;
#pragma unroll
        for (int o = 32; o > 0; o >>= 1) {
            s += __shfl_xor(s, o);
            q += __shfl_xor(q, o);
        }
        float mean = s * (1.0f / 96.0f);
        float var = q * (1.0f / 96.0f) - mean * mean;
        float rs = rsqrtf(var + 1e-5f);
        __hip_bfloat16* yr = ybf + (size_t)row * HIDD;
        yr[lane] = __float2bfloat16((v0 - mean) * rs * g1[lane] + b1[lane]);
        if (lane < 32)
            yr[64 + lane] = __float2bfloat16((v1 - mean) * rs * g1[64 + lane] + b1[64 + lane]);
    }
}

// ---------------- MFMA GEMM body (LDS-staged B) ----------------
// C = A[M x K](bf16) @ BT[96-col slab x K]^T + bias (+ epilogue)
// Block: 256 thr = 4 waves, BM=128; wave owns 32 rows (2x 16-row frags) x 96 cols.
// NOTE: no early return — all waves must stage B and hit barriers.
// C/D frag: col = lane&15, row = (lane>>4)*4 + reg   [m89-verified]
// SMODE: 0 = fp32 flat, 1 = bf16 flat, 2 = fp8 kv-interleaved (+koff)
// EPI==2 residual R is bf16.
template<int K, int EPI, int SMODE>
__device__ __forceinline__ void gemm_body(
    const __hip_bfloat16* __restrict__ A, const __hip_bfloat16* __restrict__ BT,
    const float* __restrict__ bias, const __hip_bfloat16* __restrict__ R,
    void* __restrict__ Cptr, int ldc, int col0, int koff, int xb) {
    constexpr int BK = (K > 192) ? 192 : K;
    __shared__ __hip_bfloat16 Bs[96][BK + 8];
    int t = threadIdx.x;
    int lane = t & 63, wave = t >> 6;
    int row0 = xb * 128 + wave * 32;
    int lr = lane & 15, kg = lane >> 4;
    bool val0 = (row0 + 16 <= NN);
    bool val1 = (row0 + 32 <= NN);
    int ra0 = val0 ? row0 : 0;
    int ra1 = val1 ? (row0 + 16) : 0;
    const __hip_bfloat16* A0 = A + (size_t)(ra0 + lr) * K + kg * 8;
    const __hip_bfloat16* A1 = A + (size_t)(ra1 + lr) * K + kg * 8;
    f32x4 acc[2][6];
#pragma unroll
    for (int f = 0; f < 2; f++)
#pragma unroll
        for (int ct = 0; ct < 6; ct++) acc[f][ct] = (f32x4){0.f, 0.f, 0.f, 0.f};

    for (int k0 = 0; k0 < K; k0 += BK) {
        for (int i = t * 8; i < 96 * BK; i += 256 * 8) {
            int r = i / BK, c = i % BK;
            *(short8*)&Bs[r][c] = *(const short8*)&BT[(size_t)r * K + k0 + c];
        }
        __syncthreads();
#pragma unroll
        for (int kc = 0; kc < BK; kc += 32) {
            short8 a0 = *(const short8*)(A0 + k0 + kc);
            short8 a1 = *(const short8*)(A1 + k0 + kc);
#pragma unroll
            for (int ct = 0; ct < 6; ct++) {
                short8 bf_ = *(const short8*)&Bs[ct * 16 + lr][kc + kg * 8];
                acc[0][ct] = __builtin_amdgcn_mfma_f32_16x16x32_bf16(a0, bf_, acc[0][ct], 0, 0, 0);
                acc[1][ct] = __builtin_amdgcn_mfma_f32_16x16x32_bf16(a1, bf_, acc[1][ct], 0, 0, 0);
            }
        }
        __syncthreads();
    }

#pragma unroll
    for (int f = 0; f < 2; f++) {
        if (f == 0 ? !val0 : !val1) continue;
        int crow = row0 + f * 16 + kg * 4;
#pragma unroll
        for (int ct = 0; ct < 6; ct++) {
            int col = col0 + ct * 16 + lr;
            float bb = bias[col];
#pragma unroll
            for (int r = 0; r < 4; r++) {
                float o = acc[f][ct][r] + bb;
                if (EPI == 1)
                    o = 0.5f * o * (1.0f + erff(o * 0.70710678118654752f));
                if (EPI == 2)
                    o += __bfloat162float(R[(size_t)(crow + r) * 96 + col]);
                if (SMODE == 0)
                    ((float*)Cptr)[(size_t)(crow + r) * ldc + col] = o;
                else if (SMODE == 1)
                    ((__hip_bfloat16*)Cptr)[(size_t)(crow + r) * ldc + col] = __float2bfloat16(o);
                else {
                    unsigned int enc = (unsigned int)__builtin_amdgcn_cvt_pk_fp8_f32(o, o, 0, false);
                    ((unsigned char*)Cptr)[(size_t)(crow + r) * 192 + ((col - col0) / 12) * 24 + koff + ((col - col0) % 12)]
                        = (unsigned char)(enc & 0xffu);
                }
            }
        }
    }
}

template<int K, int EPI, int SMODE>
__global__ __launch_bounds__(256) void mfma_gemm(
    const __hip_bfloat16* __restrict__ A, const __hip_bfloat16* __restrict__ BT,
    const float* __restrict__ bias, const __hip_bfloat16* __restrict__ R,
    void* __restrict__ Cptr, int ldc) {
    int col0 = blockIdx.y * 96;
    gemm_body<K, EPI, SMODE>(A, BT + (size_t)col0 * K, bias, R, Cptr, ldc, col0, 0, blockIdx.x);
}

// ---------------- P2: bucket_scatter ∥ qkv MFMA (one launch) ----------------
// blocks [0,391): edge scatter to fixed-stride bucket ebuf; [391,1564): qkv slabs.
__global__ __launch_bounds__(256) void scatter_qkv(
    const int* __restrict__ ei, int* __restrict__ gcursor,
    unsigned int* __restrict__ ebuf,
    const __hip_bfloat16* __restrict__ A, const __hip_bfloat16* __restrict__ wbuf,
    const float* __restrict__ bq, const float* __restrict__ bk,
    const float* __restrict__ bv,
    __hip_bfloat16* __restrict__ qbf, unsigned char* __restrict__ kv) {
    int b = blockIdx.x;
    if (b < 391) {
        __shared__ int lcount[128];
        __shared__ int lbase[128];
        int t = threadIdx.x;
        int e0 = b * 2048;
        if (t < 128) lcount[t] = 0;
        __syncthreads();
        int rank[8], dsts[8], srcv[8];
#pragma unroll
        for (int i = 0; i < 8; i++) {
            int e = e0 + t + i * 256;
            if (e < NE) {
                srcv[i] = ei[e];
                int d = ei[NE + e];
                dsts[i] = d;
                rank[i] = atomicAdd(&lcount[d >> 9], 1);
            } else dsts[i] = -1;
        }
        __syncthreads();
        if (t < 128) lbase[t] = lcount[t] ? atomicAdd(&gcursor[t], lcount[t]) : 0;
        __syncthreads();
#pragma unroll
        for (int i = 0; i < 8; i++) {
            if (dsts[i] >= 0) {
                int bk_ = dsts[i] >> 9;
                ebuf[lbase[bk_] + rank[i]] =
                    ((unsigned int)dsts[i] << 16) | (unsigned int)srcv[i];
            }
        }
    } else {
        int idx = b - 391;
        int y = idx / 391, xb = idx % 391;
        if (y == 0)
            gemm_body<96, 0, 1>(A, wbuf, bq, nullptr, qbf, 96, 0, 0, xb);
        else if (y == 1)
            gemm_body<96, 0, 2>(A, wbuf + 9216, bk, nullptr, kv, 0, 0, 0, xb);
        else
            gemm_body<96, 0, 2>(A, wbuf + 18432, bv, nullptr, kv, 0, 0, 12, xb);
    }
}

// ---------------- bucket build (1024 thr): per-bucket rowrange + ordered u16 srcs ----------------
// Fixed-stride buckets: bucket b edges at ebuf[b*BSTRIDE, gcursor[b]).
__global__ __launch_bounds__(1024) void bucket_build(
    const unsigned int* __restrict__ ebuf, const int* __restrict__ gcursor,
    uint2* __restrict__ rowrange, unsigned short* __restrict__ srcs) {
    __shared__ int cnt[512];
    int b = blockIdx.x;
    int t = threadIdx.x;
    int n0 = b * 512;
    int beg = b * BSTRIDE;
    int end = gcursor[b];
    if (t < 512) cnt[t] = 0;
    __syncthreads();
    for (int e = beg + t; e < end; e += 1024)
        atomicAdd(&cnt[(ebuf[e] >> 16) - n0], 1);
    __syncthreads();
    int my = (t < 512) ? cnt[t] : 0;
    for (int off = 1; off < 512; off <<= 1) {
        int v = (t >= off && t < 512) ? cnt[t - off] : 0;
        __syncthreads();
        if (t < 512) cnt[t] += v;
        __syncthreads();
    }
    int excl = (t > 0 && t < 512) ? cnt[t - 1] : 0;
    int base = beg + excl;
    if (t < 512 && n0 + t < NN)
        rowrange[n0 + t] = make_uint2((unsigned)base, (unsigned)(base + my));
    __syncthreads();
    if (t < 512) cnt[t] = base;
    __syncthreads();
    for (int e = beg + t; e < end; e += 1024) {
        unsigned int u = ebuf[e];
        int pos = atomicAdd(&cnt[(u >> 16) - n0], 1);
        srcs[pos] = (unsigned short)(u & 0xffffu);
    }
}

// ---------------- proj + LN2 fused (x2 out in bf16) ----------------
__global__ __launch_bounds__(256) void proj_ln(
    const __hip_bfloat16* __restrict__ A, const __hip_bfloat16* __restrict__ BT,
    const float* __restrict__ bias, const float* __restrict__ R,
    const float* __restrict__ g2, const float* __restrict__ b2v,
    __hip_bfloat16* __restrict__ x2, __hip_bfloat16* __restrict__ ybf) {
    constexpr int K = 96;
    __shared__ __hip_bfloat16 Bs[96][K + 8];
    int t = threadIdx.x;
    int lane = t & 63, wave = t >> 6;
    int row0 = blockIdx.x * 128 + wave * 32;
    int lr = lane & 15, kg = lane >> 4;
    bool val0 = (row0 + 16 <= NN);
    bool val1 = (row0 + 32 <= NN);
    int ra0 = val0 ? row0 : 0;
    int ra1 = val1 ? (row0 + 16) : 0;
    const __hip_bfloat16* A0 = A + (size_t)(ra0 + lr) * K + kg * 8;
    const __hip_bfloat16* A1 = A + (size_t)(ra1 + lr) * K + kg * 8;
    f32x4 acc[2][6];
#pragma unroll
    for (int f = 0; f < 2; f++)
#pragma unroll
        for (int ct = 0; ct < 6; ct++) acc[f][ct] = (f32x4){0.f, 0.f, 0.f, 0.f};

    for (int i = t * 8; i < 96 * K; i += 256 * 8) {
        int r = i / K, c = i % K;
        *(short8*)&Bs[r][c] = *(const short8*)&BT[(size_t)r * K + c];
    }
    __syncthreads();
#pragma unroll
    for (int kc = 0; kc < K; kc += 32) {
        short8 a0 = *(const short8*)(A0 + kc);
        short8 a1 = *(const short8*)(A1 + kc);
#pragma unroll
        for (int ct = 0; ct < 6; ct++) {
            short8 bf_ = *(const short8*)&Bs[ct * 16 + lr][kc + kg * 8];
            acc[0][ct] = __builtin_amdgcn_mfma_f32_16x16x32_bf16(a0, bf_, acc[0][ct], 0, 0, 0);
            acc[1][ct] = __builtin_amdgcn_mfma_f32_16x16x32_bf16(a1, bf_, acc[1][ct], 0, 0, 0);
        }
    }

    float bo_[6], gv[6], bv_[6];
#pragma unroll
    for (int ct = 0; ct < 6; ct++) {
        int col = ct * 16 + lr;
        bo_[ct] = bias[col];
        gv[ct]  = g2[col];
        bv_[ct] = b2v[col];
    }
#pragma unroll
    for (int f = 0; f < 2; f++) {
        if (f == 0 ? !val0 : !val1) continue;
        int crow = row0 + f * 16 + kg * 4;
#pragma unroll
        for (int r = 0; r < 4; r++) {
            int row = crow + r;
            float o[6], s1 = 0.f, s2 = 0.f;
#pragma unroll
            for (int ct = 0; ct < 6; ct++) {
                int col = ct * 16 + lr;
                float val = acc[f][ct][r] + bo_[ct] + R[(size_t)row * 96 + col];
                o[ct] = val; s1 += val; s2 += val * val;
            }
#pragma unroll
            for (int m = 1; m < 16; m <<= 1) {
                s1 += __shfl_xor(s1, m);
                s2 += __shfl_xor(s2, m);
            }
            float mu = s1 * (1.0f / 96.0f);
            float var = s2 * (1.0f / 96.0f) - mu * mu;
            float rs = rsqrtf(var + 1e-5f);
#pragma unroll
            for (int ct = 0; ct < 6; ct++) {
                int col = ct * 16 + lr;
                x2[(size_t)row * 96 + col] = __float2bfloat16(o[ct]);
                ybf[(size_t)row * 96 + col] =
                    __float2bfloat16((o[ct] - mu) * rs * gv[ct] + bv_[ct]);
            }
        }
    }
}

// ---------------- Sparse attention gather (fp8 kv, software-pipelined) ----------------
__global__ __launch_bounds__(256) void attn_gather(
    const __hip_bfloat16* __restrict__ qbf, const unsigned char* __restrict__ kv,
    const uint2* __restrict__ rowrange, const unsigned short* __restrict__ srcs,
    __hip_bfloat16* __restrict__ abf) {
    int wave = (blockIdx.x * blockDim.x + threadIdx.x) >> 6;
    int lane = threadIdx.x & 63;
    if (wave >= NN) return;
    int dst = wave;
    int h = lane & 7;
    int eslot = lane >> 3;
    float qf[12];
    {
        const uint2* qp = (const uint2*)(qbf + (size_t)dst * HIDD + h * HD);
        uint2 u0 = qp[0], u1 = qp[1], u2 = qp[2];
        unsigned int w[6] = {u0.x, u0.y, u1.x, u1.y, u2.x, u2.y};
#pragma unroll
        for (int i = 0; i < 6; i++) {
            qf[2 * i]     = bf2f((unsigned short)(w[i] & 0xffffu));
            qf[2 * i + 1] = bf2f((unsigned short)(w[i] >> 16));
        }
    }
    uint2 rr = rowrange[dst];
    int beg = (int)rr.x, end = (int)rr.y;
    float acc[12];
#pragma unroll
    for (int i = 0; i < 12; i++) acc[i] = 0.0f;
    float zz = 0.0f;

    // 2-stage software pipeline: prefetch next src index + kv row during compute
    int e = beg + eslot;
    bool has = e < end;
    uint2 cA, cB, cC;
    if (has) {
        int src = (int)srcs[e];
        const uint2* kp = (const uint2*)(kv + (size_t)src * 192 + h * 24);
        cA = kp[0]; cB = kp[1]; cC = kp[2];
    }
    while (has) {
        int en = e + 8;
        bool hasn = en < end;
        uint2 nA, nB, nC;
        if (hasn) {
            int srcn = (int)srcs[en];
            const uint2* kp = (const uint2*)(kv + (size_t)srcn * 192 + h * 24);
            nA = kp[0]; nB = kp[1]; nC = kp[2];
        }
        f32x2 p;
        float dot = 0.0f;
        p = __builtin_amdgcn_cvt_pk_f32_fp8(cA.x, false); dot += p[0] * qf[0]  + p[1] * qf[1];
        p = __builtin_amdgcn_cvt_pk_f32_fp8(cA.x, true);  dot += p[0] * qf[2]  + p[1] * qf[3];
        p = __builtin_amdgcn_cvt_pk_f32_fp8(cA.y, false); dot += p[0] * qf[4]  + p[1] * qf[5];
        p = __builtin_amdgcn_cvt_pk_f32_fp8(cA.y, true);  dot += p[0] * qf[6]  + p[1] * qf[7];
        p = __builtin_amdgcn_cvt_pk_f32_fp8(cB.x, false); dot += p[0] * qf[8]  + p[1] * qf[9];
        p = __builtin_amdgcn_cvt_pk_f32_fp8(cB.x, true);  dot += p[0] * qf[10] + p[1] * qf[11];
        float s = fminf(fmaxf(dot * INV_SCALE, -5.0f), 5.0f);
        float sc = exp2f(s * LOG2E);
        p = __builtin_amdgcn_cvt_pk_f32_fp8(cB.y, false); acc[0]  += p[0] * sc; acc[1]  += p[1] * sc;
        p = __builtin_amdgcn_cvt_pk_f32_fp8(cB.y, true);  acc[2]  += p[0] * sc; acc[3]  += p[1] * sc;
        p = __builtin_amdgcn_cvt_pk_f32_fp8(cC.x, false); acc[4]  += p[0] * sc; acc[5]  += p[1] * sc;
        p = __builtin_amdgcn_cvt_pk_f32_fp8(cC.x, true);  acc[6]  += p[0] * sc; acc[7]  += p[1] * sc;
        p = __builtin_amdgcn_cvt_pk_f32_fp8(cC.y, false); acc[8]  += p[0] * sc; acc[9]  += p[1] * sc;
        p = __builtin_amdgcn_cvt_pk_f32_fp8(cC.y, true);  acc[10] += p[0] * sc; acc[11] += p[1] * sc;
        zz += sc;
        cA = nA; cB = nB; cC = nC;
        e = en; has = hasn;
    }
#pragma unroll
    for (int m = 8; m < 64; m <<= 1) {
#pragma unroll
        for (int i = 0; i < 12; i++) acc[i] += __shfl_xor(acc[i], m);
        zz += __shfl_xor(zz, m);
    }
    if (eslot == 0) {
        float inv = 1.0f / (zz + 1e-6f);
        __hip_bfloat16* ar = abf + (size_t)dst * HIDD + h * HD;
#pragma unroll
        for (int i = 0; i < 12; i++) ar[i] = __float2bfloat16(acc[i] * inv);
    }
}

extern "C" void kernel_launch(void* const* d_in, const int* in_sizes, int n_in,
                              void* d_out, int out_size, void* d_ws, size_t ws_size,
                              hipStream_t stream) {
    const float* x     = (const float*)d_in[0];
    const int*   ei    = (const int*)d_in[1];
    const float* ln1_g = (const float*)d_in[2];
    const float* ln1_b = (const float*)d_in[3];
    const float* Wq    = (const float*)d_in[4];
    const float* bq    = (const float*)d_in[5];
    const float* Wk    = (const float*)d_in[6];
    const float* bk    = (const float*)d_in[7];
    const float* Wv    = (const float*)d_in[8];
    const float* bv    = (const float*)d_in[9];
    const float* Wo    = (const float*)d_in[10];
    const float* bo    = (const float*)d_in[11];
    const float* ln2_g = (const float*)d_in[12];
    const float* ln2_b = (const float*)d_in[13];
    const float* W1    = (const float*)d_in[14];
    const float* b1    = (const float*)d_in[15];
    const float* W2    = (const float*)d_in[16];
    const float* b2    = (const float*)d_in[17];
    float* out = (float*)d_out;

    // Workspace layout (float units, NF = NN*96 = 4.8M floats):
    //   qbf  bf16 [0, 0.5NF)
    //   kv   fp8  [0.5NF, NF)       (NN*192 bytes)
    //   abf  bf16 [1.5NF, 2NF)
    //   hbf  bf16 [0, 2NF)          aliases qbf/kv/abf (dead by ffn1)
    //   x2   bf16 [2NF, 2.5NF)
    //   ybf  bf16 [2.5NF, 3NF)
    //   CSR at 3NF: rowrange[NN] uint2, srcs[NB*BSTRIDE] u16, gcursor[128],
    //               ebuf[NB*BSTRIDE] u32
    //   wbuf bf16 at 3.5NF (110592 bf16)
    float* ws = (float*)d_ws;
    const size_t NF = (size_t)NN * HIDD;
    __hip_bfloat16* qbf = (__hip_bfloat16*)ws;
    unsigned char*  kv  = (unsigned char*)(ws + NF / 2);
    __hip_bfloat16* abf = (__hip_bfloat16*)(ws + NF / 2 + NF);
    __hip_bfloat16* hbf = (__hip_bfloat16*)ws;
    __hip_bfloat16* x2  = (__hip_bfloat16*)(ws + 2 * NF);
    __hip_bfloat16* ybf = (__hip_bfloat16*)(ws + 2 * NF + NF / 2);
    int* ibase = (int*)(ws + 3 * NF);
    uint2* rowrange = (uint2*)ibase;                              // NN uint2
    unsigned short* srcs = (unsigned short*)(ibase + 2 * NN);     // NB*BSTRIDE u16
    int* gcursor = ibase + 2 * NN + (NB * BSTRIDE + 1) / 2;       // 128
    unsigned int* ebuf = (unsigned int*)(gcursor + 128);          // NB*BSTRIDE u32
    __hip_bfloat16* wbuf = (__hip_bfloat16*)(ws + 3 * NF + NF / 2);
    __hip_bfloat16* WoT = wbuf + 27648;
    __hip_bfloat16* W1T = wbuf + 36864;
    __hip_bfloat16* W2T = wbuf + 73728;

    const int MT = (NN + 127) / 128;             // 391

    // 1. P1: gcursor-init ∥ wconv ∥ LN1
    prep<<<433 + 12500, 256, 0, stream>>>(gcursor, Wq, Wk, Wv, Wo, W1, W2, wbuf,
                                          x, ln1_g, ln1_b, ybf);
    // 2. P2: bucket_scatter (fixed-stride) ∥ qkv MFMA
    scatter_qkv<<<391 + 3 * MT, 256, 0, stream>>>(ei, gcursor, ebuf,
                                                  ybf, wbuf, bq, bk, bv, qbf, kv);
    // 3. per-bucket CSR finalize (1024 thr)
    bucket_build<<<NB, 1024, 0, stream>>>(ebuf, gcursor, rowrange, srcs);
    // 4. sparse attention
    attn_gather<<<(NN + 3) / 4, 256, 0, stream>>>(qbf, kv, rowrange, srcs, abf);
    // 5. output projection + residual + LN2 (x2 in bf16)
    proj_ln<<<MT, 256, 0, stream>>>(abf, WoT, bo, x, ln2_g, ln2_b, x2, ybf);
    // 6. FFN1 (+gelu)
    {
        dim3 g(MT, 4);
        mfma_gemm<96, 1, 1><<<g, 256, 0, stream>>>(ybf, W1T, b1, nullptr, hbf, FFND);
    }
    // 7. FFN2 + residual (bf16 residual)
    mfma_gemm<384, 2, 0><<<MT, 256, 0, stream>>>(hbf, W2T, b2, x2, out, 96);
}